// Round 1
// baseline (1397.908 us; speedup 1.0000x reference)
//
#include <hip/hip_runtime.h>
#include <cstdint>
#include <cstddef>

// Problem constants (fixed by setup_inputs)
constexpr int R_ = 2048;   // reg_len
constexpr int B_ = 2;      // batch
constexpr int S_ = 128;    // sum_len
constexpr int E_ = 512;    // embed dim
constexpr int H_ = 8;      // heads
constexpr int D_ = 64;     // head dim
constexpr int N_ = R_ * B_;            // 4096 token rows
constexpr float SCALE_ = 0.125f;       // D^-0.5

// ---------------------------------------------------------------------------
// Generic NT GEMM: C[n][o] = (sum_i A[n][i] * W[o][i] + bias[o]) * scale
// layout 0: C row-major [N][Ocols]
// layout 1: C scattered to attention layout [B][H][R][D]  (n = r*B+b, o = h*D+d)
// 64x64 tile, 256 threads, 4x4 per thread, K-chunks of 16.
// ---------------------------------------------------------------------------
__global__ __launch_bounds__(256)
void gemm_nt_kernel(const float* __restrict__ A, const float* __restrict__ W,
                    const float* __restrict__ bias, float* __restrict__ C,
                    int Kdim, int Ocols, float scale, int layout)
{
  __shared__ float As[64][17];
  __shared__ float Ws[64][17];
  const int tid = threadIdx.x;
  const int tn = tid >> 4;          // 0..15
  const int to = tid & 15;          // 0..15
  const int n0 = blockIdx.x * 64;
  const int o0 = blockIdx.y * 64;
  const int lr = tid >> 2;          // 0..63 load row
  const int lc = (tid & 3) << 2;    // 0,4,8,12

  float acc[4][4] = {};

  for (int k0 = 0; k0 < Kdim; k0 += 16) {
    float4 a4 = *(const float4*)(A + (size_t)(n0 + lr) * Kdim + k0 + lc);
    float4 w4 = *(const float4*)(W + (size_t)(o0 + lr) * Kdim + k0 + lc);
    As[lr][lc + 0] = a4.x; As[lr][lc + 1] = a4.y;
    As[lr][lc + 2] = a4.z; As[lr][lc + 3] = a4.w;
    Ws[lr][lc + 0] = w4.x; Ws[lr][lc + 1] = w4.y;
    Ws[lr][lc + 2] = w4.z; Ws[lr][lc + 3] = w4.w;
    __syncthreads();
#pragma unroll
    for (int kk = 0; kk < 16; ++kk) {
      float a[4], w[4];
#pragma unroll
      for (int j = 0; j < 4; ++j) a[j] = As[tn * 4 + j][kk];
#pragma unroll
      for (int j = 0; j < 4; ++j) w[j] = Ws[to * 4 + j][kk];
#pragma unroll
      for (int i = 0; i < 4; ++i)
#pragma unroll
        for (int j = 0; j < 4; ++j)
          acc[i][j] = fmaf(a[i], w[j], acc[i][j]);
    }
    __syncthreads();
  }

#pragma unroll
  for (int i = 0; i < 4; ++i) {
    const int n = n0 + tn * 4 + i;
#pragma unroll
    for (int j = 0; j < 4; ++j) {
      const int o = o0 + to * 4 + j;
      float v = acc[i][j];
      if (bias) v += bias[o];
      v *= scale;
      if (layout == 0) {
        C[(size_t)n * Ocols + o] = v;
      } else {
        const int b = n & (B_ - 1);
        const int r = n >> 1;           // n / B_
        const int h = o >> 6;           // o / D_
        const int d = o & (D_ - 1);
        C[(((size_t)(b * H_ + h)) * R_ + r) * D_ + d] = v;
      }
    }
  }
}

// ---------------------------------------------------------------------------
// Summary-query gather: outq[b][h][s][d] = table[ids[b][s]][h*D+d] * SCALE
// ---------------------------------------------------------------------------
__global__ __launch_bounds__(256)
void gather_sumq_kernel(const float* __restrict__ table, const int* __restrict__ ids,
                        float* __restrict__ outq)
{
  const int idx = blockIdx.x * 256 + threadIdx.x;   // < B*H*S*D = 131072
  const int d = idx & (D_ - 1);
  const int s = (idx >> 6) & (S_ - 1);
  const int h = (idx >> 13) & (H_ - 1);
  const int b = idx >> 16;
  const int tok = ids[b * S_ + s];
  outq[idx] = table[(size_t)tok * E_ + h * D_ + d] * SCALE_;
}

// ---------------------------------------------------------------------------
// Generic fp32 flash attention, one (b,h) per blockIdx.y, 32 q-rows per block.
// Q layout: [bh][q_len][D]; K,V layout: [bh][kv_len][D].
// out_mode 0: Out[bh][q][d]                     (stage-1 -> sum_x2)
// out_mode 1: Out[(q*B + b)*E + h*D + d]        (stages 2/3 -> [R,B,E] rows)
// Q must already carry the softmax scale.
// ---------------------------------------------------------------------------
__global__ __launch_bounds__(256)
void flash_kernel(const float* __restrict__ Q, const float* __restrict__ Kp,
                  const float* __restrict__ Vp, float* __restrict__ Out,
                  int q_len, int kv_len, int out_mode)
{
  const int bh = blockIdx.y;
  const int b = bh / H_;
  const int h = bh % H_;
  const int q0 = blockIdx.x * 32;
  const float* Qb = Q + (size_t)bh * q_len * D_;
  const float* Kb = Kp + (size_t)bh * kv_len * D_;
  const float* Vb = Vp + (size_t)bh * kv_len * D_;

  __shared__ float Qs[32][66];
  __shared__ float Ks[32][66];
  __shared__ float Vs[32][66];
  __shared__ float Ps[32][33];

  const int tid = threadIdx.x;
  const int r = tid >> 3;      // 0..31 q row within tile
  const int g = tid & 7;       // 8-lane group within the row

  // Load Q tile (32 x 64): each thread 8 contiguous floats of its row
  {
    const int lc = g * 8;
    float4 qa = *(const float4*)(Qb + (size_t)(q0 + r) * D_ + lc);
    float4 qb2 = *(const float4*)(Qb + (size_t)(q0 + r) * D_ + lc + 4);
    Qs[r][lc + 0] = qa.x; Qs[r][lc + 1] = qa.y; Qs[r][lc + 2] = qa.z; Qs[r][lc + 3] = qa.w;
    Qs[r][lc + 4] = qb2.x; Qs[r][lc + 5] = qb2.y; Qs[r][lc + 6] = qb2.z; Qs[r][lc + 7] = qb2.w;
  }

  float acc[8] = {0, 0, 0, 0, 0, 0, 0, 0};
  float m = -INFINITY;
  float l = 0.0f;

  for (int k0 = 0; k0 < kv_len; k0 += 32) {
    __syncthreads();   // prior iter reads done (also covers initial Q-store visibility)
    {
      const int lc = g * 8;
      float4 ka = *(const float4*)(Kb + (size_t)(k0 + r) * D_ + lc);
      float4 kb2 = *(const float4*)(Kb + (size_t)(k0 + r) * D_ + lc + 4);
      float4 va = *(const float4*)(Vb + (size_t)(k0 + r) * D_ + lc);
      float4 vb2 = *(const float4*)(Vb + (size_t)(k0 + r) * D_ + lc + 4);
      Ks[r][lc + 0] = ka.x; Ks[r][lc + 1] = ka.y; Ks[r][lc + 2] = ka.z; Ks[r][lc + 3] = ka.w;
      Ks[r][lc + 4] = kb2.x; Ks[r][lc + 5] = kb2.y; Ks[r][lc + 6] = kb2.z; Ks[r][lc + 7] = kb2.w;
      Vs[r][lc + 0] = va.x; Vs[r][lc + 1] = va.y; Vs[r][lc + 2] = va.z; Vs[r][lc + 3] = va.w;
      Vs[r][lc + 4] = vb2.x; Vs[r][lc + 5] = vb2.y; Vs[r][lc + 6] = vb2.z; Vs[r][lc + 7] = vb2.w;
    }
    __syncthreads();

    // scores: this thread computes 4 kv columns c = g*4 + j
    float s[4] = {0, 0, 0, 0};
    for (int d = 0; d < D_; d += 2) {
      float2 q2 = *(const float2*)&Qs[r][d];
#pragma unroll
      for (int j = 0; j < 4; ++j) {
        float2 k2 = *(const float2*)&Ks[g * 4 + j][d];
        s[j] = fmaf(q2.x, k2.x, s[j]);
        s[j] = fmaf(q2.y, k2.y, s[j]);
      }
    }

    // online softmax (8-lane group owns the row)
    float tm = fmaxf(fmaxf(s[0], s[1]), fmaxf(s[2], s[3]));
    tm = fmaxf(tm, __shfl_xor(tm, 1));
    tm = fmaxf(tm, __shfl_xor(tm, 2));
    tm = fmaxf(tm, __shfl_xor(tm, 4));
    const float mnew = fmaxf(m, tm);
    float p[4];
    float ls = 0.0f;
#pragma unroll
    for (int j = 0; j < 4; ++j) { p[j] = __expf(s[j] - mnew); ls += p[j]; }
    ls += __shfl_xor(ls, 1);
    ls += __shfl_xor(ls, 2);
    ls += __shfl_xor(ls, 4);
    const float f = __expf(m - mnew);   // first iter: exp(-inf) = 0
    l = l * f + ls;
    m = mnew;
#pragma unroll
    for (int c = 0; c < 8; ++c) acc[c] *= f;
    Ps[r][g * 4 + 0] = p[0];
    Ps[r][g * 4 + 1] = p[1];
    Ps[r][g * 4 + 2] = p[2];
    Ps[r][g * 4 + 3] = p[3];
    __syncthreads();

    // PV: this thread accumulates O[r][g*8 .. g*8+7]
#pragma unroll
    for (int k = 0; k < 32; ++k) {
      const float pk = Ps[r][k];
#pragma unroll
      for (int j = 0; j < 8; j += 2) {
        float2 v2 = *(const float2*)&Vs[k][g * 8 + j];
        acc[j]     = fmaf(pk, v2.x, acc[j]);
        acc[j + 1] = fmaf(pk, v2.y, acc[j + 1]);
      }
    }
  }

  const float inv = 1.0f / l;
  const int q = q0 + r;
  size_t base;
  if (out_mode == 0) base = ((size_t)bh * q_len + q) * D_ + g * 8;
  else               base = ((size_t)q * B_ + b) * E_ + h * D_ + g * 8;
  float4 o0v = make_float4(acc[0] * inv, acc[1] * inv, acc[2] * inv, acc[3] * inv);
  float4 o1v = make_float4(acc[4] * inv, acc[5] * inv, acc[6] * inv, acc[7] * inv);
  *(float4*)(Out + base) = o0v;
  *(float4*)(Out + base + 4) = o1v;
}

// ---------------------------------------------------------------------------
// gate = sigmoid(t1 + t2 + gate_bias[e]); attn = g*sum_out + (1-g)*reg_out
// ---------------------------------------------------------------------------
__global__ __launch_bounds__(256)
void gate_blend_kernel(const float* __restrict__ t1, const float* __restrict__ t2,
                       const float* __restrict__ gb, const float* __restrict__ so,
                       const float* __restrict__ ro, float* __restrict__ attn)
{
  const int idx = blockIdx.x * 256 + threadIdx.x;   // < N_*E_
  const float x = t1[idx] + t2[idx] + gb[idx & (E_ - 1)];
  const float gp = 1.0f / (1.0f + __expf(-x));
  attn[idx] = gp * so[idx] + (1.0f - gp) * ro[idx];
}

// ---------------------------------------------------------------------------
extern "C" void kernel_launch(void* const* d_in, const int* in_sizes, int n_in,
                              void* d_out, int out_size, void* d_ws, size_t ws_size,
                              hipStream_t stream)
{
  const float* reg_x = (const float*)d_in[0];
  const int*   ids   = (const int*)d_in[1];
  // d_in[2] = sum_len, d_in[3] = reg_len (scalars, unused; shapes are fixed)
  const float* table = (const float*)d_in[4];
  const float* wq1 = (const float*)d_in[5];  const float* bq1 = (const float*)d_in[6];
  const float* wq2 = (const float*)d_in[7];  const float* bq2 = (const float*)d_in[8];
  const float* wk  = (const float*)d_in[9];  const float* bk  = (const float*)d_in[10];
  const float* wv  = (const float*)d_in[11]; const float* bv  = (const float*)d_in[12];
  const float* wo  = (const float*)d_in[13]; const float* bo  = (const float*)d_in[14];
  const float* sgw = (const float*)d_in[15];
  const float* rgw = (const float*)d_in[16];
  const float* gb  = (const float*)d_in[17];
  float* out = (float*)d_out;
  float* ws  = (float*)d_ws;

  const size_t NE = (size_t)N_ * E_;          // 2097152
  const size_t BHSD = (size_t)B_ * H_ * S_ * D_;  // 131072

  float* q1    = ws;               // [B][H][R][D], scaled
  float* q2    = q1 + NE;          // [B][H][R][D], scaled
  float* kbuf  = q2 + NE;          // [B][H][R][D]
  float* vbuf  = kbuf + NE;        // [B][H][R][D]
  float* sumq  = vbuf + NE;        // [B][H][S][D], scaled
  float* sumx2 = sumq + BHSD;      // [B][H][S][D]
  float* sout  = sumx2 + BHSD;     // [N][E]
  float* rout  = sout + NE;        // [N][E]
  // reuse regions whose producers are no longer needed (stream-ordered):
  float* t1   = q1;                // gate GEMM 1 (q1 dead after stage-2 flash)
  float* t2   = q2;                // gate GEMM 2 (q2 dead after stage-3 flash)
  float* attn = kbuf;              // blended attn (k dead after stage-3 flash)

  const dim3 blk(256);
  const dim3 ggrid(N_ / 64, E_ / 64);       // (64, 8)

  // projections (SCALE folded into q1/q2)
  gemm_nt_kernel<<<ggrid, blk, 0, stream>>>(reg_x, wk,  bk,  kbuf, E_, E_, 1.0f,   1);
  gemm_nt_kernel<<<ggrid, blk, 0, stream>>>(reg_x, wv,  bv,  vbuf, E_, E_, 1.0f,   1);
  gemm_nt_kernel<<<ggrid, blk, 0, stream>>>(reg_x, wq1, bq1, q1,   E_, E_, SCALE_, 1);
  gemm_nt_kernel<<<ggrid, blk, 0, stream>>>(reg_x, wq2, bq2, q2,   E_, E_, SCALE_, 1);

  // summary queries
  gather_sumq_kernel<<<dim3(BHSD / 256), blk, 0, stream>>>(table, ids, sumq);

  // stage 1: summary queries attend to regular tokens -> sum_x2 [B][H][S][D]
  flash_kernel<<<dim3(S_ / 32, B_ * H_), blk, 0, stream>>>(sumq, kbuf, vbuf, sumx2, S_, R_, 0);
  // stage 2: regular queries attend to summary tokens -> sum_output [N][E]
  flash_kernel<<<dim3(R_ / 32, B_ * H_), blk, 0, stream>>>(q1, sumx2, sumx2, sout, R_, S_, 1);
  // stage 3: regular self-attention -> reg_output [N][E]
  flash_kernel<<<dim3(R_ / 32, B_ * H_), blk, 0, stream>>>(q2, kbuf, vbuf, rout, R_, R_, 1);

  // gated fusion
  gemm_nt_kernel<<<ggrid, blk, 0, stream>>>(sout, sgw, nullptr, t1, E_, E_, 1.0f, 0);
  gemm_nt_kernel<<<ggrid, blk, 0, stream>>>(rout, rgw, nullptr, t2, E_, E_, 1.0f, 0);
  gate_blend_kernel<<<dim3(NE / 256), blk, 0, stream>>>(t1, t2, gb, sout, rout, attn);

  // output projection
  gemm_nt_kernel<<<ggrid, blk, 0, stream>>>(attn, wo, bo, out, E_, E_, 1.0f, 0);
}

// Round 2
// 600.338 us; speedup vs baseline: 2.3285x; 2.3285x over previous
//
#include <hip/hip_runtime.h>
#include <cstdint>
#include <cstddef>

// Problem constants (fixed by setup_inputs)
constexpr int R_ = 2048;   // reg_len
constexpr int B_ = 2;      // batch
constexpr int S_ = 128;    // sum_len
constexpr int E_ = 512;    // embed dim
constexpr int H_ = 8;      // heads
constexpr int D_ = 64;     // head dim
constexpr int N_ = R_ * B_;            // 4096 token rows
constexpr float SCALE_ = 0.125f;       // D^-0.5

typedef short bf8_t __attribute__((ext_vector_type(8)));   // 8 bf16 in 4 VGPRs
typedef float f32x4 __attribute__((ext_vector_type(4)));

#define MFMA16(a, b, c) __builtin_amdgcn_mfma_f32_16x16x32_bf16((a), (b), (c), 0, 0, 0)

__device__ __forceinline__ unsigned short f2bf(float f) {
  unsigned u = __builtin_bit_cast(unsigned, f);
  unsigned r = u + 0x7FFFu + ((u >> 16) & 1u);   // RNE
  return (unsigned short)(r >> 16);
}
__device__ __forceinline__ float bf2f(unsigned short h) {
  unsigned u = ((unsigned)h) << 16;
  return __builtin_bit_cast(float, u);
}

// ---------------------------------------------------------------------------
// Weight split: src fp32 [512][512] -> dst bf16 [512][2048] laid out (hi|hi|lo|lo)
// ---------------------------------------------------------------------------
__global__ __launch_bounds__(256)
void split_w_kernel(const float* __restrict__ src, unsigned short* __restrict__ dst)
{
  const int idx = blockIdx.x * 256 + threadIdx.x;   // < 512*512
  const int r = idx >> 9, c = idx & 511;
  const float v = src[idx];
  const unsigned short hi = f2bf(v);
  const unsigned short lo = f2bf(v - bf2f(hi));
  unsigned short* d = dst + ((size_t)r << 11) + c;
  d[0] = hi; d[512] = hi; d[1024] = lo; d[1536] = lo;
}

// ---------------------------------------------------------------------------
// A split: src fp32 [4096][512] -> dst bf16 [4096][1024] laid out (hi|lo)
// ---------------------------------------------------------------------------
__global__ __launch_bounds__(256)
void split_a_kernel(const float* __restrict__ src, unsigned short* __restrict__ dst)
{
  const int idx = blockIdx.x * 256 + threadIdx.x;   // < 4096*512
  const int r = idx >> 9, c = idx & 511;
  const float v = src[idx];
  const unsigned short hi = f2bf(v);
  unsigned short* d = dst + ((size_t)r << 10) + c;
  d[0] = hi; d[512] = f2bf(v - bf2f(hi));
}

// ---------------------------------------------------------------------------
// Summary-query gather + split: qhi/qlo [bh][S][64], scale folded
// ---------------------------------------------------------------------------
__global__ __launch_bounds__(256)
void gather_split_kernel(const float* __restrict__ table, const int* __restrict__ ids,
                         unsigned short* __restrict__ qhi, unsigned short* __restrict__ qlo)
{
  const int idx = blockIdx.x * 256 + threadIdx.x;   // < B*H*S*D = 131072
  const int d = idx & 63;
  const int s = (idx >> 6) & 127;
  const int h = (idx >> 13) & 7;
  const int b = idx >> 16;
  const float v = table[(size_t)ids[b * S_ + s] * E_ + h * 64 + d] * SCALE_;
  const unsigned short hi = f2bf(v);
  qhi[idx] = hi;
  qlo[idx] = f2bf(v - bf2f(hi));
}

// ---------------------------------------------------------------------------
// Split-precision MFMA GEMM.
// A: bf16 [M][Ka] (hi|lo pair, Ka=1024); logical K = Keff (2048) with A column
// index wrapping mod Ka. W: bf16 [512][Keff] (hi|hi|lo|lo).
// Tile 128x64, 256 threads (4 waves, each 32 rows x 64 cols = 2x4 fragments).
// mode 0: Cf[row*512+col] (+bias)(+accum). mode 1: hi/lo pair scattered to
// attention layout [b*8+h][row>>1][col&63] with scale.
// ---------------------------------------------------------------------------
struct GemmOut {
  const unsigned short* W;
  const float* bias;
  float scale;
  float* Cf;
  unsigned short* hi;
  unsigned short* lo;
  int mode;
  int accum;
};
struct GemmOuts4 { GemmOut o[4]; };

__global__ __launch_bounds__(256)
void gemm_split_kernel(const unsigned short* __restrict__ A, int Ka, int Keff, GemmOuts4 P)
{
  const GemmOut g = P.o[blockIdx.z];
  __shared__ unsigned short As[128][48];
  __shared__ unsigned short Ws[64][48];

  const int tid = threadIdx.x;
  const int w = tid >> 6;          // wave 0..3
  const int l = tid & 63;
  const int lr = l & 15;
  const int lg = l >> 4;
  const int n0 = blockIdx.x * 128;
  const int o0 = blockIdx.y * 64;

  f32x4 acc[2][4];
#pragma unroll
  for (int m = 0; m < 2; ++m)
#pragma unroll
    for (int n = 0; n < 4; ++n) acc[m][n] = (f32x4){0.f, 0.f, 0.f, 0.f};

  const int ar = tid >> 1;          // 0..127
  const int ac = (tid & 1) * 16;
  const int wr = tid >> 2;          // 0..63
  const int wc = (tid & 3) * 8;

  for (int k0 = 0; k0 < Keff; k0 += 32) {
    const int ak = k0 & (Ka - 1);
    bf8_t a0 = *(const bf8_t*)(A + (size_t)(n0 + ar) * Ka + ak + ac);
    bf8_t a1 = *(const bf8_t*)(A + (size_t)(n0 + ar) * Ka + ak + ac + 8);
    bf8_t w0 = *(const bf8_t*)(g.W + (size_t)(o0 + wr) * Keff + k0 + wc);
    *(bf8_t*)&As[ar][ac] = a0;
    *(bf8_t*)&As[ar][ac + 8] = a1;
    *(bf8_t*)&Ws[wr][wc] = w0;
    __syncthreads();

    bf8_t bvs[4];
#pragma unroll
    for (int n = 0; n < 4; ++n)
      bvs[n] = *(const bf8_t*)&Ws[n * 16 + lr][lg * 8];
#pragma unroll
    for (int m = 0; m < 2; ++m) {
      bf8_t av = *(const bf8_t*)&As[w * 32 + m * 16 + lr][lg * 8];
#pragma unroll
      for (int n = 0; n < 4; ++n)
        acc[m][n] = MFMA16(av, bvs[n], acc[m][n]);
    }
    __syncthreads();
  }

#pragma unroll
  for (int m = 0; m < 2; ++m)
#pragma unroll
    for (int n = 0; n < 4; ++n)
#pragma unroll
      for (int r = 0; r < 4; ++r) {
        const int row = n0 + w * 32 + m * 16 + lg * 4 + r;
        const int col = o0 + n * 16 + lr;
        float v = acc[m][n][r];
        if (g.bias) v += g.bias[col];
        v *= g.scale;
        if (g.mode == 0) {
          const size_t id = ((size_t)row << 9) + col;
          if (g.accum) v += g.Cf[id];
          g.Cf[id] = v;
        } else {
          const int bb = row & 1, rr = row >> 1;
          const int hh = col >> 6, dd = col & 63;
          const size_t id = (((size_t)(bb * H_ + hh) * R_) + rr) * 64 + dd;
          const unsigned short hv = f2bf(v);
          g.hi[id] = hv;
          g.lo[id] = f2bf(v - bf2f(hv));
        }
      }
}

// ---------------------------------------------------------------------------
// Split-precision MFMA flash attention.
// Q/K/V given as bf16 hi/lo pairs [bh][len][64]; Q pre-scaled.
// Block: 64 q-rows, 256 threads (4 waves x 16 q-rows). KV tiles of 32.
// out_mode 0: hi/lo pair [bh][q][64]. out_mode 1: pair packed [q*B+b][1024]
// with hi at col h*64+d, lo at 512+col (written through OutHi only).
// ---------------------------------------------------------------------------
__global__ __launch_bounds__(256)
void flash_mfma_kernel(const unsigned short* __restrict__ Qhi, const unsigned short* __restrict__ Qlo,
                       const unsigned short* __restrict__ Khi, const unsigned short* __restrict__ Klo,
                       const unsigned short* __restrict__ Vhi, const unsigned short* __restrict__ Vlo,
                       int q_len, int kv_len, int out_mode,
                       unsigned short* __restrict__ OutHi, unsigned short* __restrict__ OutLo)
{
  __shared__ unsigned short KsH[32][72];
  __shared__ unsigned short KsL[32][72];
  __shared__ unsigned short VtH[64][48];
  __shared__ unsigned short VtL[64][48];
  __shared__ unsigned short PsH[4][16][48];
  __shared__ unsigned short PsL[4][16][48];

  const int tid = threadIdx.x;
  const int w = tid >> 6;
  const int l = tid & 63;
  const int lr = l & 15;
  const int lg = l >> 4;
  const int bh = blockIdx.y;
  const int b = bh >> 3;
  const int h = bh & 7;
  const int q0 = blockIdx.x * 64;

  // Q fragments, held in registers whole kernel
  bf8_t qh[2], ql[2];
  {
    const size_t qbase = ((size_t)bh * q_len + (q0 + w * 16 + lr)) * 64;
#pragma unroll
    for (int kd = 0; kd < 2; ++kd) {
      qh[kd] = *(const bf8_t*)(Qhi + qbase + kd * 32 + lg * 8);
      ql[kd] = *(const bf8_t*)(Qlo + qbase + kd * 32 + lg * 8);
    }
  }

  f32x4 acc[4];
#pragma unroll
  for (int nd = 0; nd < 4; ++nd) acc[nd] = (f32x4){0.f, 0.f, 0.f, 0.f};
  float mrow[4] = {-INFINITY, -INFINITY, -INFINITY, -INFINITY};
  float lrow[4] = {0.f, 0.f, 0.f, 0.f};

  const int sr = tid >> 3;            // staging row 0..31
  const int sc = (tid & 7) * 8;       // staging col 0,8,..,56

  for (int kv0 = 0; kv0 < kv_len; kv0 += 32) {
    // ---- stage K (row-major) and V (transposed) into LDS
    {
      const size_t kb = ((size_t)bh * kv_len + kv0 + sr) * 64 + sc;
      bf8_t kh = *(const bf8_t*)(Khi + kb);
      bf8_t kl = *(const bf8_t*)(Klo + kb);
      bf8_t vh = *(const bf8_t*)(Vhi + kb);
      bf8_t vl = *(const bf8_t*)(Vlo + kb);
      *(bf8_t*)&KsH[sr][sc] = kh;
      *(bf8_t*)&KsL[sr][sc] = kl;
#pragma unroll
      for (int j = 0; j < 8; ++j) {
        VtH[sc + j][sr] = (unsigned short)vh[j];
        VtL[sc + j][sr] = (unsigned short)vl[j];
      }
    }
    __syncthreads();

    // ---- QK^T (split, 12 MFMAs)
    f32x4 s[2];
    s[0] = (f32x4){0.f, 0.f, 0.f, 0.f};
    s[1] = (f32x4){0.f, 0.f, 0.f, 0.f};
#pragma unroll
    for (int kd = 0; kd < 2; ++kd) {
#pragma unroll
      for (int n = 0; n < 2; ++n) {
        bf8_t kfh = *(const bf8_t*)&KsH[n * 16 + lr][kd * 32 + lg * 8];
        bf8_t kfl = *(const bf8_t*)&KsL[n * 16 + lr][kd * 32 + lg * 8];
        s[n] = MFMA16(qh[kd], kfh, s[n]);
        s[n] = MFMA16(ql[kd], kfh, s[n]);
        s[n] = MFMA16(qh[kd], kfl, s[n]);
      }
    }

    // ---- online softmax (rows owned by 16-lane groups; reduce over lane&15)
    float f[4], p0[4], p1[4];
#pragma unroll
    for (int r = 0; r < 4; ++r) {
      float mx = fmaxf(s[0][r], s[1][r]);
      mx = fmaxf(mx, __shfl_xor(mx, 1));
      mx = fmaxf(mx, __shfl_xor(mx, 2));
      mx = fmaxf(mx, __shfl_xor(mx, 4));
      mx = fmaxf(mx, __shfl_xor(mx, 8));
      const float m2 = fmaxf(mrow[r], mx);
      f[r] = __expf(mrow[r] - m2);
      mrow[r] = m2;
      p0[r] = __expf(s[0][r] - m2);
      p1[r] = __expf(s[1][r] - m2);
      float t = p0[r] + p1[r];
      t += __shfl_xor(t, 1);
      t += __shfl_xor(t, 2);
      t += __shfl_xor(t, 4);
      t += __shfl_xor(t, 8);
      lrow[r] = lrow[r] * f[r] + t;
    }
#pragma unroll
    for (int nd = 0; nd < 4; ++nd)
#pragma unroll
      for (int r = 0; r < 4; ++r) acc[nd][r] *= f[r];

    // ---- P -> LDS (bf16 hi/lo), wave-local
#pragma unroll
    for (int r = 0; r < 4; ++r) {
      const unsigned short ph0 = f2bf(p0[r]);
      PsH[w][lg * 4 + r][lr] = ph0;
      PsL[w][lg * 4 + r][lr] = f2bf(p0[r] - bf2f(ph0));
      const unsigned short ph1 = f2bf(p1[r]);
      PsH[w][lg * 4 + r][16 + lr] = ph1;
      PsL[w][lg * 4 + r][16 + lr] = f2bf(p1[r] - bf2f(ph1));
    }

    // ---- PV (split, 12 MFMAs); P store/read is wave-local, no barrier needed
    bf8_t pah = *(const bf8_t*)&PsH[w][lr][lg * 8];
    bf8_t pal = *(const bf8_t*)&PsL[w][lr][lg * 8];
#pragma unroll
    for (int nd = 0; nd < 4; ++nd) {
      bf8_t vfh = *(const bf8_t*)&VtH[nd * 16 + lr][lg * 8];
      bf8_t vfl = *(const bf8_t*)&VtL[nd * 16 + lr][lg * 8];
      acc[nd] = MFMA16(pah, vfh, acc[nd]);
      acc[nd] = MFMA16(pal, vfh, acc[nd]);
      acc[nd] = MFMA16(pah, vfl, acc[nd]);
    }
    __syncthreads();
  }

  float inv[4];
#pragma unroll
  for (int r = 0; r < 4; ++r) inv[r] = 1.0f / lrow[r];

#pragma unroll
  for (int nd = 0; nd < 4; ++nd)
#pragma unroll
    for (int r = 0; r < 4; ++r) {
      const float o = acc[nd][r] * inv[r];
      const int q = q0 + w * 16 + lg * 4 + r;
      const unsigned short hv = f2bf(o);
      const unsigned short lv = f2bf(o - bf2f(hv));
      if (out_mode == 0) {
        const size_t id = ((size_t)bh * q_len + q) * 64 + nd * 16 + lr;
        OutHi[id] = hv;
        OutLo[id] = lv;
      } else {
        const size_t nrow = (size_t)q * B_ + b;
        const int col = h * 64 + nd * 16 + lr;
        OutHi[nrow * 1024 + col] = hv;
        OutHi[nrow * 1024 + 512 + col] = lv;
      }
    }
}

// ---------------------------------------------------------------------------
// gate = sigmoid(tsum + gb); attn = g*so + (1-g)*ro, written as hi/lo pair
// ---------------------------------------------------------------------------
__global__ __launch_bounds__(256)
void blend_kernel(const float* __restrict__ tsum, const float* __restrict__ gb,
                  const unsigned short* __restrict__ sp, const unsigned short* __restrict__ rp,
                  unsigned short* __restrict__ ap)
{
  const int idx = blockIdx.x * 256 + threadIdx.x;   // < N*512
  const int n = idx >> 9, e = idx & 511;
  const size_t base = (size_t)n << 10;
  const float so = bf2f(sp[base + e]) + bf2f(sp[base + 512 + e]);
  const float ro = bf2f(rp[base + e]) + bf2f(rp[base + 512 + e]);
  const float x = tsum[idx] + gb[e];
  const float gt = 1.0f / (1.0f + __expf(-x));
  const float a = gt * so + (1.0f - gt) * ro;
  const unsigned short hv = f2bf(a);
  ap[base + e] = hv;
  ap[base + 512 + e] = f2bf(a - bf2f(hv));
}

// ---------------------------------------------------------------------------
extern "C" void kernel_launch(void* const* d_in, const int* in_sizes, int n_in,
                              void* d_out, int out_size, void* d_ws, size_t ws_size,
                              hipStream_t stream)
{
  const float* reg_x = (const float*)d_in[0];
  const int*   ids   = (const int*)d_in[1];
  const float* table = (const float*)d_in[4];
  const float* wq1 = (const float*)d_in[5];  const float* bq1 = (const float*)d_in[6];
  const float* wq2 = (const float*)d_in[7];  const float* bq2 = (const float*)d_in[8];
  const float* wk  = (const float*)d_in[9];  const float* bk  = (const float*)d_in[10];
  const float* wv  = (const float*)d_in[11]; const float* bv  = (const float*)d_in[12];
  const float* wo  = (const float*)d_in[13]; const float* bo  = (const float*)d_in[14];
  const float* sgw = (const float*)d_in[15];
  const float* rgw = (const float*)d_in[16];
  const float* gb  = (const float*)d_in[17];
  float* out = (float*)d_out;
  char* W = (char*)d_ws;

  // ---- workspace layout (bytes), total 66,060,288 (< 68,157,440 known-safe)
  const size_t oApair = 0;                        // 8,388,608  (reused: sout_pair)
  const size_t oW4    = 8388608;                  // 7 x 2,097,152
  const size_t oKhi   = oW4 + 7 * 2097152;        // 23,068,672 (reused: attn_pair over Khi+Klo)
  const size_t oKlo   = oKhi + 4194304;
  const size_t oVhi   = oKlo + 4194304;
  const size_t oVlo   = oVhi + 4194304;
  const size_t oQ1hi  = oVlo + 4194304;           // 39,845,888 (reused: tsum over q1hi+q1lo)
  const size_t oQ1lo  = oQ1hi + 4194304;
  const size_t oQ2hi  = oQ1lo + 4194304;
  const size_t oQ2lo  = oQ2hi + 4194304;
  const size_t oSQhi  = oQ2lo + 4194304;          // 56,623,104
  const size_t oSQlo  = oSQhi + 262144;
  const size_t oX2hi  = oSQlo + 262144;
  const size_t oX2lo  = oX2hi + 262144;
  const size_t oRout  = oX2lo + 262144;           // 57,671,680 (+8,388,608)

  auto U16 = [&](size_t off) { return (unsigned short*)(W + off); };
  unsigned short* Apair  = U16(oApair);
  unsigned short* Wk4    = U16(oW4 + 0 * 2097152);
  unsigned short* Wv4    = U16(oW4 + 1 * 2097152);
  unsigned short* Wq14   = U16(oW4 + 2 * 2097152);
  unsigned short* Wq24   = U16(oW4 + 3 * 2097152);
  unsigned short* Wsg4   = U16(oW4 + 4 * 2097152);
  unsigned short* Wrg4   = U16(oW4 + 5 * 2097152);
  unsigned short* Wo4    = U16(oW4 + 6 * 2097152);
  unsigned short* sout_p = U16(oApair);   // after projections, Apair is dead
  unsigned short* attn_p = U16(oKhi);     // after stage 3, K is dead
  float*          tsum   = (float*)(W + oQ1hi);  // after stage 2, q1 is dead
  unsigned short* rout_p = U16(oRout);

  const dim3 blk(256);

  // ---- precision splits
  split_a_kernel<<<8192, blk, 0, stream>>>(reg_x, Apair);
  split_w_kernel<<<1024, blk, 0, stream>>>(wk,  Wk4);
  split_w_kernel<<<1024, blk, 0, stream>>>(wv,  Wv4);
  split_w_kernel<<<1024, blk, 0, stream>>>(wq1, Wq14);
  split_w_kernel<<<1024, blk, 0, stream>>>(wq2, Wq24);
  split_w_kernel<<<1024, blk, 0, stream>>>(sgw, Wsg4);
  split_w_kernel<<<1024, blk, 0, stream>>>(rgw, Wrg4);
  split_w_kernel<<<1024, blk, 0, stream>>>(wo,  Wo4);
  gather_split_kernel<<<512, blk, 0, stream>>>(table, ids, U16(oSQhi), U16(oSQlo));

  // ---- 4 projections in one launch (blockIdx.z selects weight/output)
  GemmOuts4 proj;
  proj.o[0].W = Wk4;  proj.o[0].bias = bk;  proj.o[0].scale = 1.0f;   proj.o[0].Cf = nullptr;
  proj.o[0].hi = U16(oKhi);  proj.o[0].lo = U16(oKlo);  proj.o[0].mode = 1; proj.o[0].accum = 0;
  proj.o[1].W = Wv4;  proj.o[1].bias = bv;  proj.o[1].scale = 1.0f;   proj.o[1].Cf = nullptr;
  proj.o[1].hi = U16(oVhi);  proj.o[1].lo = U16(oVlo);  proj.o[1].mode = 1; proj.o[1].accum = 0;
  proj.o[2].W = Wq14; proj.o[2].bias = bq1; proj.o[2].scale = SCALE_; proj.o[2].Cf = nullptr;
  proj.o[2].hi = U16(oQ1hi); proj.o[2].lo = U16(oQ1lo); proj.o[2].mode = 1; proj.o[2].accum = 0;
  proj.o[3].W = Wq24; proj.o[3].bias = bq2; proj.o[3].scale = SCALE_; proj.o[3].Cf = nullptr;
  proj.o[3].hi = U16(oQ2hi); proj.o[3].lo = U16(oQ2lo); proj.o[3].mode = 1; proj.o[3].accum = 0;
  gemm_split_kernel<<<dim3(32, 8, 4), blk, 0, stream>>>(Apair, 1024, 2048, proj);

  // ---- attention stages
  flash_mfma_kernel<<<dim3(2, 16), blk, 0, stream>>>(
      U16(oSQhi), U16(oSQlo), U16(oKhi), U16(oKlo), U16(oVhi), U16(oVlo),
      S_, R_, 0, U16(oX2hi), U16(oX2lo));
  flash_mfma_kernel<<<dim3(32, 16), blk, 0, stream>>>(
      U16(oQ1hi), U16(oQ1lo), U16(oX2hi), U16(oX2lo), U16(oX2hi), U16(oX2lo),
      R_, S_, 1, sout_p, nullptr);
  flash_mfma_kernel<<<dim3(32, 16), blk, 0, stream>>>(
      U16(oQ2hi), U16(oQ2lo), U16(oKhi), U16(oKlo), U16(oVhi), U16(oVlo),
      R_, R_, 1, rout_p, nullptr);

  // ---- gate GEMMs: tsum = sout*sgw^T + rout*rgw^T
  GemmOuts4 g1;
  g1.o[0].W = Wsg4; g1.o[0].bias = nullptr; g1.o[0].scale = 1.0f; g1.o[0].Cf = tsum;
  g1.o[0].hi = nullptr; g1.o[0].lo = nullptr; g1.o[0].mode = 0; g1.o[0].accum = 0;
  g1.o[1] = g1.o[0]; g1.o[2] = g1.o[0]; g1.o[3] = g1.o[0];
  gemm_split_kernel<<<dim3(32, 8, 1), blk, 0, stream>>>(sout_p, 1024, 2048, g1);
  GemmOuts4 g2;
  g2.o[0].W = Wrg4; g2.o[0].bias = nullptr; g2.o[0].scale = 1.0f; g2.o[0].Cf = tsum;
  g2.o[0].hi = nullptr; g2.o[0].lo = nullptr; g2.o[0].mode = 0; g2.o[0].accum = 1;
  g2.o[1] = g2.o[0]; g2.o[2] = g2.o[0]; g2.o[3] = g2.o[0];
  gemm_split_kernel<<<dim3(32, 8, 1), blk, 0, stream>>>(rout_p, 1024, 2048, g2);

  // ---- gated blend -> attn pair
  blend_kernel<<<8192, blk, 0, stream>>>(tsum, gb, sout_p, rout_p, attn_p);

  // ---- output projection -> d_out
  GemmOuts4 gf;
  gf.o[0].W = Wo4; gf.o[0].bias = bo; gf.o[0].scale = 1.0f; gf.o[0].Cf = out;
  gf.o[0].hi = nullptr; gf.o[0].lo = nullptr; gf.o[0].mode = 0; gf.o[0].accum = 0;
  gf.o[1] = gf.o[0]; gf.o[2] = gf.o[0]; gf.o[3] = gf.o[0];
  gemm_split_kernel<<<dim3(32, 8, 1), blk, 0, stream>>>(attn_p, 1024, 2048, gf);
}

// Round 3
// 396.443 us; speedup vs baseline: 3.5261x; 1.5143x over previous
//
#include <hip/hip_runtime.h>
#include <cstdint>
#include <cstddef>

// Problem constants (fixed by setup_inputs)
constexpr int R_ = 2048;   // reg_len
constexpr int B_ = 2;      // batch
constexpr int S_ = 128;    // sum_len
constexpr int E_ = 512;    // embed dim
constexpr int H_ = 8;      // heads
constexpr int D_ = 64;     // head dim
constexpr int N_ = R_ * B_;            // 4096 token rows
constexpr float SCALE_ = 0.125f;       // D^-0.5

typedef short bf8_t __attribute__((ext_vector_type(8)));   // 8 bf16 in 4 VGPRs
typedef float f32x4 __attribute__((ext_vector_type(4)));

#define MFMA16(a, b, c) __builtin_amdgcn_mfma_f32_16x16x32_bf16((a), (b), (c), 0, 0, 0)

__device__ __forceinline__ unsigned short f2bf(float f) {
  unsigned u = __builtin_bit_cast(unsigned, f);
  unsigned r = u + 0x7FFFu + ((u >> 16) & 1u);   // RNE
  return (unsigned short)(r >> 16);
}
__device__ __forceinline__ float bf2f(unsigned short h) {
  unsigned u = ((unsigned)h) << 16;
  return __builtin_bit_cast(float, u);
}

// ---------------------------------------------------------------------------
// Weight split: src fp32 [512][512] -> dst bf16 [512][2048] laid out (hi|hi|lo|lo)
// ---------------------------------------------------------------------------
__global__ __launch_bounds__(256)
void split_w_kernel(const float* __restrict__ src, unsigned short* __restrict__ dst)
{
  const int idx = blockIdx.x * 256 + threadIdx.x;   // < 512*512
  const int r = idx >> 9, c = idx & 511;
  const float v = src[idx];
  const unsigned short hi = f2bf(v);
  const unsigned short lo = f2bf(v - bf2f(hi));
  unsigned short* d = dst + ((size_t)r << 11) + c;
  d[0] = hi; d[512] = hi; d[1024] = lo; d[1536] = lo;
}

// ---------------------------------------------------------------------------
// A split: src fp32 [4096][512] -> dst bf16 [4096][1024] laid out (hi|lo)
// ---------------------------------------------------------------------------
__global__ __launch_bounds__(256)
void split_a_kernel(const float* __restrict__ src, unsigned short* __restrict__ dst)
{
  const int idx = blockIdx.x * 256 + threadIdx.x;   // < 4096*512
  const int r = idx >> 9, c = idx & 511;
  const float v = src[idx];
  const unsigned short hi = f2bf(v);
  unsigned short* d = dst + ((size_t)r << 10) + c;
  d[0] = hi; d[512] = f2bf(v - bf2f(hi));
}

// ---------------------------------------------------------------------------
// Summary-query gather + split: qhi/qlo [bh][S][64], scale folded
// ---------------------------------------------------------------------------
__global__ __launch_bounds__(256)
void gather_split_kernel(const float* __restrict__ table, const int* __restrict__ ids,
                         unsigned short* __restrict__ qhi, unsigned short* __restrict__ qlo)
{
  const int idx = blockIdx.x * 256 + threadIdx.x;   // < B*H*S*D = 131072
  const int d = idx & 63;
  const int s = (idx >> 6) & 127;
  const int h = (idx >> 13) & 7;
  const int b = idx >> 16;
  const float v = table[(size_t)ids[b * S_ + s] * E_ + h * 64 + d] * SCALE_;
  const unsigned short hi = f2bf(v);
  qhi[idx] = hi;
  qlo[idx] = f2bf(v - bf2f(hi));
}

// ---------------------------------------------------------------------------
// Split-precision MFMA GEMM.
// A: bf16 [M][Ka] (hi|lo pair, Ka=1024); logical K = Keff (2048), A col wraps
// mod Ka. W: bf16 [512][Keff] (hi|hi|lo|lo).
// Tile 128x64, 256 threads (4 waves, each 32 rows x 64 cols).
// mode 0: Cf[row*512+col] (+bias)(+accum)
// mode 1: hi/lo pair -> [bh][row>>1 (=r)][col&63] row-major attn layout
// mode 2: hi/lo pair -> [bh][col&63][row>>1] transposed attn layout (for V)
// ---------------------------------------------------------------------------
struct GemmOut {
  const unsigned short* W;
  const float* bias;
  float scale;
  float* Cf;
  unsigned short* hi;
  unsigned short* lo;
  int mode;
  int accum;
};
struct GemmOuts4 { GemmOut o[4]; };

__global__ __launch_bounds__(256)
void gemm_split_kernel(const unsigned short* __restrict__ A, int Ka, int Keff, GemmOuts4 P)
{
  const GemmOut g = P.o[blockIdx.z];
  __shared__ unsigned short As[128][48];
  __shared__ unsigned short Ws[64][48];

  const int tid = threadIdx.x;
  const int w = tid >> 6;          // wave 0..3
  const int l = tid & 63;
  const int lr = l & 15;
  const int lg = l >> 4;
  const int n0 = blockIdx.x * 128;
  const int o0 = blockIdx.y * 64;

  f32x4 acc[2][4];
#pragma unroll
  for (int m = 0; m < 2; ++m)
#pragma unroll
    for (int n = 0; n < 4; ++n) acc[m][n] = (f32x4){0.f, 0.f, 0.f, 0.f};

  const int ar = tid >> 1;          // 0..127
  const int ac = (tid & 1) * 16;
  const int wr = tid >> 2;          // 0..63
  const int wc = (tid & 3) * 8;

  for (int k0 = 0; k0 < Keff; k0 += 32) {
    const int ak = k0 & (Ka - 1);
    bf8_t a0 = *(const bf8_t*)(A + (size_t)(n0 + ar) * Ka + ak + ac);
    bf8_t a1 = *(const bf8_t*)(A + (size_t)(n0 + ar) * Ka + ak + ac + 8);
    bf8_t w0 = *(const bf8_t*)(g.W + (size_t)(o0 + wr) * Keff + k0 + wc);
    *(bf8_t*)&As[ar][ac] = a0;
    *(bf8_t*)&As[ar][ac + 8] = a1;
    *(bf8_t*)&Ws[wr][wc] = w0;
    __syncthreads();

    bf8_t bvs[4];
#pragma unroll
    for (int n = 0; n < 4; ++n)
      bvs[n] = *(const bf8_t*)&Ws[n * 16 + lr][lg * 8];
#pragma unroll
    for (int m = 0; m < 2; ++m) {
      bf8_t av = *(const bf8_t*)&As[w * 32 + m * 16 + lr][lg * 8];
#pragma unroll
      for (int n = 0; n < 4; ++n)
        acc[m][n] = MFMA16(av, bvs[n], acc[m][n]);
    }
    __syncthreads();
  }

#pragma unroll
  for (int m = 0; m < 2; ++m)
#pragma unroll
    for (int n = 0; n < 4; ++n)
#pragma unroll
      for (int r = 0; r < 4; ++r) {
        const int row = n0 + w * 32 + m * 16 + lg * 4 + r;
        const int col = o0 + n * 16 + lr;
        float v = acc[m][n][r];
        if (g.bias) v += g.bias[col];
        v *= g.scale;
        if (g.mode == 0) {
          const size_t id = ((size_t)row << 9) + col;
          if (g.accum) v += g.Cf[id];
          g.Cf[id] = v;
        } else {
          const int bb = row & 1, rr = row >> 1;
          const int hh = col >> 6, dd = col & 63;
          size_t id;
          if (g.mode == 1) id = (((size_t)(bb * H_ + hh) * R_) + rr) * 64 + dd;
          else             id = (((size_t)(bb * H_ + hh) * 64) + dd) * R_ + rr;
          const unsigned short hv = f2bf(v);
          g.hi[id] = hv;
          g.lo[id] = f2bf(v - bf2f(hv));
        }
      }
}

// ---------------------------------------------------------------------------
// Split-precision MFMA flash attention, PARTIAL over a KV chunk.
// Q/K: hi/lo [bh][len][64]; V: hi/lo TRANSPOSED [bh][64][kv_len]; Q pre-scaled.
// Block: 64 q-rows, 256 threads (4 waves x 16 q-rows). KV tiles of 32.
// blockIdx.z = chunk; writes unnormalized acc (fp32) + (m,l) per row.
// acc chunk base: chunk c < zsplit -> accA + c*stride, else accB + (c-zsplit)*stride
// ---------------------------------------------------------------------------
__global__ __launch_bounds__(256)
void flash_partial_kernel(const unsigned short* __restrict__ Qhi, const unsigned short* __restrict__ Qlo,
                          const unsigned short* __restrict__ Khi, const unsigned short* __restrict__ Klo,
                          const unsigned short* __restrict__ VtHi, const unsigned short* __restrict__ VtLo,
                          int q_len, int kv_len, int chunk, int zsplit,
                          float* __restrict__ accA, float* __restrict__ accB,
                          float* __restrict__ mlP)
{
  __shared__ unsigned short KsH[32][72];
  __shared__ unsigned short KsL[32][72];
  __shared__ unsigned short VsH[64][40];
  __shared__ unsigned short VsL[64][40];
  __shared__ unsigned short PsH[4][16][40];
  __shared__ unsigned short PsL[4][16][40];

  const int tid = threadIdx.x;
  const int w = tid >> 6;
  const int l = tid & 63;
  const int lr = l & 15;
  const int lg = l >> 4;
  const int bh = blockIdx.y;
  const int q0 = blockIdx.x * 64;
  const int c = blockIdx.z;
  const int kvbeg = c * chunk;

  // Q fragments, held in registers whole kernel
  bf8_t qh[2], ql[2];
  {
    const size_t qbase = ((size_t)bh * q_len + (q0 + w * 16 + lr)) * 64;
#pragma unroll
    for (int kd = 0; kd < 2; ++kd) {
      qh[kd] = *(const bf8_t*)(Qhi + qbase + kd * 32 + lg * 8);
      ql[kd] = *(const bf8_t*)(Qlo + qbase + kd * 32 + lg * 8);
    }
  }

  f32x4 acc[4];
#pragma unroll
  for (int nd = 0; nd < 4; ++nd) acc[nd] = (f32x4){0.f, 0.f, 0.f, 0.f};
  float mrow[4] = {-INFINITY, -INFINITY, -INFINITY, -INFINITY};
  float lrow[4] = {0.f, 0.f, 0.f, 0.f};

  const int sr = tid >> 3;            // K staging row 0..31
  const int sc = (tid & 7) * 8;       // K staging col
  const int vd = tid >> 2;            // V^T staging d-row 0..63
  const int vc = (tid & 3) * 8;       // V^T staging kv-col

  for (int kv0 = kvbeg; kv0 < kvbeg + chunk; kv0 += 32) {
    // ---- stage K [32][64] and V^T [64][32] into LDS (all vectorized)
    {
      const size_t kb = ((size_t)bh * kv_len + kv0 + sr) * 64 + sc;
      bf8_t kh = *(const bf8_t*)(Khi + kb);
      bf8_t kl = *(const bf8_t*)(Klo + kb);
      const size_t vb = ((size_t)bh * 64 + vd) * kv_len + kv0 + vc;
      bf8_t vh = *(const bf8_t*)(VtHi + vb);
      bf8_t vl = *(const bf8_t*)(VtLo + vb);
      *(bf8_t*)&KsH[sr][sc] = kh;
      *(bf8_t*)&KsL[sr][sc] = kl;
      *(bf8_t*)&VsH[vd][vc] = vh;
      *(bf8_t*)&VsL[vd][vc] = vl;
    }
    __syncthreads();

    // ---- QK^T (split, 12 MFMAs)
    f32x4 s[2];
    s[0] = (f32x4){0.f, 0.f, 0.f, 0.f};
    s[1] = (f32x4){0.f, 0.f, 0.f, 0.f};
#pragma unroll
    for (int kd = 0; kd < 2; ++kd) {
#pragma unroll
      for (int n = 0; n < 2; ++n) {
        bf8_t kfh = *(const bf8_t*)&KsH[n * 16 + lr][kd * 32 + lg * 8];
        bf8_t kfl = *(const bf8_t*)&KsL[n * 16 + lr][kd * 32 + lg * 8];
        s[n] = MFMA16(qh[kd], kfh, s[n]);
        s[n] = MFMA16(ql[kd], kfh, s[n]);
        s[n] = MFMA16(qh[kd], kfl, s[n]);
      }
    }

    // ---- online softmax (rows owned by 16-lane groups)
    float f[4], p0[4], p1[4];
#pragma unroll
    for (int r = 0; r < 4; ++r) {
      float mx = fmaxf(s[0][r], s[1][r]);
      mx = fmaxf(mx, __shfl_xor(mx, 1));
      mx = fmaxf(mx, __shfl_xor(mx, 2));
      mx = fmaxf(mx, __shfl_xor(mx, 4));
      mx = fmaxf(mx, __shfl_xor(mx, 8));
      const float m2 = fmaxf(mrow[r], mx);
      f[r] = __expf(mrow[r] - m2);
      mrow[r] = m2;
      p0[r] = __expf(s[0][r] - m2);
      p1[r] = __expf(s[1][r] - m2);
      float t = p0[r] + p1[r];
      t += __shfl_xor(t, 1);
      t += __shfl_xor(t, 2);
      t += __shfl_xor(t, 4);
      t += __shfl_xor(t, 8);
      lrow[r] = lrow[r] * f[r] + t;
    }
#pragma unroll
    for (int nd = 0; nd < 4; ++nd)
#pragma unroll
      for (int r = 0; r < 4; ++r) acc[nd][r] *= f[r];

    // ---- P -> LDS (bf16 hi/lo), wave-local
#pragma unroll
    for (int r = 0; r < 4; ++r) {
      const unsigned short ph0 = f2bf(p0[r]);
      PsH[w][lg * 4 + r][lr] = ph0;
      PsL[w][lg * 4 + r][lr] = f2bf(p0[r] - bf2f(ph0));
      const unsigned short ph1 = f2bf(p1[r]);
      PsH[w][lg * 4 + r][16 + lr] = ph1;
      PsL[w][lg * 4 + r][16 + lr] = f2bf(p1[r] - bf2f(ph1));
    }

    // ---- PV (split, 12 MFMAs); B-frag read directly from V^T tile
    bf8_t pah = *(const bf8_t*)&PsH[w][lr][lg * 8];
    bf8_t pal = *(const bf8_t*)&PsL[w][lr][lg * 8];
#pragma unroll
    for (int nd = 0; nd < 4; ++nd) {
      bf8_t vfh = *(const bf8_t*)&VsH[nd * 16 + lr][lg * 8];
      bf8_t vfl = *(const bf8_t*)&VsL[nd * 16 + lr][lg * 8];
      acc[nd] = MFMA16(pah, vfh, acc[nd]);
      acc[nd] = MFMA16(pal, vfh, acc[nd]);
      acc[nd] = MFMA16(pah, vfl, acc[nd]);
    }
    __syncthreads();
  }

  // ---- store partials (unnormalized)
  const size_t cstride = (size_t)16 * q_len * 64;
  float* accbase = (c < zsplit) ? accA + (size_t)c * cstride
                                : accB + (size_t)(c - zsplit) * cstride;
#pragma unroll
  for (int nd = 0; nd < 4; ++nd)
#pragma unroll
    for (int r = 0; r < 4; ++r) {
      const int q = q0 + w * 16 + lg * 4 + r;
      accbase[((size_t)bh * q_len + q) * 64 + nd * 16 + lr] = acc[nd][r];
    }
  if (lr == 0) {
#pragma unroll
    for (int r = 0; r < 4; ++r) {
      const int q = q0 + w * 16 + lg * 4 + r;
      const size_t mi = ((size_t)(c * 16 + bh) * q_len + q) * 2;
      mlP[mi] = mrow[r];
      mlP[mi + 1] = lrow[r];
    }
  }
}

// ---------------------------------------------------------------------------
// Merge stage-1 partials -> X2 (row-major pair) and X2^T (pair)
// acc: [16 chunks][bh][128][64]; ml: [(c*16+bh)*128+q]*2
// ---------------------------------------------------------------------------
__global__ __launch_bounds__(256)
void merge_x2_kernel(const float* __restrict__ acc, const float* __restrict__ ml,
                     unsigned short* __restrict__ X2hi, unsigned short* __restrict__ X2lo,
                     unsigned short* __restrict__ X2Thi, unsigned short* __restrict__ X2Tlo)
{
  const int idx = blockIdx.x * 256 + threadIdx.x;   // < 16*128*64
  const int d = idx & 63;
  const int q = (idx >> 6) & 127;
  const int bh = idx >> 13;
  float M = -INFINITY;
#pragma unroll
  for (int c = 0; c < 16; ++c)
    M = fmaxf(M, ml[((size_t)(c * 16 + bh) * 128 + q) * 2]);
  float ls = 0.f, o = 0.f;
#pragma unroll
  for (int c = 0; c < 16; ++c) {
    const size_t mi = ((size_t)(c * 16 + bh) * 128 + q) * 2;
    const float wgt = __expf(ml[mi] - M);
    ls += wgt * ml[mi + 1];
    o += wgt * acc[(size_t)c * 131072 + ((size_t)bh * 128 + q) * 64 + d];
  }
  const float v = o / ls;
  const unsigned short hv = f2bf(v);
  const unsigned short lv = f2bf(v - bf2f(hv));
  X2hi[((size_t)bh * 128 + q) * 64 + d] = hv;
  X2lo[((size_t)bh * 128 + q) * 64 + d] = lv;
  X2Thi[((size_t)bh * 64 + d) * 128 + q] = hv;
  X2Tlo[((size_t)bh * 64 + d) * 128 + q] = lv;
}

// ---------------------------------------------------------------------------
// Merge stage-2/3 partials -> packed pair rows [q*B+b][1024] (hi | lo at +512)
// ---------------------------------------------------------------------------
__global__ __launch_bounds__(256)
void merge_rows_kernel(const float* __restrict__ accA, const float* __restrict__ accB,
                       const float* __restrict__ ml, int q_len, int qbits, int nc,
                       unsigned short* __restrict__ OutP)
{
  const int idx = blockIdx.x * 256 + threadIdx.x;   // < 16*q_len*64
  const int d = idx & 63;
  const int q = (idx >> 6) & (q_len - 1);
  const int bh = idx >> (6 + qbits);
  float M = -INFINITY;
  for (int c = 0; c < nc; ++c)
    M = fmaxf(M, ml[((size_t)(c * 16 + bh) * q_len + q) * 2]);
  float ls = 0.f, o = 0.f;
  const size_t aoff = ((size_t)bh * q_len + q) * 64 + d;
  for (int c = 0; c < nc; ++c) {
    const size_t mi = ((size_t)(c * 16 + bh) * q_len + q) * 2;
    const float wgt = __expf(ml[mi] - M);
    ls += wgt * ml[mi + 1];
    const float* a = (c == 0) ? accA : accB;
    o += wgt * a[aoff];
  }
  const float v = o / ls;
  const int b = bh >> 3, h = bh & 7;
  const size_t nrow = (size_t)q * B_ + b;
  const int col = h * 64 + d;
  const unsigned short hv = f2bf(v);
  OutP[nrow * 1024 + col] = hv;
  OutP[nrow * 1024 + 512 + col] = f2bf(v - bf2f(hv));
}

// ---------------------------------------------------------------------------
// gate = sigmoid(tsum + gb); attn = g*so + (1-g)*ro, written as hi/lo pair
// ---------------------------------------------------------------------------
__global__ __launch_bounds__(256)
void blend_kernel(const float* __restrict__ tsum, const float* __restrict__ gb,
                  const unsigned short* __restrict__ sp, const unsigned short* __restrict__ rp,
                  unsigned short* __restrict__ ap)
{
  const int idx = blockIdx.x * 256 + threadIdx.x;   // < N*512
  const int n = idx >> 9, e = idx & 511;
  const size_t base = (size_t)n << 10;
  const float so = bf2f(sp[base + e]) + bf2f(sp[base + 512 + e]);
  const float ro = bf2f(rp[base + e]) + bf2f(rp[base + 512 + e]);
  const float x = tsum[idx] + gb[e];
  const float gt = 1.0f / (1.0f + __expf(-x));
  const float a = gt * so + (1.0f - gt) * ro;
  const unsigned short hv = f2bf(a);
  ap[base + e] = hv;
  ap[base + 512 + e] = f2bf(a - bf2f(hv));
}

// ---------------------------------------------------------------------------
extern "C" void kernel_launch(void* const* d_in, const int* in_sizes, int n_in,
                              void* d_out, int out_size, void* d_ws, size_t ws_size,
                              hipStream_t stream)
{
  const float* reg_x = (const float*)d_in[0];
  const int*   ids   = (const int*)d_in[1];
  const float* table = (const float*)d_in[4];
  const float* wq1 = (const float*)d_in[5];  const float* bq1 = (const float*)d_in[6];
  const float* wq2 = (const float*)d_in[7];  const float* bq2 = (const float*)d_in[8];
  const float* wk  = (const float*)d_in[9];  const float* bk  = (const float*)d_in[10];
  const float* wv  = (const float*)d_in[11]; const float* bv  = (const float*)d_in[12];
  const float* wo  = (const float*)d_in[13]; const float* bo  = (const float*)d_in[14];
  const float* sgw = (const float*)d_in[15];
  const float* rgw = (const float*)d_in[16];
  const float* gb  = (const float*)d_in[17];
  float* out = (float*)d_out;
  char* W = (char*)d_ws;

  // ---- workspace layout (bytes), total 58,720,256 (< 66,060,288 proven-safe)
  const size_t oApair = 0;                        //  8,388,608 [reuse: sout_p]
  const size_t oW4    = 8388608;                  //  7 x 2,097,152
                                                  //  slots 0-3 [reuse: accP_A 8,388,608]
  const size_t oKhi   = oW4 + 7 * 2097152;        // 23,068,672 [reuse: attn_p over Khi+Klo]
  const size_t oKlo   = oKhi + 4194304;
  const size_t oVtHi  = oKlo + 4194304;           // 31,457,280
  const size_t oVtLo  = oVtHi + 4194304;
  const size_t oQ1hi  = oVtLo + 4194304;          // 39,845,888 [reuse: accP_B, then tsum]
  const size_t oQ1lo  = oQ1hi + 4194304;
  const size_t oQ2hi  = oQ1lo + 4194304;          // 48,234,496 [reuse: rout_p over Q2hi+Q2lo]
  const size_t oQ2lo  = oQ2hi + 4194304;
  const size_t oSQhi  = oQ2lo + 4194304;          // 56,623,104
  const size_t oSQlo  = oSQhi + 262144;
  const size_t oX2hi  = oSQlo + 262144;           // 57,147,392
  const size_t oX2lo  = oX2hi + 262144;
  const size_t oX2Thi = oX2lo + 262144;           // 57,671,680
  const size_t oX2Tlo = oX2Thi + 262144;
  const size_t oMl    = oX2Tlo + 262144;          // 58,195,968 (+524,288 = 58,720,256)

  auto U16 = [&](size_t off) { return (unsigned short*)(W + off); };
  auto F32 = [&](size_t off) { return (float*)(W + off); };
  unsigned short* Apair  = U16(oApair);
  unsigned short* Wk4    = U16(oW4 + 0 * 2097152);
  unsigned short* Wv4    = U16(oW4 + 1 * 2097152);
  unsigned short* Wq14   = U16(oW4 + 2 * 2097152);
  unsigned short* Wq24   = U16(oW4 + 3 * 2097152);
  unsigned short* Wsg4   = U16(oW4 + 4 * 2097152);
  unsigned short* Wrg4   = U16(oW4 + 5 * 2097152);
  unsigned short* Wo4    = U16(oW4 + 6 * 2097152);
  float*          accA   = F32(oW4);              // W slots 0-3, dead after projections
  float*          accB   = F32(oQ1hi);            // Q1 pair, dead after stage-2 partial
  float*          mlP    = F32(oMl);
  unsigned short* sout_p = U16(oApair);           // Apair dead after projections
  unsigned short* rout_p = U16(oQ2hi);            // Q2 pair dead after stage-3 partial
  unsigned short* attn_p = U16(oKhi);             // K pair dead after stage-3 partial
  float*          tsum   = F32(oQ1hi);            // accB dead after stage-3 merge

  const dim3 blk(256);

  // ---- precision splits
  split_a_kernel<<<8192, blk, 0, stream>>>(reg_x, Apair);
  split_w_kernel<<<1024, blk, 0, stream>>>(wk,  Wk4);
  split_w_kernel<<<1024, blk, 0, stream>>>(wv,  Wv4);
  split_w_kernel<<<1024, blk, 0, stream>>>(wq1, Wq14);
  split_w_kernel<<<1024, blk, 0, stream>>>(wq2, Wq24);
  split_w_kernel<<<1024, blk, 0, stream>>>(sgw, Wsg4);
  split_w_kernel<<<1024, blk, 0, stream>>>(rgw, Wrg4);
  split_w_kernel<<<1024, blk, 0, stream>>>(wo,  Wo4);
  gather_split_kernel<<<512, blk, 0, stream>>>(table, ids, U16(oSQhi), U16(oSQlo));

  // ---- 4 projections in one launch (blockIdx.z selects weight/output)
  GemmOuts4 proj;
  proj.o[0].W = Wk4;  proj.o[0].bias = bk;  proj.o[0].scale = 1.0f;   proj.o[0].Cf = nullptr;
  proj.o[0].hi = U16(oKhi);  proj.o[0].lo = U16(oKlo);  proj.o[0].mode = 1; proj.o[0].accum = 0;
  proj.o[1].W = Wv4;  proj.o[1].bias = bv;  proj.o[1].scale = 1.0f;   proj.o[1].Cf = nullptr;
  proj.o[1].hi = U16(oVtHi); proj.o[1].lo = U16(oVtLo); proj.o[1].mode = 2; proj.o[1].accum = 0;
  proj.o[2].W = Wq14; proj.o[2].bias = bq1; proj.o[2].scale = SCALE_; proj.o[2].Cf = nullptr;
  proj.o[2].hi = U16(oQ1hi); proj.o[2].lo = U16(oQ1lo); proj.o[2].mode = 1; proj.o[2].accum = 0;
  proj.o[3].W = Wq24; proj.o[3].bias = bq2; proj.o[3].scale = SCALE_; proj.o[3].Cf = nullptr;
  proj.o[3].hi = U16(oQ2hi); proj.o[3].lo = U16(oQ2lo); proj.o[3].mode = 1; proj.o[3].accum = 0;
  gemm_split_kernel<<<dim3(32, 8, 4), blk, 0, stream>>>(Apair, 1024, 2048, proj);

  // ---- stage 1: sum_q attends to reg tokens. KV=2048 split into 16 chunks.
  flash_partial_kernel<<<dim3(2, 16, 16), blk, 0, stream>>>(
      U16(oSQhi), U16(oSQlo), U16(oKhi), U16(oKlo), U16(oVtHi), U16(oVtLo),
      S_, R_, 128, 16, accA, accA, mlP);
  merge_x2_kernel<<<512, blk, 0, stream>>>(accA, mlP,
      U16(oX2hi), U16(oX2lo), U16(oX2Thi), U16(oX2Tlo));

  // ---- stage 2: reg queries attend to summaries (KV=128, 1 chunk)
  flash_partial_kernel<<<dim3(32, 16, 1), blk, 0, stream>>>(
      U16(oQ1hi), U16(oQ1lo), U16(oX2hi), U16(oX2lo), U16(oX2Thi), U16(oX2Tlo),
      R_, S_, 128, 1, accA, accA, mlP);
  merge_rows_kernel<<<8192, blk, 0, stream>>>(accA, accA, mlP, R_, 11, 1, sout_p);

  // ---- stage 3: regular self-attention. KV=2048 split into 2 chunks.
  flash_partial_kernel<<<dim3(32, 16, 2), blk, 0, stream>>>(
      U16(oQ2hi), U16(oQ2lo), U16(oKhi), U16(oKlo), U16(oVtHi), U16(oVtLo),
      R_, R_, 1024, 1, accA, accB, mlP);
  merge_rows_kernel<<<8192, blk, 0, stream>>>(accA, accB, mlP, R_, 11, 2, rout_p);

  // ---- gate GEMMs: tsum = sout*sgw^T + rout*rgw^T
  GemmOuts4 g1;
  g1.o[0].W = Wsg4; g1.o[0].bias = nullptr; g1.o[0].scale = 1.0f; g1.o[0].Cf = tsum;
  g1.o[0].hi = nullptr; g1.o[0].lo = nullptr; g1.o[0].mode = 0; g1.o[0].accum = 0;
  g1.o[1] = g1.o[0]; g1.o[2] = g1.o[0]; g1.o[3] = g1.o[0];
  gemm_split_kernel<<<dim3(32, 8, 1), blk, 0, stream>>>(sout_p, 1024, 2048, g1);
  GemmOuts4 g2;
  g2.o[0].W = Wrg4; g2.o[0].bias = nullptr; g2.o[0].scale = 1.0f; g2.o[0].Cf = tsum;
  g2.o[0].hi = nullptr; g2.o[0].lo = nullptr; g2.o[0].mode = 0; g2.o[0].accum = 1;
  g2.o[1] = g2.o[0]; g2.o[2] = g2.o[0]; g2.o[3] = g2.o[0];
  gemm_split_kernel<<<dim3(32, 8, 1), blk, 0, stream>>>(rout_p, 1024, 2048, g2);

  // ---- gated blend -> attn pair
  blend_kernel<<<8192, blk, 0, stream>>>(tsum, gb, sout_p, rout_p, attn_p);

  // ---- output projection -> d_out
  GemmOuts4 gf;
  gf.o[0].W = Wo4; gf.o[0].bias = bo; gf.o[0].scale = 1.0f; gf.o[0].Cf = out;
  gf.o[0].hi = nullptr; gf.o[0].lo = nullptr; gf.o[0].mode = 0; gf.o[0].accum = 0;
  gf.o[1] = gf.o[0]; gf.o[2] = gf.o[0]; gf.o[3] = gf.o[0];
  gemm_split_kernel<<<dim3(32, 8, 1), blk, 0, stream>>>(attn_p, 1024, 2048, gf);
}

// Round 4
// 306.330 us; speedup vs baseline: 4.5634x; 1.2942x over previous
//
#include <hip/hip_runtime.h>
#include <cstdint>
#include <cstddef>

// Problem constants (fixed by setup_inputs)
constexpr int R_ = 2048;   // reg_len
constexpr int B_ = 2;      // batch
constexpr int S_ = 128;    // sum_len
constexpr int E_ = 512;    // embed dim
constexpr int H_ = 8;      // heads
constexpr int D_ = 64;     // head dim
constexpr int N_ = R_ * B_;            // 4096 token rows
constexpr float SCALE_ = 0.125f;       // D^-0.5

typedef short bf8_t __attribute__((ext_vector_type(8)));   // 8 bf16 in 4 VGPRs
typedef float f32x4 __attribute__((ext_vector_type(4)));

#define MFMA16(a, b, c) __builtin_amdgcn_mfma_f32_16x16x32_bf16((a), (b), (c), 0, 0, 0)

__device__ __forceinline__ unsigned short f2bf(float f) {
  unsigned u = __builtin_bit_cast(unsigned, f);
  unsigned r = u + 0x7FFFu + ((u >> 16) & 1u);   // RNE
  return (unsigned short)(r >> 16);
}
__device__ __forceinline__ float bf2f(unsigned short h) {
  unsigned u = ((unsigned)h) << 16;
  return __builtin_bit_cast(float, u);
}

// ---------------------------------------------------------------------------
// Fused weight splits: 7 x (src fp32 [512][512] -> bf16 [512][2048] hi|hi|lo|lo)
// ---------------------------------------------------------------------------
struct WSplitJob { const float* src; unsigned short* dst; };
struct WSplit7 { WSplitJob j[7]; };

__global__ __launch_bounds__(256)
void split_w7_kernel(WSplit7 P)
{
  const WSplitJob jb = P.j[blockIdx.y];
  const int idx = blockIdx.x * 256 + threadIdx.x;   // < 512*512
  const int r = idx >> 9, c = idx & 511;
  const float v = jb.src[idx];
  const unsigned short hi = f2bf(v);
  const unsigned short lo = f2bf(v - bf2f(hi));
  unsigned short* d = jb.dst + ((size_t)r << 11) + c;
  d[0] = hi; d[512] = hi; d[1024] = lo; d[1536] = lo;
}

// ---------------------------------------------------------------------------
// A split: src fp32 [4096][512] -> dst bf16 [4096][1024] laid out (hi|lo)
// ---------------------------------------------------------------------------
__global__ __launch_bounds__(256)
void split_a_kernel(const float* __restrict__ src, unsigned short* __restrict__ dst)
{
  const int idx = blockIdx.x * 256 + threadIdx.x;   // < 4096*512
  const int r = idx >> 9, c = idx & 511;
  const float v = src[idx];
  const unsigned short hi = f2bf(v);
  unsigned short* d = dst + ((size_t)r << 10) + c;
  d[0] = hi; d[512] = f2bf(v - bf2f(hi));
}

// ---------------------------------------------------------------------------
// Summary-query gather + split: qhi/qlo [bh][S][64], scale folded
// ---------------------------------------------------------------------------
__global__ __launch_bounds__(256)
void gather_split_kernel(const float* __restrict__ table, const int* __restrict__ ids,
                         unsigned short* __restrict__ qhi, unsigned short* __restrict__ qlo)
{
  const int idx = blockIdx.x * 256 + threadIdx.x;   // < B*H*S*D = 131072
  const int d = idx & 63;
  const int s = (idx >> 6) & 127;
  const int h = (idx >> 13) & 7;
  const int b = idx >> 16;
  const float v = table[(size_t)ids[b * S_ + s] * E_ + h * 64 + d] * SCALE_;
  const unsigned short hi = f2bf(v);
  qhi[idx] = hi;
  qlo[idx] = f2bf(v - bf2f(hi));
}

// ---------------------------------------------------------------------------
// Split-precision MFMA GEMM (T14 reg-prefetch staging).
// A: bf16 [M][Ka] (hi|lo pair, Ka=1024); logical K = Keff (2048), A col wraps
// mod Ka. W: bf16 [512][Keff] (hi|hi|lo|lo).
// Tile 128x64, 256 threads (4 waves, each 32 rows x 64 cols).
// mode 0: Cf[row*512+col] (+bias)(+accum)
// mode 1: hi/lo pair -> [bh][row>>1][col&63] row-major attn layout
// mode 2: hi/lo pair -> [bh][col&63][row>>1] transposed attn layout (for V)
// ---------------------------------------------------------------------------
struct GemmOut {
  const unsigned short* W;
  const float* bias;
  float scale;
  float* Cf;
  unsigned short* hi;
  unsigned short* lo;
  int mode;
  int accum;
};
struct GemmOuts4 { GemmOut o[4]; };

__global__ __launch_bounds__(256, 4)
void gemm_split_kernel(const unsigned short* __restrict__ A, int Ka, int Keff, GemmOuts4 P)
{
  const GemmOut g = P.o[blockIdx.z];
  __shared__ unsigned short As[128][48];
  __shared__ unsigned short Ws[64][48];

  const int tid = threadIdx.x;
  const int w = tid >> 6;          // wave 0..3
  const int l = tid & 63;
  const int lr = l & 15;
  const int lg = l >> 4;
  const int n0 = blockIdx.x * 128;
  const int o0 = blockIdx.y * 64;

  f32x4 acc[2][4];
#pragma unroll
  for (int m = 0; m < 2; ++m)
#pragma unroll
    for (int n = 0; n < 4; ++n) acc[m][n] = (f32x4){0.f, 0.f, 0.f, 0.f};

  const int ar = tid >> 1;          // 0..127
  const int ac = (tid & 1) * 16;
  const int wr = tid >> 2;          // 0..63
  const int wc = (tid & 3) * 8;

  // prefetch first K-step
  bf8_t ra0 = *(const bf8_t*)(A + (size_t)(n0 + ar) * Ka + ac);
  bf8_t ra1 = *(const bf8_t*)(A + (size_t)(n0 + ar) * Ka + ac + 8);
  bf8_t rw0 = *(const bf8_t*)(g.W + (size_t)(o0 + wr) * Keff + wc);

  for (int k0 = 0; k0 < Keff; k0 += 32) {
    __syncthreads();   // prior tile's readers done
    *(bf8_t*)&As[ar][ac] = ra0;
    *(bf8_t*)&As[ar][ac + 8] = ra1;
    *(bf8_t*)&Ws[wr][wc] = rw0;
    __syncthreads();
    if (k0 + 32 < Keff) {   // issue next-tile loads early; hide under MFMA
      const int ak = (k0 + 32) & (Ka - 1);
      ra0 = *(const bf8_t*)(A + (size_t)(n0 + ar) * Ka + ak + ac);
      ra1 = *(const bf8_t*)(A + (size_t)(n0 + ar) * Ka + ak + ac + 8);
      rw0 = *(const bf8_t*)(g.W + (size_t)(o0 + wr) * Keff + k0 + 32 + wc);
    }

    bf8_t bvs[4];
#pragma unroll
    for (int n = 0; n < 4; ++n)
      bvs[n] = *(const bf8_t*)&Ws[n * 16 + lr][lg * 8];
#pragma unroll
    for (int m = 0; m < 2; ++m) {
      bf8_t av = *(const bf8_t*)&As[w * 32 + m * 16 + lr][lg * 8];
#pragma unroll
      for (int n = 0; n < 4; ++n)
        acc[m][n] = MFMA16(av, bvs[n], acc[m][n]);
    }
  }

#pragma unroll
  for (int m = 0; m < 2; ++m)
#pragma unroll
    for (int n = 0; n < 4; ++n)
#pragma unroll
      for (int r = 0; r < 4; ++r) {
        const int row = n0 + w * 32 + m * 16 + lg * 4 + r;
        const int col = o0 + n * 16 + lr;
        float v = acc[m][n][r];
        if (g.bias) v += g.bias[col];
        v *= g.scale;
        if (g.mode == 0) {
          const size_t id = ((size_t)row << 9) + col;
          if (g.accum) v += g.Cf[id];
          g.Cf[id] = v;
        } else {
          const int bb = row & 1, rr = row >> 1;
          const int hh = col >> 6, dd = col & 63;
          size_t id;
          if (g.mode == 1) id = (((size_t)(bb * H_ + hh) * R_) + rr) * 64 + dd;
          else             id = (((size_t)(bb * H_ + hh) * 64) + dd) * R_ + rr;
          const unsigned short hv = f2bf(v);
          g.hi[id] = hv;
          g.lo[id] = f2bf(v - bf2f(hv));
        }
      }
}

// ---------------------------------------------------------------------------
// Split-precision MFMA flash attention, PARTIAL over a KV chunk.
// SWAPPED QK^T: computes mfma(K, Q) so each lane owns one q-row's scores
// (q = lane&15) -> softmax reduce is 2 shfl_xor instead of 8/row.
// Q/K: hi/lo [bh][len][64]; V: hi/lo TRANSPOSED [bh][64][kv_len]; Q pre-scaled.
// Block: 64 q-rows, 256 threads (4 waves x 16 q-rows). KV tiles of 32.
// T14: next tile's global loads issued before compute, LDS-written next iter.
// Writes unnormalized acc (fp32) + (m,l) per row.
// ---------------------------------------------------------------------------
__global__ __launch_bounds__(256, 4)
void flash_partial_kernel(const unsigned short* __restrict__ Qhi, const unsigned short* __restrict__ Qlo,
                          const unsigned short* __restrict__ Khi, const unsigned short* __restrict__ Klo,
                          const unsigned short* __restrict__ VtHi, const unsigned short* __restrict__ VtLo,
                          int q_len, int kv_len, int chunk, int zsplit,
                          float* __restrict__ accA, float* __restrict__ accB,
                          float* __restrict__ mlP)
{
  __shared__ unsigned short KsH[32][72];
  __shared__ unsigned short KsL[32][72];
  __shared__ unsigned short VsH[64][40];
  __shared__ unsigned short VsL[64][40];
  __shared__ unsigned short PsH[4][16][40];
  __shared__ unsigned short PsL[4][16][40];

  const int tid = threadIdx.x;
  const int w = tid >> 6;
  const int l = tid & 63;
  const int lr = l & 15;
  const int lg = l >> 4;
  const int bh = blockIdx.y;
  const int q0 = blockIdx.x * 64;
  const int c = blockIdx.z;
  const int kvbeg = c * chunk;
  const int kvend = kvbeg + chunk;

  // Q fragments (q = q0 + w*16 + lr), used as MFMA B-operand
  bf8_t qh[2], ql[2];
  {
    const size_t qbase = ((size_t)bh * q_len + (q0 + w * 16 + lr)) * 64;
#pragma unroll
    for (int kd = 0; kd < 2; ++kd) {
      qh[kd] = *(const bf8_t*)(Qhi + qbase + kd * 32 + lg * 8);
      ql[kd] = *(const bf8_t*)(Qlo + qbase + kd * 32 + lg * 8);
    }
  }

  f32x4 acc[4];
#pragma unroll
  for (int nd = 0; nd < 4; ++nd) acc[nd] = (f32x4){0.f, 0.f, 0.f, 0.f};
  float mrow = -INFINITY;   // per-lane state for q = q0 + w*16 + lr
  float lrow = 0.0f;

  const int sr = tid >> 3;            // K staging row 0..31
  const int sc = (tid & 7) * 8;       // K staging col
  const int vd = tid >> 2;            // V^T staging d-row 0..63
  const int vc = (tid & 3) * 8;       // V^T staging kv-col

  // prefetch first tile into regs (T14)
  bf8_t rkh, rkl, rvh, rvl;
  {
    const size_t kb = ((size_t)bh * kv_len + kvbeg + sr) * 64 + sc;
    rkh = *(const bf8_t*)(Khi + kb);
    rkl = *(const bf8_t*)(Klo + kb);
    const size_t vb = ((size_t)bh * 64 + vd) * kv_len + kvbeg + vc;
    rvh = *(const bf8_t*)(VtHi + vb);
    rvl = *(const bf8_t*)(VtLo + vb);
  }

  for (int kv0 = kvbeg; kv0 < kvend; kv0 += 32) {
    __syncthreads();                  // prior tile's readers done
    *(bf8_t*)&KsH[sr][sc] = rkh;
    *(bf8_t*)&KsL[sr][sc] = rkl;
    *(bf8_t*)&VsH[vd][vc] = rvh;
    *(bf8_t*)&VsL[vd][vc] = rvl;
    __syncthreads();
    if (kv0 + 32 < kvend) {           // issue next-tile loads; hide under compute
      const size_t kb = ((size_t)bh * kv_len + kv0 + 32 + sr) * 64 + sc;
      rkh = *(const bf8_t*)(Khi + kb);
      rkl = *(const bf8_t*)(Klo + kb);
      const size_t vb = ((size_t)bh * 64 + vd) * kv_len + kv0 + 32 + vc;
      rvh = *(const bf8_t*)(VtHi + vb);
      rvl = *(const bf8_t*)(VtLo + vb);
    }

    // ---- QK^T swapped (12 MFMAs): s[n][r] = S[kv = n*16+lg*4+r][q = lr]
    f32x4 s[2];
    s[0] = (f32x4){0.f, 0.f, 0.f, 0.f};
    s[1] = (f32x4){0.f, 0.f, 0.f, 0.f};
#pragma unroll
    for (int kd = 0; kd < 2; ++kd) {
#pragma unroll
      for (int n = 0; n < 2; ++n) {
        bf8_t kfh = *(const bf8_t*)&KsH[n * 16 + lr][kd * 32 + lg * 8];
        bf8_t kfl = *(const bf8_t*)&KsL[n * 16 + lr][kd * 32 + lg * 8];
        s[n] = MFMA16(kfh, qh[kd], s[n]);
        s[n] = MFMA16(kfh, ql[kd], s[n]);
        s[n] = MFMA16(kfl, qh[kd], s[n]);
      }
    }

    // ---- online softmax: lane owns q = lr; reduce across lg via 2 shuffles
    float mx = fmaxf(fmaxf(fmaxf(s[0][0], s[0][1]), fmaxf(s[0][2], s[0][3])),
                     fmaxf(fmaxf(s[1][0], s[1][1]), fmaxf(s[1][2], s[1][3])));
    mx = fmaxf(mx, __shfl_xor(mx, 16));
    mx = fmaxf(mx, __shfl_xor(mx, 32));
    const float m2 = fmaxf(mrow, mx);
    const float f = __expf(mrow - m2);   // first iter: exp(-inf) = 0
    mrow = m2;
    float p0[4], p1[4];
    float ts = 0.f;
#pragma unroll
    for (int r = 0; r < 4; ++r) {
      p0[r] = __expf(s[0][r] - m2);
      p1[r] = __expf(s[1][r] - m2);
      ts += p0[r] + p1[r];
    }
    ts += __shfl_xor(ts, 16);
    ts += __shfl_xor(ts, 32);
    lrow = lrow * f + ts;

    // broadcast rescale factor to acc-row layout (q' = lg*4 + r)
    float fr[4];
#pragma unroll
    for (int r = 0; r < 4; ++r) fr[r] = __shfl(f, lg * 4 + r);
#pragma unroll
    for (int nd = 0; nd < 4; ++nd)
#pragma unroll
      for (int r = 0; r < 4; ++r) acc[nd][r] *= fr[r];

    // ---- P -> LDS: packed u32 stores, trunc-hi + RNE-lo split, wave-local
#pragma unroll
    for (int n = 0; n < 2; ++n) {
      const float pa = n ? p1[0] : p0[0];
      const float pb = n ? p1[1] : p0[1];
      const float pc = n ? p1[2] : p0[2];
      const float pd = n ? p1[3] : p0[3];
      const unsigned ua = __builtin_bit_cast(unsigned, pa);
      const unsigned ub = __builtin_bit_cast(unsigned, pb);
      const unsigned uc = __builtin_bit_cast(unsigned, pc);
      const unsigned ud = __builtin_bit_cast(unsigned, pd);
      const unsigned h01 = (ua >> 16) | (ub & 0xFFFF0000u);
      const unsigned h23 = (uc >> 16) | (ud & 0xFFFF0000u);
      const float la = pa - __builtin_bit_cast(float, ua & 0xFFFF0000u);
      const float lb = pb - __builtin_bit_cast(float, ub & 0xFFFF0000u);
      const float lc = pc - __builtin_bit_cast(float, uc & 0xFFFF0000u);
      const float ld = pd - __builtin_bit_cast(float, ud & 0xFFFF0000u);
      const unsigned l01 = (unsigned)f2bf(la) | ((unsigned)f2bf(lb) << 16);
      const unsigned l23 = (unsigned)f2bf(lc) | ((unsigned)f2bf(ld) << 16);
      *(unsigned*)&PsH[w][lr][n * 16 + lg * 4]     = h01;
      *(unsigned*)&PsH[w][lr][n * 16 + lg * 4 + 2] = h23;
      *(unsigned*)&PsL[w][lr][n * 16 + lg * 4]     = l01;
      *(unsigned*)&PsL[w][lr][n * 16 + lg * 4 + 2] = l23;
    }

    // ---- PV (12 MFMAs); P is A-operand (row = q = lr), V^T is B-operand
    bf8_t pah = *(const bf8_t*)&PsH[w][lr][lg * 8];
    bf8_t pal = *(const bf8_t*)&PsL[w][lr][lg * 8];
#pragma unroll
    for (int nd = 0; nd < 4; ++nd) {
      bf8_t vfh = *(const bf8_t*)&VsH[nd * 16 + lr][lg * 8];
      bf8_t vfl = *(const bf8_t*)&VsL[nd * 16 + lr][lg * 8];
      acc[nd] = MFMA16(pah, vfh, acc[nd]);
      acc[nd] = MFMA16(pal, vfh, acc[nd]);
      acc[nd] = MFMA16(pah, vfl, acc[nd]);
    }
  }

  // ---- store partials (unnormalized; acc row q = q0 + w*16 + lg*4 + r)
  const size_t cstride = (size_t)16 * q_len * 64;
  float* accbase = (c < zsplit) ? accA + (size_t)c * cstride
                                : accB + (size_t)(c - zsplit) * cstride;
#pragma unroll
  for (int nd = 0; nd < 4; ++nd)
#pragma unroll
    for (int r = 0; r < 4; ++r) {
      const int q = q0 + w * 16 + lg * 4 + r;
      accbase[((size_t)bh * q_len + q) * 64 + nd * 16 + lr] = acc[nd][r];
    }
  if (l < 16) {
    const int q = q0 + w * 16 + l;
    *(float2*)&mlP[((size_t)(c * 16 + bh) * q_len + q) * 2] = make_float2(mrow, lrow);
  }
}

// ---------------------------------------------------------------------------
// Merge stage-1 partials -> X2 (row-major pair) and X2^T (pair)
// acc: [16 chunks][bh][128][64]; ml: [(c*16+bh)*128+q]*2
// ---------------------------------------------------------------------------
__global__ __launch_bounds__(256)
void merge_x2_kernel(const float* __restrict__ acc, const float* __restrict__ ml,
                     unsigned short* __restrict__ X2hi, unsigned short* __restrict__ X2lo,
                     unsigned short* __restrict__ X2Thi, unsigned short* __restrict__ X2Tlo)
{
  const int idx = blockIdx.x * 256 + threadIdx.x;   // < 16*128*64
  const int d = idx & 63;
  const int q = (idx >> 6) & 127;
  const int bh = idx >> 13;
  float M = -INFINITY;
#pragma unroll
  for (int c = 0; c < 16; ++c)
    M = fmaxf(M, ml[((size_t)(c * 16 + bh) * 128 + q) * 2]);
  float ls = 0.f, o = 0.f;
#pragma unroll
  for (int c = 0; c < 16; ++c) {
    const size_t mi = ((size_t)(c * 16 + bh) * 128 + q) * 2;
    const float wgt = __expf(ml[mi] - M);
    ls += wgt * ml[mi + 1];
    o += wgt * acc[(size_t)c * 131072 + ((size_t)bh * 128 + q) * 64 + d];
  }
  const float v = o / ls;
  const unsigned short hv = f2bf(v);
  const unsigned short lv = f2bf(v - bf2f(hv));
  X2hi[((size_t)bh * 128 + q) * 64 + d] = hv;
  X2lo[((size_t)bh * 128 + q) * 64 + d] = lv;
  X2Thi[((size_t)bh * 64 + d) * 128 + q] = hv;
  X2Tlo[((size_t)bh * 64 + d) * 128 + q] = lv;
}

// ---------------------------------------------------------------------------
// Merge stage-2/3 partials -> packed pair rows [q*B+b][1024] (hi | lo at +512)
// ---------------------------------------------------------------------------
__global__ __launch_bounds__(256)
void merge_rows_kernel(const float* __restrict__ accA, const float* __restrict__ accB,
                       const float* __restrict__ ml, int q_len, int qbits, int nc,
                       unsigned short* __restrict__ OutP)
{
  const int idx = blockIdx.x * 256 + threadIdx.x;   // < 16*q_len*64
  const int d = idx & 63;
  const int q = (idx >> 6) & (q_len - 1);
  const int bh = idx >> (6 + qbits);
  float M = -INFINITY;
  for (int c = 0; c < nc; ++c)
    M = fmaxf(M, ml[((size_t)(c * 16 + bh) * q_len + q) * 2]);
  float ls = 0.f, o = 0.f;
  const size_t aoff = ((size_t)bh * q_len + q) * 64 + d;
  for (int c = 0; c < nc; ++c) {
    const size_t mi = ((size_t)(c * 16 + bh) * q_len + q) * 2;
    const float wgt = __expf(ml[mi] - M);
    ls += wgt * ml[mi + 1];
    const float* a = (c == 0) ? accA : accB;
    o += wgt * a[aoff];
  }
  const float v = o / ls;
  const int b = bh >> 3, h = bh & 7;
  const size_t nrow = (size_t)q * B_ + b;
  const int col = h * 64 + d;
  const unsigned short hv = f2bf(v);
  OutP[nrow * 1024 + col] = hv;
  OutP[nrow * 1024 + 512 + col] = f2bf(v - bf2f(hv));
}

// ---------------------------------------------------------------------------
// gate = sigmoid(tsum + gb); attn = g*so + (1-g)*ro, written as hi/lo pair
// ---------------------------------------------------------------------------
__global__ __launch_bounds__(256)
void blend_kernel(const float* __restrict__ tsum, const float* __restrict__ gb,
                  const unsigned short* __restrict__ sp, const unsigned short* __restrict__ rp,
                  unsigned short* __restrict__ ap)
{
  const int idx = blockIdx.x * 256 + threadIdx.x;   // < N*512
  const int n = idx >> 9, e = idx & 511;
  const size_t base = (size_t)n << 10;
  const float so = bf2f(sp[base + e]) + bf2f(sp[base + 512 + e]);
  const float ro = bf2f(rp[base + e]) + bf2f(rp[base + 512 + e]);
  const float x = tsum[idx] + gb[e];
  const float gt = 1.0f / (1.0f + __expf(-x));
  const float a = gt * so + (1.0f - gt) * ro;
  const unsigned short hv = f2bf(a);
  ap[base + e] = hv;
  ap[base + 512 + e] = f2bf(a - bf2f(hv));
}

// ---------------------------------------------------------------------------
extern "C" void kernel_launch(void* const* d_in, const int* in_sizes, int n_in,
                              void* d_out, int out_size, void* d_ws, size_t ws_size,
                              hipStream_t stream)
{
  const float* reg_x = (const float*)d_in[0];
  const int*   ids   = (const int*)d_in[1];
  const float* table = (const float*)d_in[4];
  const float* wq1 = (const float*)d_in[5];  const float* bq1 = (const float*)d_in[6];
  const float* wq2 = (const float*)d_in[7];  const float* bq2 = (const float*)d_in[8];
  const float* wk  = (const float*)d_in[9];  const float* bk  = (const float*)d_in[10];
  const float* wv  = (const float*)d_in[11]; const float* bv  = (const float*)d_in[12];
  const float* wo  = (const float*)d_in[13]; const float* bo  = (const float*)d_in[14];
  const float* sgw = (const float*)d_in[15];
  const float* rgw = (const float*)d_in[16];
  const float* gb  = (const float*)d_in[17];
  float* out = (float*)d_out;
  char* W = (char*)d_ws;

  // ---- workspace layout (bytes), total 58,720,256 (< 66,060,288 proven-safe)
  const size_t oApair = 0;                        //  8,388,608 [reuse: sout_p]
  const size_t oW4    = 8388608;                  //  7 x 2,097,152
                                                  //  slots 0-3 [reuse: accP_A 8,388,608]
  const size_t oKhi   = oW4 + 7 * 2097152;        // 23,068,672 [reuse: attn_p over Khi+Klo]
  const size_t oKlo   = oKhi + 4194304;
  const size_t oVtHi  = oKlo + 4194304;           // 31,457,280
  const size_t oVtLo  = oVtHi + 4194304;
  const size_t oQ1hi  = oVtLo + 4194304;          // 39,845,888 [reuse: accP_B, then tsum]
  const size_t oQ1lo  = oQ1hi + 4194304;
  const size_t oQ2hi  = oQ1lo + 4194304;          // 48,234,496 [reuse: rout_p over Q2hi+Q2lo]
  const size_t oQ2lo  = oQ2hi + 4194304;
  const size_t oSQhi  = oQ2lo + 4194304;          // 56,623,104
  const size_t oSQlo  = oSQhi + 262144;
  const size_t oX2hi  = oSQlo + 262144;           // 57,147,392
  const size_t oX2lo  = oX2hi + 262144;
  const size_t oX2Thi = oX2lo + 262144;           // 57,671,680
  const size_t oX2Tlo = oX2Thi + 262144;
  const size_t oMl    = oX2Tlo + 262144;          // 58,195,968 (+524,288 = 58,720,256)

  auto U16 = [&](size_t off) { return (unsigned short*)(W + off); };
  auto F32 = [&](size_t off) { return (float*)(W + off); };
  unsigned short* Apair  = U16(oApair);
  unsigned short* Wk4    = U16(oW4 + 0 * 2097152);
  unsigned short* Wv4    = U16(oW4 + 1 * 2097152);
  unsigned short* Wq14   = U16(oW4 + 2 * 2097152);
  unsigned short* Wq24   = U16(oW4 + 3 * 2097152);
  unsigned short* Wsg4   = U16(oW4 + 4 * 2097152);
  unsigned short* Wrg4   = U16(oW4 + 5 * 2097152);
  unsigned short* Wo4    = U16(oW4 + 6 * 2097152);
  float*          accA   = F32(oW4);              // W slots 0-3, dead after projections
  float*          accB   = F32(oQ1hi);            // Q1 pair, dead after stage-2 partial
  float*          mlP    = F32(oMl);
  unsigned short* sout_p = U16(oApair);           // Apair dead after projections
  unsigned short* rout_p = U16(oQ2hi);            // Q2 pair dead after stage-3 partial
  unsigned short* attn_p = U16(oKhi);             // K pair dead after stage-3 partial
  float*          tsum   = F32(oQ1hi);            // accB dead after stage-3 merge

  const dim3 blk(256);

  // ---- precision splits (weights fused into one launch)
  split_a_kernel<<<8192, blk, 0, stream>>>(reg_x, Apair);
  WSplit7 ws7;
  ws7.j[0] = WSplitJob{wk,  Wk4};
  ws7.j[1] = WSplitJob{wv,  Wv4};
  ws7.j[2] = WSplitJob{wq1, Wq14};
  ws7.j[3] = WSplitJob{wq2, Wq24};
  ws7.j[4] = WSplitJob{sgw, Wsg4};
  ws7.j[5] = WSplitJob{rgw, Wrg4};
  ws7.j[6] = WSplitJob{wo,  Wo4};
  split_w7_kernel<<<dim3(1024, 7), blk, 0, stream>>>(ws7);
  gather_split_kernel<<<512, blk, 0, stream>>>(table, ids, U16(oSQhi), U16(oSQlo));

  // ---- 4 projections in one launch (blockIdx.z selects weight/output)
  GemmOuts4 proj;
  proj.o[0].W = Wk4;  proj.o[0].bias = bk;  proj.o[0].scale = 1.0f;   proj.o[0].Cf = nullptr;
  proj.o[0].hi = U16(oKhi);  proj.o[0].lo = U16(oKlo);  proj.o[0].mode = 1; proj.o[0].accum = 0;
  proj.o[1].W = Wv4;  proj.o[1].bias = bv;  proj.o[1].scale = 1.0f;   proj.o[1].Cf = nullptr;
  proj.o[1].hi = U16(oVtHi); proj.o[1].lo = U16(oVtLo); proj.o[1].mode = 2; proj.o[1].accum = 0;
  proj.o[2].W = Wq14; proj.o[2].bias = bq1; proj.o[2].scale = SCALE_; proj.o[2].Cf = nullptr;
  proj.o[2].hi = U16(oQ1hi); proj.o[2].lo = U16(oQ1lo); proj.o[2].mode = 1; proj.o[2].accum = 0;
  proj.o[3].W = Wq24; proj.o[3].bias = bq2; proj.o[3].scale = SCALE_; proj.o[3].Cf = nullptr;
  proj.o[3].hi = U16(oQ2hi); proj.o[3].lo = U16(oQ2lo); proj.o[3].mode = 1; proj.o[3].accum = 0;
  gemm_split_kernel<<<dim3(32, 8, 4), blk, 0, stream>>>(Apair, 1024, 2048, proj);

  // ---- stage 1: sum_q attends to reg tokens. KV=2048 split into 16 chunks.
  flash_partial_kernel<<<dim3(2, 16, 16), blk, 0, stream>>>(
      U16(oSQhi), U16(oSQlo), U16(oKhi), U16(oKlo), U16(oVtHi), U16(oVtLo),
      S_, R_, 128, 16, accA, accA, mlP);
  merge_x2_kernel<<<512, blk, 0, stream>>>(accA, mlP,
      U16(oX2hi), U16(oX2lo), U16(oX2Thi), U16(oX2Tlo));

  // ---- stage 2: reg queries attend to summaries (KV=128, 1 chunk)
  flash_partial_kernel<<<dim3(32, 16, 1), blk, 0, stream>>>(
      U16(oQ1hi), U16(oQ1lo), U16(oX2hi), U16(oX2lo), U16(oX2Thi), U16(oX2Tlo),
      R_, S_, 128, 1, accA, accA, mlP);
  merge_rows_kernel<<<8192, blk, 0, stream>>>(accA, accA, mlP, R_, 11, 1, sout_p);

  // ---- stage 3: regular self-attention. KV=2048 split into 2 chunks.
  flash_partial_kernel<<<dim3(32, 16, 2), blk, 0, stream>>>(
      U16(oQ2hi), U16(oQ2lo), U16(oKhi), U16(oKlo), U16(oVtHi), U16(oVtLo),
      R_, R_, 1024, 1, accA, accB, mlP);
  merge_rows_kernel<<<8192, blk, 0, stream>>>(accA, accB, mlP, R_, 11, 2, rout_p);

  // ---- gate GEMMs: tsum = sout*sgw^T + rout*rgw^T
  GemmOuts4 g1;
  g1.o[0].W = Wsg4; g1.o[0].bias = nullptr; g1.o[0].scale = 1.0f; g1.o[0].Cf = tsum;
  g1.o[0].hi = nullptr; g1.o[0].lo = nullptr; g1.o[0].mode = 0; g1.o[0].accum = 0;
  g1.o[1] = g1.o[0]; g1.o[2] = g1.o[0]; g1.o[3] = g1.o[0];
  gemm_split_kernel<<<dim3(32, 8, 1), blk, 0, stream>>>(sout_p, 1024, 2048, g1);
  GemmOuts4 g2;
  g2.o[0].W = Wrg4; g2.o[0].bias = nullptr; g2.o[0].scale = 1.0f; g2.o[0].Cf = tsum;
  g2.o[0].hi = nullptr; g2.o[0].lo = nullptr; g2.o[0].mode = 0; g2.o[0].accum = 1;
  g2.o[1] = g2.o[0]; g2.o[2] = g2.o[0]; g2.o[3] = g2.o[0];
  gemm_split_kernel<<<dim3(32, 8, 1), blk, 0, stream>>>(rout_p, 1024, 2048, g2);

  // ---- gated blend -> attn pair
  blend_kernel<<<8192, blk, 0, stream>>>(tsum, gb, sout_p, rout_p, attn_p);

  // ---- output projection -> d_out
  GemmOuts4 gf;
  gf.o[0].W = Wo4; gf.o[0].bias = bo; gf.o[0].scale = 1.0f; gf.o[0].Cf = out;
  gf.o[0].hi = nullptr; gf.o[0].lo = nullptr; gf.o[0].mode = 0; gf.o[0].accum = 0;
  gf.o[1] = gf.o[0]; gf.o[2] = gf.o[0]; gf.o[3] = gf.o[0];
  gemm_split_kernel<<<dim3(32, 8, 1), blk, 0, stream>>>(attn_p, 1024, 2048, gf);
}

// Round 5
// 268.641 us; speedup vs baseline: 5.2036x; 1.1403x over previous
//
#include <hip/hip_runtime.h>
#include <cstdint>
#include <cstddef>

// Problem constants (fixed by setup_inputs)
constexpr int R_ = 2048;   // reg_len
constexpr int B_ = 2;      // batch
constexpr int S_ = 128;    // sum_len
constexpr int E_ = 512;    // embed dim
constexpr int H_ = 8;      // heads
constexpr int D_ = 64;     // head dim
constexpr int N_ = R_ * B_;            // 4096 token rows
constexpr float SCALE_ = 0.125f;       // D^-0.5

typedef short bf8_t __attribute__((ext_vector_type(8)));   // 8 bf16 in 4 VGPRs
typedef short bf4_t __attribute__((ext_vector_type(4)));   // 4 bf16 in 2 VGPRs
typedef float f32x4 __attribute__((ext_vector_type(4)));

#define MFMA16(a, b, c) __builtin_amdgcn_mfma_f32_16x16x32_bf16((a), (b), (c), 0, 0, 0)

__device__ __forceinline__ unsigned short f2bf(float f) {
  unsigned u = __builtin_bit_cast(unsigned, f);
  unsigned r = u + 0x7FFFu + ((u >> 16) & 1u);   // RNE
  return (unsigned short)(r >> 16);
}
__device__ __forceinline__ float bf2f(unsigned short h) {
  unsigned u = ((unsigned)h) << 16;
  return __builtin_bit_cast(float, u);
}

// ---------------------------------------------------------------------------
// Fused weight splits: 7 x (src fp32 [512][512] -> bf16 [512][1536] hi|hi|lo)
// (logical K=1536: terms Ahi*Whi, Alo*Whi, Ahi*Wlo; lo*lo dropped, <=2^-18 rel)
// ---------------------------------------------------------------------------
struct WSplitJob { const float* src; unsigned short* dst; };
struct WSplit7 { WSplitJob j[7]; };

__global__ __launch_bounds__(256)
void split_w7_kernel(WSplit7 P)
{
  const WSplitJob jb = P.j[blockIdx.y];
  const int idx = blockIdx.x * 256 + threadIdx.x;   // < 512*512
  const int r = idx >> 9, c = idx & 511;
  const float v = jb.src[idx];
  const unsigned short hi = f2bf(v);
  const unsigned short lo = f2bf(v - bf2f(hi));
  unsigned short* d = jb.dst + (size_t)r * 1536 + c;
  d[0] = hi; d[512] = hi; d[1024] = lo;
}

// ---------------------------------------------------------------------------
// A split: src fp32 [4096][512] -> dst bf16 [4096][1024] laid out (hi|lo)
// ---------------------------------------------------------------------------
__global__ __launch_bounds__(256)
void split_a_kernel(const float* __restrict__ src, unsigned short* __restrict__ dst)
{
  const int idx = blockIdx.x * 256 + threadIdx.x;   // < 4096*512
  const int r = idx >> 9, c = idx & 511;
  const float v = src[idx];
  const unsigned short hi = f2bf(v);
  unsigned short* d = dst + ((size_t)r << 10) + c;
  d[0] = hi; d[512] = f2bf(v - bf2f(hi));
}

// ---------------------------------------------------------------------------
// Summary-query gather + split: qhi/qlo [bh][S][64], scale folded
// ---------------------------------------------------------------------------
__global__ __launch_bounds__(256)
void gather_split_kernel(const float* __restrict__ table, const int* __restrict__ ids,
                         unsigned short* __restrict__ qhi, unsigned short* __restrict__ qlo)
{
  const int idx = blockIdx.x * 256 + threadIdx.x;   // < B*H*S*D = 131072
  const int d = idx & 63;
  const int s = (idx >> 6) & 127;
  const int h = (idx >> 13) & 7;
  const int b = idx >> 16;
  const float v = table[(size_t)ids[b * S_ + s] * E_ + h * 64 + d] * SCALE_;
  const unsigned short hi = f2bf(v);
  qhi[idx] = hi;
  qlo[idx] = f2bf(v - bf2f(hi));
}

// ---------------------------------------------------------------------------
// Split-precision MFMA GEMM (T14 reg-prefetch staging).
// A: bf16 [M][1024] (hi|lo); logical K = 1536, A col wraps mod 1024
// (k 0..511: hi, 512..1023: lo, 1024..1535: hi). W: bf16 [512][1536] hi|hi|lo.
// Tile 128x64, 256 threads (4 waves, each 32 rows x 64 cols).
// mode 0: Cf[row*512+col] (+bias)
// mode 1: hi/lo pair -> [bh][row>>1][col&63] row-major attn layout
// mode 2: hi/lo pair -> [bh][col&63][row>>1] transposed attn layout (for V)
// ---------------------------------------------------------------------------
struct GemmOut {
  const unsigned short* W;
  const float* bias;
  float scale;
  float* Cf;
  unsigned short* hi;
  unsigned short* lo;
  int mode;
};
struct GemmOuts4 { GemmOut o[4]; };

__global__ __launch_bounds__(256, 4)
void gemm_split_kernel(const unsigned short* __restrict__ A, GemmOuts4 P)
{
  const GemmOut g = P.o[blockIdx.z];
  __shared__ unsigned short As[128][48];
  __shared__ unsigned short Ws[64][48];

  const int tid = threadIdx.x;
  const int w = tid >> 6;          // wave 0..3
  const int l = tid & 63;
  const int lr = l & 15;
  const int lg = l >> 4;
  const int n0 = blockIdx.x * 128;
  const int o0 = blockIdx.y * 64;

  f32x4 acc[2][4];
#pragma unroll
  for (int m = 0; m < 2; ++m)
#pragma unroll
    for (int n = 0; n < 4; ++n) acc[m][n] = (f32x4){0.f, 0.f, 0.f, 0.f};

  const int ar = tid >> 1;          // 0..127
  const int ac = (tid & 1) * 16;
  const int wr = tid >> 2;          // 0..63
  const int wc = (tid & 3) * 8;

  // prefetch first K-step
  bf8_t ra0 = *(const bf8_t*)(A + (size_t)(n0 + ar) * 1024 + ac);
  bf8_t ra1 = *(const bf8_t*)(A + (size_t)(n0 + ar) * 1024 + ac + 8);
  bf8_t rw0 = *(const bf8_t*)(g.W + (size_t)(o0 + wr) * 1536 + wc);

  for (int k0 = 0; k0 < 1536; k0 += 32) {
    __syncthreads();   // prior tile's readers done
    *(bf8_t*)&As[ar][ac] = ra0;
    *(bf8_t*)&As[ar][ac + 8] = ra1;
    *(bf8_t*)&Ws[wr][wc] = rw0;
    __syncthreads();
    if (k0 + 32 < 1536) {   // issue next-tile loads early; hide under MFMA
      const int ak = (k0 + 32) & 1023;
      ra0 = *(const bf8_t*)(A + (size_t)(n0 + ar) * 1024 + ak + ac);
      ra1 = *(const bf8_t*)(A + (size_t)(n0 + ar) * 1024 + ak + ac + 8);
      rw0 = *(const bf8_t*)(g.W + (size_t)(o0 + wr) * 1536 + k0 + 32 + wc);
    }

    bf8_t bvs[4];
#pragma unroll
    for (int n = 0; n < 4; ++n)
      bvs[n] = *(const bf8_t*)&Ws[n * 16 + lr][lg * 8];
#pragma unroll
    for (int m = 0; m < 2; ++m) {
      bf8_t av = *(const bf8_t*)&As[w * 32 + m * 16 + lr][lg * 8];
#pragma unroll
      for (int n = 0; n < 4; ++n)
        acc[m][n] = MFMA16(av, bvs[n], acc[m][n]);
    }
  }

#pragma unroll
  for (int m = 0; m < 2; ++m)
#pragma unroll
    for (int n = 0; n < 4; ++n)
#pragma unroll
      for (int r = 0; r < 4; ++r) {
        const int row = n0 + w * 32 + m * 16 + lg * 4 + r;
        const int col = o0 + n * 16 + lr;
        float v = acc[m][n][r];
        if (g.bias) v += g.bias[col];
        v *= g.scale;
        if (g.mode == 0) {
          g.Cf[((size_t)row << 9) + col] = v;
        } else {
          const int bb = row & 1, rr = row >> 1;
          const int hh = col >> 6, dd = col & 63;
          size_t id;
          if (g.mode == 1) id = (((size_t)(bb * H_ + hh) * R_) + rr) * 64 + dd;
          else             id = (((size_t)(bb * H_ + hh) * 64) + dd) * R_ + rr;
          const unsigned short hv = f2bf(v);
          g.hi[id] = hv;
          g.lo[id] = f2bf(v - bf2f(hv));
        }
      }
}

// ---------------------------------------------------------------------------
// Fused gate GEMMs + sigmoid + blend:
// t = A1*W1^T + A2*W2^T (both split, K=1536 each); gate = sigmoid(t + gb);
// attn = gate*sum_out + (1-gate)*reg_out, written as hi/lo pair [row][1024].
// A1 = sout pair, A2 = rout pair (packed [row][1024] hi|lo).
// ---------------------------------------------------------------------------
__global__ __launch_bounds__(256, 4)
void gate_blend_gemm_kernel(const unsigned short* __restrict__ A1,
                            const unsigned short* __restrict__ A2,
                            const unsigned short* __restrict__ W1,
                            const unsigned short* __restrict__ W2,
                            const float* __restrict__ gb,
                            unsigned short* __restrict__ attnP)
{
  __shared__ unsigned short As[128][48];
  __shared__ unsigned short Ws[64][48];

  const int tid = threadIdx.x;
  const int w = tid >> 6;
  const int l = tid & 63;
  const int lr = l & 15;
  const int lg = l >> 4;
  const int n0 = blockIdx.x * 128;
  const int o0 = blockIdx.y * 64;

  f32x4 acc[2][4];
#pragma unroll
  for (int m = 0; m < 2; ++m)
#pragma unroll
    for (int n = 0; n < 4; ++n) acc[m][n] = (f32x4){0.f, 0.f, 0.f, 0.f};

  const int ar = tid >> 1;
  const int ac = (tid & 1) * 16;
  const int wr = tid >> 2;
  const int wc = (tid & 3) * 8;

  auto aP = [&](int kk) {
    const unsigned short* Ax = (kk < 48) ? A1 : A2;
    const int k0 = ((kk < 48) ? kk : kk - 48) * 32;
    return Ax + (size_t)(n0 + ar) * 1024 + (k0 & 1023) + ac;
  };
  auto wP = [&](int kk) {
    const unsigned short* Wx = (kk < 48) ? W1 : W2;
    const int k0 = ((kk < 48) ? kk : kk - 48) * 32;
    return Wx + (size_t)(o0 + wr) * 1536 + k0 + wc;
  };

  bf8_t ra0 = *(const bf8_t*)aP(0);
  bf8_t ra1 = *(const bf8_t*)(aP(0) + 8);
  bf8_t rw0 = *(const bf8_t*)wP(0);

  for (int kk = 0; kk < 96; ++kk) {
    __syncthreads();
    *(bf8_t*)&As[ar][ac] = ra0;
    *(bf8_t*)&As[ar][ac + 8] = ra1;
    *(bf8_t*)&Ws[wr][wc] = rw0;
    __syncthreads();
    if (kk + 1 < 96) {
      ra0 = *(const bf8_t*)aP(kk + 1);
      ra1 = *(const bf8_t*)(aP(kk + 1) + 8);
      rw0 = *(const bf8_t*)wP(kk + 1);
    }

    bf8_t bvs[4];
#pragma unroll
    for (int n = 0; n < 4; ++n)
      bvs[n] = *(const bf8_t*)&Ws[n * 16 + lr][lg * 8];
#pragma unroll
    for (int m = 0; m < 2; ++m) {
      bf8_t av = *(const bf8_t*)&As[w * 32 + m * 16 + lr][lg * 8];
#pragma unroll
      for (int n = 0; n < 4; ++n)
        acc[m][n] = MFMA16(av, bvs[n], acc[m][n]);
    }
  }

#pragma unroll
  for (int m = 0; m < 2; ++m)
#pragma unroll
    for (int n = 0; n < 4; ++n)
#pragma unroll
      for (int r = 0; r < 4; ++r) {
        const int row = n0 + w * 32 + m * 16 + lg * 4 + r;
        const int col = o0 + n * 16 + lr;
        const float t = acc[m][n][r] + gb[col];
        const float gt = 1.0f / (1.0f + __expf(-t));
        const size_t base = (size_t)row << 10;
        const float so = bf2f(A1[base + col]) + bf2f(A1[base + 512 + col]);
        const float ro = bf2f(A2[base + col]) + bf2f(A2[base + 512 + col]);
        const float a = gt * so + (1.0f - gt) * ro;
        const unsigned short hv = f2bf(a);
        attnP[base + col] = hv;
        attnP[base + 512 + col] = f2bf(a - bf2f(hv));
      }
}

// ---------------------------------------------------------------------------
// Split-precision MFMA flash attention, PARTIAL over a KV chunk.
// SWAPPED QK^T: mfma(K, Q) -> lane owns one q-row's scores (q = lane&15).
// P stays entirely in REGISTERS: lane (lr,lg) owns P[q=lr][kv in
// {lg*4+r, 16+lg*4+r}], which is a legal per-(lg,j) k-slot assignment for the
// PV A-operand; V's B-fragment is read at the SAME permuted kv columns
// (2x ds_read_b64 at cols lg*4 and 16+lg*4), so the permutation cancels.
// Q/K: hi/lo [bh][len][64]; V: hi/lo TRANSPOSED [bh][64][kv_len]; Q pre-scaled.
// Block: 64 q-rows, 256 threads (4 waves x 16 q-rows). KV tiles of 32.
// T14: next tile's global loads issued before compute, LDS-written next iter.
// Writes unnormalized acc (fp32) + (m,l) per row.
// ---------------------------------------------------------------------------
__global__ __launch_bounds__(256, 4)
void flash_partial_kernel(const unsigned short* __restrict__ Qhi, const unsigned short* __restrict__ Qlo,
                          const unsigned short* __restrict__ Khi, const unsigned short* __restrict__ Klo,
                          const unsigned short* __restrict__ VtHi, const unsigned short* __restrict__ VtLo,
                          int q_len, int kv_len, int chunk, int zsplit,
                          float* __restrict__ accA, float* __restrict__ accB,
                          float* __restrict__ mlP)
{
  __shared__ unsigned short KsH[32][72];
  __shared__ unsigned short KsL[32][72];
  __shared__ unsigned short VsH[64][40];
  __shared__ unsigned short VsL[64][40];

  const int tid = threadIdx.x;
  const int w = tid >> 6;
  const int l = tid & 63;
  const int lr = l & 15;
  const int lg = l >> 4;
  const int bh = blockIdx.y;
  const int q0 = blockIdx.x * 64;
  const int c = blockIdx.z;
  const int kvbeg = c * chunk;
  const int kvend = kvbeg + chunk;

  // Q fragments (q = q0 + w*16 + lr), used as MFMA B-operand
  bf8_t qh[2], ql[2];
  {
    const size_t qbase = ((size_t)bh * q_len + (q0 + w * 16 + lr)) * 64;
#pragma unroll
    for (int kd = 0; kd < 2; ++kd) {
      qh[kd] = *(const bf8_t*)(Qhi + qbase + kd * 32 + lg * 8);
      ql[kd] = *(const bf8_t*)(Qlo + qbase + kd * 32 + lg * 8);
    }
  }

  f32x4 acc[4];
#pragma unroll
  for (int nd = 0; nd < 4; ++nd) acc[nd] = (f32x4){0.f, 0.f, 0.f, 0.f};
  float mrow = -INFINITY;   // per-lane state for q = q0 + w*16 + lr
  float lrow = 0.0f;

  const int sr = tid >> 3;            // K staging row 0..31
  const int sc = (tid & 7) * 8;       // K staging col
  const int vd = tid >> 2;            // V^T staging d-row 0..63
  const int vc = (tid & 3) * 8;       // V^T staging kv-col

  // prefetch first tile into regs (T14)
  bf8_t rkh, rkl, rvh, rvl;
  {
    const size_t kb = ((size_t)bh * kv_len + kvbeg + sr) * 64 + sc;
    rkh = *(const bf8_t*)(Khi + kb);
    rkl = *(const bf8_t*)(Klo + kb);
    const size_t vb = ((size_t)bh * 64 + vd) * kv_len + kvbeg + vc;
    rvh = *(const bf8_t*)(VtHi + vb);
    rvl = *(const bf8_t*)(VtLo + vb);
  }

  for (int kv0 = kvbeg; kv0 < kvend; kv0 += 32) {
    __syncthreads();                  // prior tile's readers done
    *(bf8_t*)&KsH[sr][sc] = rkh;
    *(bf8_t*)&KsL[sr][sc] = rkl;
    *(bf8_t*)&VsH[vd][vc] = rvh;
    *(bf8_t*)&VsL[vd][vc] = rvl;
    __syncthreads();
    if (kv0 + 32 < kvend) {           // issue next-tile loads; hide under compute
      const size_t kb = ((size_t)bh * kv_len + kv0 + 32 + sr) * 64 + sc;
      rkh = *(const bf8_t*)(Khi + kb);
      rkl = *(const bf8_t*)(Klo + kb);
      const size_t vb = ((size_t)bh * 64 + vd) * kv_len + kv0 + 32 + vc;
      rvh = *(const bf8_t*)(VtHi + vb);
      rvl = *(const bf8_t*)(VtLo + vb);
    }

    // ---- QK^T swapped (12 MFMAs): s[n][r] = S[kv = n*16+lg*4+r][q = lr]
    f32x4 s[2];
    s[0] = (f32x4){0.f, 0.f, 0.f, 0.f};
    s[1] = (f32x4){0.f, 0.f, 0.f, 0.f};
#pragma unroll
    for (int kd = 0; kd < 2; ++kd) {
#pragma unroll
      for (int n = 0; n < 2; ++n) {
        bf8_t kfh = *(const bf8_t*)&KsH[n * 16 + lr][kd * 32 + lg * 8];
        bf8_t kfl = *(const bf8_t*)&KsL[n * 16 + lr][kd * 32 + lg * 8];
        s[n] = MFMA16(kfh, qh[kd], s[n]);
        s[n] = MFMA16(kfh, ql[kd], s[n]);
        s[n] = MFMA16(kfl, qh[kd], s[n]);
      }
    }

    // ---- online softmax: lane owns q = lr; reduce across lg via 2 shuffles
    float mx = fmaxf(fmaxf(fmaxf(s[0][0], s[0][1]), fmaxf(s[0][2], s[0][3])),
                     fmaxf(fmaxf(s[1][0], s[1][1]), fmaxf(s[1][2], s[1][3])));
    mx = fmaxf(mx, __shfl_xor(mx, 16));
    mx = fmaxf(mx, __shfl_xor(mx, 32));
    const float m2 = fmaxf(mrow, mx);
    const float f = __expf(mrow - m2);   // first iter: exp(-inf) = 0
    mrow = m2;
    float p0[4], p1[4];
    float ts = 0.f;
#pragma unroll
    for (int r = 0; r < 4; ++r) {
      p0[r] = __expf(s[0][r] - m2);
      p1[r] = __expf(s[1][r] - m2);
      ts += p0[r] + p1[r];
    }
    ts += __shfl_xor(ts, 16);
    ts += __shfl_xor(ts, 32);
    lrow = lrow * f + ts;

    // broadcast rescale factor to acc-row layout (q' = lg*4 + r)
    float fr[4];
#pragma unroll
    for (int r = 0; r < 4; ++r) fr[r] = __shfl(f, lg * 4 + r);
#pragma unroll
    for (int nd = 0; nd < 4; ++nd)
#pragma unroll
      for (int r = 0; r < 4; ++r) acc[nd][r] *= fr[r];

    // ---- P -> registers (hi = trunc, lo = RNE residual); lane-local
    bf8_t pah, pal;
#pragma unroll
    for (int r = 0; r < 4; ++r) {
      const unsigned u0 = __builtin_bit_cast(unsigned, p0[r]);
      pah[r] = (short)(u0 >> 16);
      pal[r] = (short)f2bf(p0[r] - __builtin_bit_cast(float, u0 & 0xFFFF0000u));
      const unsigned u1 = __builtin_bit_cast(unsigned, p1[r]);
      pah[4 + r] = (short)(u1 >> 16);
      pal[4 + r] = (short)f2bf(p1[r] - __builtin_bit_cast(float, u1 & 0xFFFF0000u));
    }

    // ---- PV (12 MFMAs); V read at the SAME permuted kv columns as P's slots
#pragma unroll
    for (int nd = 0; nd < 4; ++nd) {
      const bf4_t vh0 = *(const bf4_t*)&VsH[nd * 16 + lr][lg * 4];
      const bf4_t vh1 = *(const bf4_t*)&VsH[nd * 16 + lr][16 + lg * 4];
      const bf4_t vl0 = *(const bf4_t*)&VsL[nd * 16 + lr][lg * 4];
      const bf4_t vl1 = *(const bf4_t*)&VsL[nd * 16 + lr][16 + lg * 4];
      const bf8_t vfh = {vh0[0], vh0[1], vh0[2], vh0[3], vh1[0], vh1[1], vh1[2], vh1[3]};
      const bf8_t vfl = {vl0[0], vl0[1], vl0[2], vl0[3], vl1[0], vl1[1], vl1[2], vl1[3]};
      acc[nd] = MFMA16(pah, vfh, acc[nd]);
      acc[nd] = MFMA16(pal, vfh, acc[nd]);
      acc[nd] = MFMA16(pah, vfl, acc[nd]);
    }
  }

  // ---- store partials (unnormalized; acc row q = q0 + w*16 + lg*4 + r)
  const size_t cstride = (size_t)16 * q_len * 64;
  float* accbase = (c < zsplit) ? accA + (size_t)c * cstride
                                : accB + (size_t)(c - zsplit) * cstride;
#pragma unroll
  for (int nd = 0; nd < 4; ++nd)
#pragma unroll
    for (int r = 0; r < 4; ++r) {
      const int q = q0 + w * 16 + lg * 4 + r;
      accbase[((size_t)bh * q_len + q) * 64 + nd * 16 + lr] = acc[nd][r];
    }
  if (l < 16) {
    const int q = q0 + w * 16 + l;
    *(float2*)&mlP[((size_t)(c * 16 + bh) * q_len + q) * 2] = make_float2(mrow, lrow);
  }
}

// ---------------------------------------------------------------------------
// Merge stage-1 partials -> X2 (row-major pair) and X2^T (pair)
// acc: [16 chunks][bh][128][64]; ml: [(c*16+bh)*128+q]*2
// ---------------------------------------------------------------------------
__global__ __launch_bounds__(256)
void merge_x2_kernel(const float* __restrict__ acc, const float* __restrict__ ml,
                     unsigned short* __restrict__ X2hi, unsigned short* __restrict__ X2lo,
                     unsigned short* __restrict__ X2Thi, unsigned short* __restrict__ X2Tlo)
{
  const int idx = blockIdx.x * 256 + threadIdx.x;   // < 16*128*64
  const int d = idx & 63;
  const int q = (idx >> 6) & 127;
  const int bh = idx >> 13;
  float M = -INFINITY;
#pragma unroll
  for (int c = 0; c < 16; ++c)
    M = fmaxf(M, ml[((size_t)(c * 16 + bh) * 128 + q) * 2]);
  float ls = 0.f, o = 0.f;
#pragma unroll
  for (int c = 0; c < 16; ++c) {
    const size_t mi = ((size_t)(c * 16 + bh) * 128 + q) * 2;
    const float wgt = __expf(ml[mi] - M);
    ls += wgt * ml[mi + 1];
    o += wgt * acc[(size_t)c * 131072 + ((size_t)bh * 128 + q) * 64 + d];
  }
  const float v = o / ls;
  const unsigned short hv = f2bf(v);
  const unsigned short lv = f2bf(v - bf2f(hv));
  X2hi[((size_t)bh * 128 + q) * 64 + d] = hv;
  X2lo[((size_t)bh * 128 + q) * 64 + d] = lv;
  X2Thi[((size_t)bh * 64 + d) * 128 + q] = hv;
  X2Tlo[((size_t)bh * 64 + d) * 128 + q] = lv;
}

// ---------------------------------------------------------------------------
// Merge stage-2/3 partials -> packed pair rows [q*B+b][1024] (hi | lo at +512)
// ---------------------------------------------------------------------------
__global__ __launch_bounds__(256)
void merge_rows_kernel(const float* __restrict__ accA, const float* __restrict__ accB,
                       const float* __restrict__ ml, int q_len, int qbits, int nc,
                       unsigned short* __restrict__ OutP)
{
  const int idx = blockIdx.x * 256 + threadIdx.x;   // < 16*q_len*64
  const int d = idx & 63;
  const int q = (idx >> 6) & (q_len - 1);
  const int bh = idx >> (6 + qbits);
  float M = -INFINITY;
  for (int c = 0; c < nc; ++c)
    M = fmaxf(M, ml[((size_t)(c * 16 + bh) * q_len + q) * 2]);
  float ls = 0.f, o = 0.f;
  const size_t aoff = ((size_t)bh * q_len + q) * 64 + d;
  for (int c = 0; c < nc; ++c) {
    const size_t mi = ((size_t)(c * 16 + bh) * q_len + q) * 2;
    const float wgt = __expf(ml[mi] - M);
    ls += wgt * ml[mi + 1];
    const float* a = (c == 0) ? accA : accB;
    o += wgt * a[aoff];
  }
  const float v = o / ls;
  const int b = bh >> 3, h = bh & 7;
  const size_t nrow = (size_t)q * B_ + b;
  const int col = h * 64 + d;
  const unsigned short hv = f2bf(v);
  OutP[nrow * 1024 + col] = hv;
  OutP[nrow * 1024 + 512 + col] = f2bf(v - bf2f(hv));
}

// ---------------------------------------------------------------------------
extern "C" void kernel_launch(void* const* d_in, const int* in_sizes, int n_in,
                              void* d_out, int out_size, void* d_ws, size_t ws_size,
                              hipStream_t stream)
{
  const float* reg_x = (const float*)d_in[0];
  const int*   ids   = (const int*)d_in[1];
  const float* table = (const float*)d_in[4];
  const float* wq1 = (const float*)d_in[5];  const float* bq1 = (const float*)d_in[6];
  const float* wq2 = (const float*)d_in[7];  const float* bq2 = (const float*)d_in[8];
  const float* wk  = (const float*)d_in[9];  const float* bk  = (const float*)d_in[10];
  const float* wv  = (const float*)d_in[11]; const float* bv  = (const float*)d_in[12];
  const float* wo  = (const float*)d_in[13]; const float* bo  = (const float*)d_in[14];
  const float* sgw = (const float*)d_in[15];
  const float* rgw = (const float*)d_in[16];
  const float* gb  = (const float*)d_in[17];
  float* out = (float*)d_out;
  char* W = (char*)d_ws;

  // ---- workspace layout (bytes), total 63,438,848 (< 66,060,288 proven-safe)
  const size_t WSLOT  = 1572864;                  // 512*1536*2
  const size_t oApair = 0;                        //  8 MB [reuse: stage-1/2 acc, stage-3 accA]
  const size_t oW     = 8388608;                  //  7 x 1.5 MB = 11,010,048
  const size_t oKhi   = oW + 7 * WSLOT;           // 19,398,656 [reuse: attn_p over Khi+Klo]
  const size_t oKlo   = oKhi + 4194304;
  const size_t oVtHi  = oKlo + 4194304;
  const size_t oVtLo  = oVtHi + 4194304;
  const size_t oQ1hi  = oVtLo + 4194304;          // [reuse: sout_p over Q1hi+Q1lo]
  const size_t oQ1lo  = oQ1hi + 4194304;
  const size_t oQ2hi  = oQ1lo + 4194304;          // [reuse: rout_p over Q2hi+Q2lo]
  const size_t oQ2lo  = oQ2hi + 4194304;
  const size_t oAcc1  = oQ2lo + 4194304;          // 52,953,088 (8 MB, stage-3 accB)
  const size_t oSQhi  = oAcc1 + 8388608;          // 61,341,696
  const size_t oSQlo  = oSQhi + 262144;
  const size_t oX2hi  = oSQlo + 262144;
  const size_t oX2lo  = oX2hi + 262144;
  const size_t oX2Thi = oX2lo + 262144;
  const size_t oX2Tlo = oX2Thi + 262144;
  const size_t oMl    = oX2Tlo + 262144;          // 62,914,560 (+524,288)

  auto U16 = [&](size_t off) { return (unsigned short*)(W + off); };
  auto F32 = [&](size_t off) { return (float*)(W + off); };
  unsigned short* Apair  = U16(oApair);
  unsigned short* Wk3    = U16(oW + 0 * WSLOT);
  unsigned short* Wv3    = U16(oW + 1 * WSLOT);
  unsigned short* Wq13   = U16(oW + 2 * WSLOT);
  unsigned short* Wq23   = U16(oW + 3 * WSLOT);
  unsigned short* Wsg3   = U16(oW + 4 * WSLOT);
  unsigned short* Wrg3   = U16(oW + 5 * WSLOT);
  unsigned short* Wo3    = U16(oW + 6 * WSLOT);
  float*          accS   = F32(oApair);           // stage-1/2 partials; stage-3 chunk 0
  float*          accB3  = F32(oAcc1);            // stage-3 chunk 1
  float*          mlP    = F32(oMl);
  unsigned short* sout_p = U16(oQ1hi);            // Q1 dead after stage-2 partial
  unsigned short* rout_p = U16(oQ2hi);            // Q2 dead after stage-3 partial
  unsigned short* attn_p = U16(oKhi);             // K dead after stage-3 partial

  const dim3 blk(256);

  // ---- precision splits
  split_a_kernel<<<8192, blk, 0, stream>>>(reg_x, Apair);
  WSplit7 ws7;
  ws7.j[0] = WSplitJob{wk,  Wk3};
  ws7.j[1] = WSplitJob{wv,  Wv3};
  ws7.j[2] = WSplitJob{wq1, Wq13};
  ws7.j[3] = WSplitJob{wq2, Wq23};
  ws7.j[4] = WSplitJob{sgw, Wsg3};
  ws7.j[5] = WSplitJob{rgw, Wrg3};
  ws7.j[6] = WSplitJob{wo,  Wo3};
  split_w7_kernel<<<dim3(1024, 7), blk, 0, stream>>>(ws7);
  gather_split_kernel<<<512, blk, 0, stream>>>(table, ids, U16(oSQhi), U16(oSQlo));

  // ---- 4 projections in one launch (blockIdx.z selects weight/output)
  GemmOuts4 proj;
  proj.o[0].W = Wk3;  proj.o[0].bias = bk;  proj.o[0].scale = 1.0f;   proj.o[0].Cf = nullptr;
  proj.o[0].hi = U16(oKhi);  proj.o[0].lo = U16(oKlo);  proj.o[0].mode = 1;
  proj.o[1].W = Wv3;  proj.o[1].bias = bv;  proj.o[1].scale = 1.0f;   proj.o[1].Cf = nullptr;
  proj.o[1].hi = U16(oVtHi); proj.o[1].lo = U16(oVtLo); proj.o[1].mode = 2;
  proj.o[2].W = Wq13; proj.o[2].bias = bq1; proj.o[2].scale = SCALE_; proj.o[2].Cf = nullptr;
  proj.o[2].hi = U16(oQ1hi); proj.o[2].lo = U16(oQ1lo); proj.o[2].mode = 1;
  proj.o[3].W = Wq23; proj.o[3].bias = bq2; proj.o[3].scale = SCALE_; proj.o[3].Cf = nullptr;
  proj.o[3].hi = U16(oQ2hi); proj.o[3].lo = U16(oQ2lo); proj.o[3].mode = 1;
  gemm_split_kernel<<<dim3(32, 8, 4), blk, 0, stream>>>(Apair, proj);

  // ---- stage 1: sum_q attends to reg tokens. KV=2048 split into 16 chunks.
  flash_partial_kernel<<<dim3(2, 16, 16), blk, 0, stream>>>(
      U16(oSQhi), U16(oSQlo), U16(oKhi), U16(oKlo), U16(oVtHi), U16(oVtLo),
      S_, R_, 128, 16, accS, accS, mlP);
  merge_x2_kernel<<<512, blk, 0, stream>>>(accS, mlP,
      U16(oX2hi), U16(oX2lo), U16(oX2Thi), U16(oX2Tlo));

  // ---- stage 2: reg queries attend to summaries (KV=128, 1 chunk)
  flash_partial_kernel<<<dim3(32, 16, 1), blk, 0, stream>>>(
      U16(oQ1hi), U16(oQ1lo), U16(oX2hi), U16(oX2lo), U16(oX2Thi), U16(oX2Tlo),
      R_, S_, 128, 1, accS, accS, mlP);
  merge_rows_kernel<<<8192, blk, 0, stream>>>(accS, accS, mlP, R_, 11, 1, sout_p);

  // ---- stage 3: regular self-attention. KV=2048 split into 2 chunks.
  flash_partial_kernel<<<dim3(32, 16, 2), blk, 0, stream>>>(
      U16(oQ2hi), U16(oQ2lo), U16(oKhi), U16(oKlo), U16(oVtHi), U16(oVtLo),
      R_, R_, 1024, 1, accS, accB3, mlP);
  merge_rows_kernel<<<8192, blk, 0, stream>>>(accS, accB3, mlP, R_, 11, 2, rout_p);

  // ---- fused gate GEMMs + sigmoid + blend -> attn pair
  gate_blend_gemm_kernel<<<dim3(32, 8), blk, 0, stream>>>(
      sout_p, rout_p, Wsg3, Wrg3, gb, attn_p);

  // ---- output projection -> d_out
  GemmOuts4 gf;
  gf.o[0].W = Wo3; gf.o[0].bias = bo; gf.o[0].scale = 1.0f; gf.o[0].Cf = out;
  gf.o[0].hi = nullptr; gf.o[0].lo = nullptr; gf.o[0].mode = 0;
  gf.o[1] = gf.o[0]; gf.o[2] = gf.o[0]; gf.o[3] = gf.o[0];
  gemm_split_kernel<<<dim3(32, 8, 1), blk, 0, stream>>>(attn_p, gf);
}

// Round 6
// 244.625 us; speedup vs baseline: 5.7145x; 1.0982x over previous
//
#include <hip/hip_runtime.h>
#include <cstdint>
#include <cstddef>

// Problem constants (fixed by setup_inputs)
constexpr int R_ = 2048;   // reg_len
constexpr int B_ = 2;      // batch
constexpr int S_ = 128;    // sum_len
constexpr int E_ = 512;    // embed dim
constexpr int H_ = 8;      // heads
constexpr int D_ = 64;     // head dim
constexpr int N_ = R_ * B_;            // 4096 token rows
constexpr float SCALE_ = 0.125f;       // D^-0.5

typedef short bf8_t __attribute__((ext_vector_type(8)));   // 8 bf16 in 4 VGPRs
typedef short bf4_t __attribute__((ext_vector_type(4)));   // 4 bf16 in 2 VGPRs
typedef float f32x4 __attribute__((ext_vector_type(4)));
typedef float f32x16 __attribute__((ext_vector_type(16)));

#define MFMA16(a, b, c) __builtin_amdgcn_mfma_f32_16x16x32_bf16((a), (b), (c), 0, 0, 0)
#define MFMA32(a, b, c) __builtin_amdgcn_mfma_f32_32x32x16_bf16((a), (b), (c), 0, 0, 0)

__device__ __forceinline__ unsigned short f2bf(float f) {
  unsigned u = __builtin_bit_cast(unsigned, f);
  unsigned r = u + 0x7FFFu + ((u >> 16) & 1u);   // RNE
  return (unsigned short)(r >> 16);
}
__device__ __forceinline__ float bf2f(unsigned short h) {
  unsigned u = ((unsigned)h) << 16;
  return __builtin_bit_cast(float, u);
}

// ---------------------------------------------------------------------------
// Fused weight splits: 7 x (src fp32 [512][512] -> bf16 [512][1536] hi|hi|lo)
// (logical K=1536: terms Ahi*Whi, Alo*Whi, Ahi*Wlo; lo*lo dropped, <=2^-18 rel)
// ---------------------------------------------------------------------------
struct WSplitJob { const float* src; unsigned short* dst; };
struct WSplit7 { WSplitJob j[7]; };

__global__ __launch_bounds__(256)
void split_w7_kernel(WSplit7 P)
{
  const WSplitJob jb = P.j[blockIdx.y];
  const int idx = blockIdx.x * 256 + threadIdx.x;   // < 512*512
  const int r = idx >> 9, c = idx & 511;
  const float v = jb.src[idx];
  const unsigned short hi = f2bf(v);
  const unsigned short lo = f2bf(v - bf2f(hi));
  unsigned short* d = jb.dst + (size_t)r * 1536 + c;
  d[0] = hi; d[512] = hi; d[1024] = lo;
}

// ---------------------------------------------------------------------------
// A split: src fp32 [4096][512] -> dst bf16 [4096][1024] laid out (hi|lo)
// ---------------------------------------------------------------------------
__global__ __launch_bounds__(256)
void split_a_kernel(const float* __restrict__ src, unsigned short* __restrict__ dst)
{
  const int idx = blockIdx.x * 256 + threadIdx.x;   // < 4096*512
  const int r = idx >> 9, c = idx & 511;
  const float v = src[idx];
  const unsigned short hi = f2bf(v);
  unsigned short* d = dst + ((size_t)r << 10) + c;
  d[0] = hi; d[512] = f2bf(v - bf2f(hi));
}

// ---------------------------------------------------------------------------
// Summary-query gather + split: qhi/qlo [bh][S][64], scale folded
// ---------------------------------------------------------------------------
__global__ __launch_bounds__(256)
void gather_split_kernel(const float* __restrict__ table, const int* __restrict__ ids,
                         unsigned short* __restrict__ qhi, unsigned short* __restrict__ qlo)
{
  const int idx = blockIdx.x * 256 + threadIdx.x;   // < B*H*S*D = 131072
  const int d = idx & 63;
  const int s = (idx >> 6) & 127;
  const int h = (idx >> 13) & 7;
  const int b = idx >> 16;
  const float v = table[(size_t)ids[b * S_ + s] * E_ + h * 64 + d] * SCALE_;
  const unsigned short hi = f2bf(v);
  qhi[idx] = hi;
  qlo[idx] = f2bf(v - bf2f(hi));
}

// ---------------------------------------------------------------------------
// Split-precision MFMA GEMM (T14 reg-prefetch staging).
// A: bf16 [M][1024] (hi|lo); logical K = 1536, A col wraps mod 1024
// (k 0..511: hi, 512..1023: lo, 1024..1535: hi). W: bf16 [512][1536] hi|hi|lo.
// Tile 128x64, 256 threads (4 waves, each 32 rows x 64 cols).
// mode 0: Cf[row*512+col] (+bias)
// mode 1: hi/lo pair -> [bh][row>>1][col&63] row-major attn layout
// mode 2: hi/lo pair -> [bh][col&63][row>>1] transposed attn layout (for V)
// ---------------------------------------------------------------------------
struct GemmOut {
  const unsigned short* W;
  const float* bias;
  float scale;
  float* Cf;
  unsigned short* hi;
  unsigned short* lo;
  int mode;
};
struct GemmOuts4 { GemmOut o[4]; };

__global__ __launch_bounds__(256, 4)
void gemm_split_kernel(const unsigned short* __restrict__ A, GemmOuts4 P)
{
  const GemmOut g = P.o[blockIdx.z];
  __shared__ unsigned short As[128][48];
  __shared__ unsigned short Ws[64][48];

  const int tid = threadIdx.x;
  const int w = tid >> 6;          // wave 0..3
  const int l = tid & 63;
  const int lr = l & 15;
  const int lg = l >> 4;
  const int n0 = blockIdx.x * 128;
  const int o0 = blockIdx.y * 64;

  f32x4 acc[2][4];
#pragma unroll
  for (int m = 0; m < 2; ++m)
#pragma unroll
    for (int n = 0; n < 4; ++n) acc[m][n] = (f32x4){0.f, 0.f, 0.f, 0.f};

  const int ar = tid >> 1;          // 0..127
  const int ac = (tid & 1) * 16;
  const int wr = tid >> 2;          // 0..63
  const int wc = (tid & 3) * 8;

  // prefetch first K-step
  bf8_t ra0 = *(const bf8_t*)(A + (size_t)(n0 + ar) * 1024 + ac);
  bf8_t ra1 = *(const bf8_t*)(A + (size_t)(n0 + ar) * 1024 + ac + 8);
  bf8_t rw0 = *(const bf8_t*)(g.W + (size_t)(o0 + wr) * 1536 + wc);

  for (int k0 = 0; k0 < 1536; k0 += 32) {
    __syncthreads();   // prior tile's readers done
    *(bf8_t*)&As[ar][ac] = ra0;
    *(bf8_t*)&As[ar][ac + 8] = ra1;
    *(bf8_t*)&Ws[wr][wc] = rw0;
    __syncthreads();
    if (k0 + 32 < 1536) {   // issue next-tile loads early; hide under MFMA
      const int ak = (k0 + 32) & 1023;
      ra0 = *(const bf8_t*)(A + (size_t)(n0 + ar) * 1024 + ak + ac);
      ra1 = *(const bf8_t*)(A + (size_t)(n0 + ar) * 1024 + ak + ac + 8);
      rw0 = *(const bf8_t*)(g.W + (size_t)(o0 + wr) * 1536 + k0 + 32 + wc);
    }

    bf8_t bvs[4];
#pragma unroll
    for (int n = 0; n < 4; ++n)
      bvs[n] = *(const bf8_t*)&Ws[n * 16 + lr][lg * 8];
#pragma unroll
    for (int m = 0; m < 2; ++m) {
      bf8_t av = *(const bf8_t*)&As[w * 32 + m * 16 + lr][lg * 8];
#pragma unroll
      for (int n = 0; n < 4; ++n)
        acc[m][n] = MFMA16(av, bvs[n], acc[m][n]);
    }
  }

#pragma unroll
  for (int m = 0; m < 2; ++m)
#pragma unroll
    for (int n = 0; n < 4; ++n)
#pragma unroll
      for (int r = 0; r < 4; ++r) {
        const int row = n0 + w * 32 + m * 16 + lg * 4 + r;
        const int col = o0 + n * 16 + lr;
        float v = acc[m][n][r];
        if (g.bias) v += g.bias[col];
        v *= g.scale;
        if (g.mode == 0) {
          g.Cf[((size_t)row << 9) + col] = v;
        } else {
          const int bb = row & 1, rr = row >> 1;
          const int hh = col >> 6, dd = col & 63;
          size_t id;
          if (g.mode == 1) id = (((size_t)(bb * H_ + hh) * R_) + rr) * 64 + dd;
          else             id = (((size_t)(bb * H_ + hh) * 64) + dd) * R_ + rr;
          const unsigned short hv = f2bf(v);
          g.hi[id] = hv;
          g.lo[id] = f2bf(v - bf2f(hv));
        }
      }
}

// ---------------------------------------------------------------------------
// Fused gate GEMMs + sigmoid + blend:
// t = A1*W1^T + A2*W2^T (both split, K=1536 each); gate = sigmoid(t + gb);
// attn = gate*sum_out + (1-gate)*reg_out, written as hi/lo pair [row][1024].
// A1 = sout pair, A2 = rout pair (packed [row][1024] hi|lo).
// ---------------------------------------------------------------------------
__global__ __launch_bounds__(256, 4)
void gate_blend_gemm_kernel(const unsigned short* __restrict__ A1,
                            const unsigned short* __restrict__ A2,
                            const unsigned short* __restrict__ W1,
                            const unsigned short* __restrict__ W2,
                            const float* __restrict__ gb,
                            unsigned short* __restrict__ attnP)
{
  __shared__ unsigned short As[128][48];
  __shared__ unsigned short Ws[64][48];

  const int tid = threadIdx.x;
  const int w = tid >> 6;
  const int l = tid & 63;
  const int lr = l & 15;
  const int lg = l >> 4;
  const int n0 = blockIdx.x * 128;
  const int o0 = blockIdx.y * 64;

  f32x4 acc[2][4];
#pragma unroll
  for (int m = 0; m < 2; ++m)
#pragma unroll
    for (int n = 0; n < 4; ++n) acc[m][n] = (f32x4){0.f, 0.f, 0.f, 0.f};

  const int ar = tid >> 1;
  const int ac = (tid & 1) * 16;
  const int wr = tid >> 2;
  const int wc = (tid & 3) * 8;

  auto aP = [&](int kk) {
    const unsigned short* Ax = (kk < 48) ? A1 : A2;
    const int k0 = ((kk < 48) ? kk : kk - 48) * 32;
    return Ax + (size_t)(n0 + ar) * 1024 + (k0 & 1023) + ac;
  };
  auto wP = [&](int kk) {
    const unsigned short* Wx = (kk < 48) ? W1 : W2;
    const int k0 = ((kk < 48) ? kk : kk - 48) * 32;
    return Wx + (size_t)(o0 + wr) * 1536 + k0 + wc;
  };

  bf8_t ra0 = *(const bf8_t*)aP(0);
  bf8_t ra1 = *(const bf8_t*)(aP(0) + 8);
  bf8_t rw0 = *(const bf8_t*)wP(0);

  for (int kk = 0; kk < 96; ++kk) {
    __syncthreads();
    *(bf8_t*)&As[ar][ac] = ra0;
    *(bf8_t*)&As[ar][ac + 8] = ra1;
    *(bf8_t*)&Ws[wr][wc] = rw0;
    __syncthreads();
    if (kk + 1 < 96) {
      ra0 = *(const bf8_t*)aP(kk + 1);
      ra1 = *(const bf8_t*)(aP(kk + 1) + 8);
      rw0 = *(const bf8_t*)wP(kk + 1);
    }

    bf8_t bvs[4];
#pragma unroll
    for (int n = 0; n < 4; ++n)
      bvs[n] = *(const bf8_t*)&Ws[n * 16 + lr][lg * 8];
#pragma unroll
    for (int m = 0; m < 2; ++m) {
      bf8_t av = *(const bf8_t*)&As[w * 32 + m * 16 + lr][lg * 8];
#pragma unroll
      for (int n = 0; n < 4; ++n)
        acc[m][n] = MFMA16(av, bvs[n], acc[m][n]);
    }
  }

#pragma unroll
  for (int m = 0; m < 2; ++m)
#pragma unroll
    for (int n = 0; n < 4; ++n)
#pragma unroll
      for (int r = 0; r < 4; ++r) {
        const int row = n0 + w * 32 + m * 16 + lg * 4 + r;
        const int col = o0 + n * 16 + lr;
        const float t = acc[m][n][r] + gb[col];
        const float gt = 1.0f / (1.0f + __expf(-t));
        const size_t base = (size_t)row << 10;
        const float so = bf2f(A1[base + col]) + bf2f(A1[base + 512 + col]);
        const float ro = bf2f(A2[base + col]) + bf2f(A2[base + 512 + col]);
        const float a = gt * so + (1.0f - gt) * ro;
        const unsigned short hv = f2bf(a);
        attnP[base + col] = hv;
        attnP[base + 512 + col] = f2bf(a - bf2f(hv));
      }
}

// ---------------------------------------------------------------------------
// Split-precision 32x32x16-MFMA flash attention, PARTIAL over a KV chunk.
// Swapped QK^T via MFMA32(A=K-frag[32kv x 16d], B=Q-frag): S col=q=lane&31,
// row kv=(r&3)+8*(r>>2)+4*(lane>>5) -> lane owns all 16 scores of ONE q.
// Softmax: 15 in-reg fmax + 1 shfl_xor(32); rescale factor is lane-local.
// P's layout depends only on (hi=lane>>5, j) -> legal PV B-operand k-slot
// assignment; V^T (A-operand) is read at the SAME permuted kv columns
// (2x ds_read_b64 at ks*16+hi*4 and ks*16+8+hi*4), so the permutation cancels.
// Q/K: hi/lo [bh][len][64]; V: hi/lo TRANSPOSED [bh][64][kv_len]; Q pre-scaled.
// Block: 128 q-rows, 256 threads (4 waves x 32 q-rows). KV tiles of 32.
// T14: next tile's global loads issued before compute, LDS-written next iter.
// Writes unnormalized acc (fp32, [bh][q][64]) + (m,l) per row.
// ---------------------------------------------------------------------------
__global__ __launch_bounds__(256, 2)
void flash_partial_kernel(const unsigned short* __restrict__ Qhi, const unsigned short* __restrict__ Qlo,
                          const unsigned short* __restrict__ Khi, const unsigned short* __restrict__ Klo,
                          const unsigned short* __restrict__ VtHi, const unsigned short* __restrict__ VtLo,
                          int q_len, int kv_len, int chunk, int zsplit,
                          float* __restrict__ accA, float* __restrict__ accB,
                          float* __restrict__ mlP)
{
  __shared__ unsigned short KsH[32][72];   // row stride 144B = 36dw -> conflict-free b128 col reads
  __shared__ unsigned short KsL[32][72];
  __shared__ unsigned short VsH[64][40];   // row stride 80B = 20dw
  __shared__ unsigned short VsL[64][40];

  const int tid = threadIdx.x;
  const int w = tid >> 6;
  const int l = tid & 63;
  const int lq = l & 31;           // q col / kv row (A) / d row (PV A)
  const int hi = l >> 5;           // k-slot group
  const int bh = blockIdx.y;
  const int q0 = blockIdx.x * 128;
  const int c = blockIdx.z;
  const int kvbeg = c * chunk;
  const int kvend = kvbeg + chunk;
  const int qrow = q0 + w * 32 + lq;

  // Q B-fragments (col q = lq, k-slot hi*8+j -> d = kd*16 + hi*8 + j)
  bf8_t qh[4], ql[4];
  {
    const size_t qbase = ((size_t)bh * q_len + qrow) * 64;
#pragma unroll
    for (int kd = 0; kd < 4; ++kd) {
      qh[kd] = *(const bf8_t*)(Qhi + qbase + kd * 16 + hi * 8);
      ql[kd] = *(const bf8_t*)(Qlo + qbase + kd * 16 + hi * 8);
    }
  }

  // O^T accumulators: col q = lq, row d = (r&3)+8*(r>>2)+4*hi (+32 for acc1)
  f32x16 acc0 = {0,0,0,0,0,0,0,0,0,0,0,0,0,0,0,0};
  f32x16 acc1 = {0,0,0,0,0,0,0,0,0,0,0,0,0,0,0,0};
  float mrow = -INFINITY;   // per-lane state for q = qrow (halves kept identical)
  float lrow = 0.0f;

  const int sr = tid >> 3;            // K staging row 0..31
  const int sc = (tid & 7) * 8;       // K staging col
  const int vd = tid >> 2;            // V^T staging d-row 0..63
  const int vc = (tid & 3) * 8;       // V^T staging kv-col

  // prefetch first tile into regs (T14)
  bf8_t rkh, rkl, rvh, rvl;
  {
    const size_t kb = ((size_t)bh * kv_len + kvbeg + sr) * 64 + sc;
    rkh = *(const bf8_t*)(Khi + kb);
    rkl = *(const bf8_t*)(Klo + kb);
    const size_t vb = ((size_t)bh * 64 + vd) * kv_len + kvbeg + vc;
    rvh = *(const bf8_t*)(VtHi + vb);
    rvl = *(const bf8_t*)(VtLo + vb);
  }

  for (int kv0 = kvbeg; kv0 < kvend; kv0 += 32) {
    __syncthreads();                  // prior tile's readers done
    *(bf8_t*)&KsH[sr][sc] = rkh;
    *(bf8_t*)&KsL[sr][sc] = rkl;
    *(bf8_t*)&VsH[vd][vc] = rvh;
    *(bf8_t*)&VsL[vd][vc] = rvl;
    __syncthreads();
    if (kv0 + 32 < kvend) {           // issue next-tile loads; hide under compute
      const size_t kb = ((size_t)bh * kv_len + kv0 + 32 + sr) * 64 + sc;
      rkh = *(const bf8_t*)(Khi + kb);
      rkl = *(const bf8_t*)(Klo + kb);
      const size_t vb = ((size_t)bh * 64 + vd) * kv_len + kv0 + 32 + vc;
      rvh = *(const bf8_t*)(VtHi + vb);
      rvl = *(const bf8_t*)(VtLo + vb);
    }

    // ---- QK^T swapped (12 MFMA32): S[kv][q] for the whole 32x32 tile
    f32x16 s = {0,0,0,0,0,0,0,0,0,0,0,0,0,0,0,0};
#pragma unroll
    for (int kd = 0; kd < 4; ++kd) {
      const bf8_t kfh = *(const bf8_t*)&KsH[lq][kd * 16 + hi * 8];
      const bf8_t kfl = *(const bf8_t*)&KsL[lq][kd * 16 + hi * 8];
      s = MFMA32(kfh, qh[kd], s);
      s = MFMA32(kfh, ql[kd], s);
      s = MFMA32(kfl, qh[kd], s);
    }

    // ---- online softmax: lane owns q = lq; combine halves via 1 shuffle
    float mx = s[0];
#pragma unroll
    for (int r = 1; r < 16; ++r) mx = fmaxf(mx, s[r]);
    mx = fmaxf(mx, __shfl_xor(mx, 32));
    const float m2 = fmaxf(mrow, mx);
    const float f = __expf(mrow - m2);   // first iter: exp(-inf) = 0
    mrow = m2;
    float p[16];
    float ts = 0.f;
#pragma unroll
    for (int r = 0; r < 16; ++r) { p[r] = __expf(s[r] - m2); ts += p[r]; }
    ts += __shfl_xor(ts, 32);
    lrow = lrow * f + ts;
#pragma unroll
    for (int r = 0; r < 16; ++r) { acc0[r] *= f; acc1[r] *= f; }

    // ---- P -> bf16 hi/lo (trunc hi + RNE residual); lane-local
    bf8_t pah[2], pal[2];
#pragma unroll
    for (int ks = 0; ks < 2; ++ks)
#pragma unroll
      for (int j = 0; j < 8; ++j) {
        const float v = p[ks * 8 + j];
        const unsigned u = __builtin_bit_cast(unsigned, v);
        pah[ks][j] = (short)(u >> 16);
        pal[ks][j] = (short)f2bf(v - __builtin_bit_cast(float, u & 0xFFFF0000u));
      }

    // ---- PV (12 MFMA32): O^T += V^T * P; V read at permuted kv cols
#pragma unroll
    for (int ks = 0; ks < 2; ++ks) {
      {
        const bf4_t vh0 = *(const bf4_t*)&VsH[lq][ks * 16 + hi * 4];
        const bf4_t vh1 = *(const bf4_t*)&VsH[lq][ks * 16 + 8 + hi * 4];
        const bf4_t vl0 = *(const bf4_t*)&VsL[lq][ks * 16 + hi * 4];
        const bf4_t vl1 = *(const bf4_t*)&VsL[lq][ks * 16 + 8 + hi * 4];
        const bf8_t vfh = {vh0[0], vh0[1], vh0[2], vh0[3], vh1[0], vh1[1], vh1[2], vh1[3]};
        const bf8_t vfl = {vl0[0], vl0[1], vl0[2], vl0[3], vl1[0], vl1[1], vl1[2], vl1[3]};
        acc0 = MFMA32(vfh, pah[ks], acc0);
        acc0 = MFMA32(vfh, pal[ks], acc0);
        acc0 = MFMA32(vfl, pah[ks], acc0);
      }
      {
        const bf4_t vh0 = *(const bf4_t*)&VsH[32 + lq][ks * 16 + hi * 4];
        const bf4_t vh1 = *(const bf4_t*)&VsH[32 + lq][ks * 16 + 8 + hi * 4];
        const bf4_t vl0 = *(const bf4_t*)&VsL[32 + lq][ks * 16 + hi * 4];
        const bf4_t vl1 = *(const bf4_t*)&VsL[32 + lq][ks * 16 + 8 + hi * 4];
        const bf8_t vfh = {vh0[0], vh0[1], vh0[2], vh0[3], vh1[0], vh1[1], vh1[2], vh1[3]};
        const bf8_t vfl = {vl0[0], vl0[1], vl0[2], vl0[3], vl1[0], vl1[1], vl1[2], vl1[3]};
        acc1 = MFMA32(vfh, pah[ks], acc1);
        acc1 = MFMA32(vfh, pal[ks], acc1);
        acc1 = MFMA32(vfl, pah[ks], acc1);
      }
    }
  }

  // ---- store partials (unnormalized): [bh][q][64]; reg group rg -> d =
  // dblk*32 + rg*8 + hi*4 + (0..3), contiguous -> dwordx4 stores
  const size_t cstride = (size_t)16 * q_len * 64;
  float* accbase = (c < zsplit) ? accA + (size_t)c * cstride
                                : accB + (size_t)(c - zsplit) * cstride;
  float* rowp = accbase + ((size_t)bh * q_len + qrow) * 64;
#pragma unroll
  for (int rg = 0; rg < 4; ++rg) {
    *(float4*)(rowp + rg * 8 + hi * 4) =
        make_float4(acc0[rg * 4 + 0], acc0[rg * 4 + 1], acc0[rg * 4 + 2], acc0[rg * 4 + 3]);
    *(float4*)(rowp + 32 + rg * 8 + hi * 4) =
        make_float4(acc1[rg * 4 + 0], acc1[rg * 4 + 1], acc1[rg * 4 + 2], acc1[rg * 4 + 3]);
  }
  if (l < 32) {
    const int q = q0 + w * 32 + l;
    *(float2*)&mlP[((size_t)(c * 16 + bh) * q_len + q) * 2] = make_float2(mrow, lrow);
  }
}

// ---------------------------------------------------------------------------
// Merge stage-1 partials -> X2 (row-major pair) and X2^T (pair)
// acc: [16 chunks][bh][128][64]; ml: [(c*16+bh)*128+q]*2
// ---------------------------------------------------------------------------
__global__ __launch_bounds__(256)
void merge_x2_kernel(const float* __restrict__ acc, const float* __restrict__ ml,
                     unsigned short* __restrict__ X2hi, unsigned short* __restrict__ X2lo,
                     unsigned short* __restrict__ X2Thi, unsigned short* __restrict__ X2Tlo)
{
  const int idx = blockIdx.x * 256 + threadIdx.x;   // < 16*128*64
  const int d = idx & 63;
  const int q = (idx >> 6) & 127;
  const int bh = idx >> 13;
  float M = -INFINITY;
#pragma unroll
  for (int c = 0; c < 16; ++c)
    M = fmaxf(M, ml[((size_t)(c * 16 + bh) * 128 + q) * 2]);
  float ls = 0.f, o = 0.f;
#pragma unroll
  for (int c = 0; c < 16; ++c) {
    const size_t mi = ((size_t)(c * 16 + bh) * 128 + q) * 2;
    const float wgt = __expf(ml[mi] - M);
    ls += wgt * ml[mi + 1];
    o += wgt * acc[(size_t)c * 131072 + ((size_t)bh * 128 + q) * 64 + d];
  }
  const float v = o / ls;
  const unsigned short hv = f2bf(v);
  const unsigned short lv = f2bf(v - bf2f(hv));
  X2hi[((size_t)bh * 128 + q) * 64 + d] = hv;
  X2lo[((size_t)bh * 128 + q) * 64 + d] = lv;
  X2Thi[((size_t)bh * 64 + d) * 128 + q] = hv;
  X2Tlo[((size_t)bh * 64 + d) * 128 + q] = lv;
}

// ---------------------------------------------------------------------------
// Merge stage-2/3 partials -> packed pair rows [q*B+b][1024] (hi | lo at +512)
// ---------------------------------------------------------------------------
__global__ __launch_bounds__(256)
void merge_rows_kernel(const float* __restrict__ accA, const float* __restrict__ accB,
                       const float* __restrict__ ml, int q_len, int qbits, int nc,
                       unsigned short* __restrict__ OutP)
{
  const int idx = blockIdx.x * 256 + threadIdx.x;   // < 16*q_len*64
  const int d = idx & 63;
  const int q = (idx >> 6) & (q_len - 1);
  const int bh = idx >> (6 + qbits);
  float M = -INFINITY;
  for (int c = 0; c < nc; ++c)
    M = fmaxf(M, ml[((size_t)(c * 16 + bh) * q_len + q) * 2]);
  float ls = 0.f, o = 0.f;
  const size_t aoff = ((size_t)bh * q_len + q) * 64 + d;
  for (int c = 0; c < nc; ++c) {
    const size_t mi = ((size_t)(c * 16 + bh) * q_len + q) * 2;
    const float wgt = __expf(ml[mi] - M);
    ls += wgt * ml[mi + 1];
    const float* a = (c == 0) ? accA : accB;
    o += wgt * a[aoff];
  }
  const float v = o / ls;
  const int b = bh >> 3, h = bh & 7;
  const size_t nrow = (size_t)q * B_ + b;
  const int col = h * 64 + d;
  const unsigned short hv = f2bf(v);
  OutP[nrow * 1024 + col] = hv;
  OutP[nrow * 1024 + 512 + col] = f2bf(v - bf2f(hv));
}

// ---------------------------------------------------------------------------
extern "C" void kernel_launch(void* const* d_in, const int* in_sizes, int n_in,
                              void* d_out, int out_size, void* d_ws, size_t ws_size,
                              hipStream_t stream)
{
  const float* reg_x = (const float*)d_in[0];
  const int*   ids   = (const int*)d_in[1];
  const float* table = (const float*)d_in[4];
  const float* wq1 = (const float*)d_in[5];  const float* bq1 = (const float*)d_in[6];
  const float* wq2 = (const float*)d_in[7];  const float* bq2 = (const float*)d_in[8];
  const float* wk  = (const float*)d_in[9];  const float* bk  = (const float*)d_in[10];
  const float* wv  = (const float*)d_in[11]; const float* bv  = (const float*)d_in[12];
  const float* wo  = (const float*)d_in[13]; const float* bo  = (const float*)d_in[14];
  const float* sgw = (const float*)d_in[15];
  const float* rgw = (const float*)d_in[16];
  const float* gb  = (const float*)d_in[17];
  float* out = (float*)d_out;
  char* W = (char*)d_ws;

  // ---- workspace layout (bytes), total 63,438,848 (< 66,060,288 proven-safe)
  const size_t WSLOT  = 1572864;                  // 512*1536*2
  const size_t oApair = 0;                        //  8 MB [reuse: stage-1/2 acc, stage-3 accA]
  const size_t oW     = 8388608;                  //  7 x 1.5 MB = 11,010,048
  const size_t oKhi   = oW + 7 * WSLOT;           // 19,398,656 [reuse: attn_p over Khi+Klo]
  const size_t oKlo   = oKhi + 4194304;
  const size_t oVtHi  = oKlo + 4194304;
  const size_t oVtLo  = oVtHi + 4194304;
  const size_t oQ1hi  = oVtLo + 4194304;          // [reuse: sout_p over Q1hi+Q1lo]
  const size_t oQ1lo  = oQ1hi + 4194304;
  const size_t oQ2hi  = oQ1lo + 4194304;          // [reuse: rout_p over Q2hi+Q2lo]
  const size_t oQ2lo  = oQ2hi + 4194304;
  const size_t oAcc1  = oQ2lo + 4194304;          // 52,953,088 (8 MB, stage-3 accB)
  const size_t oSQhi  = oAcc1 + 8388608;          // 61,341,696
  const size_t oSQlo  = oSQhi + 262144;
  const size_t oX2hi  = oSQlo + 262144;
  const size_t oX2lo  = oX2hi + 262144;
  const size_t oX2Thi = oX2lo + 262144;
  const size_t oX2Tlo = oX2Thi + 262144;
  const size_t oMl    = oX2Tlo + 262144;          // 62,914,560 (+524,288)

  auto U16 = [&](size_t off) { return (unsigned short*)(W + off); };
  auto F32 = [&](size_t off) { return (float*)(W + off); };
  unsigned short* Apair  = U16(oApair);
  unsigned short* Wk3    = U16(oW + 0 * WSLOT);
  unsigned short* Wv3    = U16(oW + 1 * WSLOT);
  unsigned short* Wq13   = U16(oW + 2 * WSLOT);
  unsigned short* Wq23   = U16(oW + 3 * WSLOT);
  unsigned short* Wsg3   = U16(oW + 4 * WSLOT);
  unsigned short* Wrg3   = U16(oW + 5 * WSLOT);
  unsigned short* Wo3    = U16(oW + 6 * WSLOT);
  float*          accS   = F32(oApair);           // stage-1/2 partials; stage-3 chunk 0
  float*          accB3  = F32(oAcc1);            // stage-3 chunk 1
  float*          mlP    = F32(oMl);
  unsigned short* sout_p = U16(oQ1hi);            // Q1 dead after stage-2 partial
  unsigned short* rout_p = U16(oQ2hi);            // Q2 dead after stage-3 partial
  unsigned short* attn_p = U16(oKhi);             // K dead after stage-3 partial

  const dim3 blk(256);

  // ---- precision splits
  split_a_kernel<<<8192, blk, 0, stream>>>(reg_x, Apair);
  WSplit7 ws7;
  ws7.j[0] = WSplitJob{wk,  Wk3};
  ws7.j[1] = WSplitJob{wv,  Wv3};
  ws7.j[2] = WSplitJob{wq1, Wq13};
  ws7.j[3] = WSplitJob{wq2, Wq23};
  ws7.j[4] = WSplitJob{sgw, Wsg3};
  ws7.j[5] = WSplitJob{rgw, Wrg3};
  ws7.j[6] = WSplitJob{wo,  Wo3};
  split_w7_kernel<<<dim3(1024, 7), blk, 0, stream>>>(ws7);
  gather_split_kernel<<<512, blk, 0, stream>>>(table, ids, U16(oSQhi), U16(oSQlo));

  // ---- 4 projections in one launch (blockIdx.z selects weight/output)
  GemmOuts4 proj;
  proj.o[0].W = Wk3;  proj.o[0].bias = bk;  proj.o[0].scale = 1.0f;   proj.o[0].Cf = nullptr;
  proj.o[0].hi = U16(oKhi);  proj.o[0].lo = U16(oKlo);  proj.o[0].mode = 1;
  proj.o[1].W = Wv3;  proj.o[1].bias = bv;  proj.o[1].scale = 1.0f;   proj.o[1].Cf = nullptr;
  proj.o[1].hi = U16(oVtHi); proj.o[1].lo = U16(oVtLo); proj.o[1].mode = 2;
  proj.o[2].W = Wq13; proj.o[2].bias = bq1; proj.o[2].scale = SCALE_; proj.o[2].Cf = nullptr;
  proj.o[2].hi = U16(oQ1hi); proj.o[2].lo = U16(oQ1lo); proj.o[2].mode = 1;
  proj.o[3].W = Wq23; proj.o[3].bias = bq2; proj.o[3].scale = SCALE_; proj.o[3].Cf = nullptr;
  proj.o[3].hi = U16(oQ2hi); proj.o[3].lo = U16(oQ2lo); proj.o[3].mode = 1;
  gemm_split_kernel<<<dim3(32, 8, 4), blk, 0, stream>>>(Apair, proj);

  // ---- stage 1: sum_q attends to reg tokens. KV=2048 split into 16 chunks.
  flash_partial_kernel<<<dim3(1, 16, 16), blk, 0, stream>>>(
      U16(oSQhi), U16(oSQlo), U16(oKhi), U16(oKlo), U16(oVtHi), U16(oVtLo),
      S_, R_, 128, 16, accS, accS, mlP);
  merge_x2_kernel<<<512, blk, 0, stream>>>(accS, mlP,
      U16(oX2hi), U16(oX2lo), U16(oX2Thi), U16(oX2Tlo));

  // ---- stage 2: reg queries attend to summaries (KV=128, 1 chunk)
  flash_partial_kernel<<<dim3(16, 16, 1), blk, 0, stream>>>(
      U16(oQ1hi), U16(oQ1lo), U16(oX2hi), U16(oX2lo), U16(oX2Thi), U16(oX2Tlo),
      R_, S_, 128, 1, accS, accS, mlP);
  merge_rows_kernel<<<8192, blk, 0, stream>>>(accS, accS, mlP, R_, 11, 1, sout_p);

  // ---- stage 3: regular self-attention. KV=2048 split into 2 chunks.
  flash_partial_kernel<<<dim3(16, 16, 2), blk, 0, stream>>>(
      U16(oQ2hi), U16(oQ2lo), U16(oKhi), U16(oKlo), U16(oVtHi), U16(oVtLo),
      R_, R_, 1024, 1, accS, accB3, mlP);
  merge_rows_kernel<<<8192, blk, 0, stream>>>(accS, accB3, mlP, R_, 11, 2, rout_p);

  // ---- fused gate GEMMs + sigmoid + blend -> attn pair
  gate_blend_gemm_kernel<<<dim3(32, 8), blk, 0, stream>>>(
      sout_p, rout_p, Wsg3, Wrg3, gb, attn_p);

  // ---- output projection -> d_out
  GemmOuts4 gf;
  gf.o[0].W = Wo3; gf.o[0].bias = bo; gf.o[0].scale = 1.0f; gf.o[0].Cf = out;
  gf.o[0].hi = nullptr; gf.o[0].lo = nullptr; gf.o[0].mode = 0;
  gf.o[1] = gf.o[0]; gf.o[2] = gf.o[0]; gf.o[3] = gf.o[0];
  gemm_split_kernel<<<dim3(32, 8, 1), blk, 0, stream>>>(attn_p, gf);
}

// Round 7
// 230.511 us; speedup vs baseline: 6.0644x; 1.0612x over previous
//
#include <hip/hip_runtime.h>
#include <cstdint>
#include <cstddef>

// Problem constants (fixed by setup_inputs)
constexpr int R_ = 2048;   // reg_len
constexpr int B_ = 2;      // batch
constexpr int S_ = 128;    // sum_len
constexpr int E_ = 512;    // embed dim
constexpr int H_ = 8;      // heads
constexpr int D_ = 64;     // head dim
constexpr int N_ = R_ * B_;            // 4096 token rows
constexpr float SCALE_ = 0.125f;       // D^-0.5
constexpr float LOG2E_ = 1.44269504088896340736f;
constexpr float SLOG2E_ = SCALE_ * LOG2E_;   // folded into Q scales (exp2 domain)

typedef short bf8_t __attribute__((ext_vector_type(8)));   // 8 bf16 in 4 VGPRs
typedef float f32x4 __attribute__((ext_vector_type(4)));
typedef float f32x16 __attribute__((ext_vector_type(16)));
typedef unsigned u32x4 __attribute__((ext_vector_type(4)));

#define MFMA16(a, b, c) __builtin_amdgcn_mfma_f32_16x16x32_bf16((a), (b), (c), 0, 0, 0)
#define MFMA32(a, b, c) __builtin_amdgcn_mfma_f32_32x32x16_bf16((a), (b), (c), 0, 0, 0)

__device__ __forceinline__ unsigned short f2bf(float f) {
  unsigned u = __builtin_bit_cast(unsigned, f);
  unsigned r = u + 0x7FFFu + ((u >> 16) & 1u);   // RNE
  return (unsigned short)(r >> 16);
}
__device__ __forceinline__ float bf2f(unsigned short h) {
  unsigned u = ((unsigned)h) << 16;
  return __builtin_bit_cast(float, u);
}
// kv-permutation (swap bits 2<->3 within each 16) used for V^T storage so PV
// B-fragments are contiguous; involution.
__device__ __forceinline__ int kvperm(int kv) {
  return (kv & ~15) | (kv & 3) | ((kv & 4) << 1) | ((kv & 8) >> 1);
}

// ---------------------------------------------------------------------------
// Fused precision splits + gather (one launch):
// blocks [0,8192): reg_x fp32 [4096][512] -> Apair bf16 [4096][1024] (hi|lo)
// blocks [8192,15360): 7 weights [512][512] -> bf16 [512][1536] (hi|hi|lo)
// blocks [15360,15872): summary-query gather+split, scale SLOG2E_ folded
// ---------------------------------------------------------------------------
struct WSplitJob { const float* src; unsigned short* dst; };
struct WSplit7 { WSplitJob j[7]; };

__global__ __launch_bounds__(256)
void fused_split_kernel(const float* __restrict__ reg_x, unsigned short* __restrict__ Apair,
                        WSplit7 P, const float* __restrict__ table,
                        const int* __restrict__ ids,
                        unsigned short* __restrict__ sqhi, unsigned short* __restrict__ sqlo)
{
  const int bx = blockIdx.x;
  const int tid = threadIdx.x;
  if (bx < 8192) {
    const int idx = bx * 256 + tid;                 // < 4096*512
    const int r = idx >> 9, c = idx & 511;
    const float v = reg_x[idx];
    const unsigned short hi = f2bf(v);
    unsigned short* d = Apair + ((size_t)r << 10) + c;
    d[0] = hi; d[512] = f2bf(v - bf2f(hi));
  } else if (bx < 15360) {
    const int bj = bx - 8192;
    const WSplitJob jb = P.j[bj >> 10];
    const int idx = (bj & 1023) * 256 + tid;        // < 512*512
    const int r = idx >> 9, c = idx & 511;
    const float v = jb.src[idx];
    const unsigned short hi = f2bf(v);
    const unsigned short lo = f2bf(v - bf2f(hi));
    unsigned short* d = jb.dst + (size_t)r * 1536 + c;
    d[0] = hi; d[512] = hi; d[1024] = lo;
  } else {
    const int idx = (bx - 15360) * 256 + tid;       // < B*H*S*D = 131072
    const int d = idx & 63;
    const int s = (idx >> 6) & 127;
    const int h = (idx >> 13) & 7;
    const int b = idx >> 16;
    const float v = table[(size_t)ids[b * S_ + s] * E_ + h * 64 + d] * SLOG2E_;
    const unsigned short hi = f2bf(v);
    sqhi[idx] = hi;
    sqlo[idx] = f2bf(v - bf2f(hi));
  }
}

// ---------------------------------------------------------------------------
// Split-precision MFMA GEMM (T14 reg-prefetch staging).
// A: bf16 [M][1024] (hi|lo); logical K = 1536, A col wraps mod 1024.
// W: bf16 [512][1536] hi|hi|lo.  Tile 128x64, 256 threads.
// mode 0: Cf[row*512+col] (+bias)
// mode 1: hi/lo pair -> [bh][row>>1][col&63] row-major attn layout
// mode 2: hi/lo pair -> [bh][col&63][kvperm(row>>1)] transposed V layout
// ---------------------------------------------------------------------------
struct GemmOut {
  const unsigned short* W;
  const float* bias;
  float scale;
  float* Cf;
  unsigned short* hi;
  unsigned short* lo;
  int mode;
};
struct GemmOuts4 { GemmOut o[4]; };

__global__ __launch_bounds__(256, 4)
void gemm_split_kernel(const unsigned short* __restrict__ A, GemmOuts4 P)
{
  const GemmOut g = P.o[blockIdx.z];
  __shared__ unsigned short As[128][48];
  __shared__ unsigned short Ws[64][48];

  const int tid = threadIdx.x;
  const int w = tid >> 6;          // wave 0..3
  const int l = tid & 63;
  const int lr = l & 15;
  const int lg = l >> 4;
  const int n0 = blockIdx.x * 128;
  const int o0 = blockIdx.y * 64;

  f32x4 acc[2][4];
#pragma unroll
  for (int m = 0; m < 2; ++m)
#pragma unroll
    for (int n = 0; n < 4; ++n) acc[m][n] = (f32x4){0.f, 0.f, 0.f, 0.f};

  const int ar = tid >> 1;          // 0..127
  const int ac = (tid & 1) * 16;
  const int wr = tid >> 2;          // 0..63
  const int wc = (tid & 3) * 8;

  bf8_t ra0 = *(const bf8_t*)(A + (size_t)(n0 + ar) * 1024 + ac);
  bf8_t ra1 = *(const bf8_t*)(A + (size_t)(n0 + ar) * 1024 + ac + 8);
  bf8_t rw0 = *(const bf8_t*)(g.W + (size_t)(o0 + wr) * 1536 + wc);

  for (int k0 = 0; k0 < 1536; k0 += 32) {
    __syncthreads();
    *(bf8_t*)&As[ar][ac] = ra0;
    *(bf8_t*)&As[ar][ac + 8] = ra1;
    *(bf8_t*)&Ws[wr][wc] = rw0;
    __syncthreads();
    if (k0 + 32 < 1536) {
      const int ak = (k0 + 32) & 1023;
      ra0 = *(const bf8_t*)(A + (size_t)(n0 + ar) * 1024 + ak + ac);
      ra1 = *(const bf8_t*)(A + (size_t)(n0 + ar) * 1024 + ak + ac + 8);
      rw0 = *(const bf8_t*)(g.W + (size_t)(o0 + wr) * 1536 + k0 + 32 + wc);
    }

    bf8_t bvs[4];
#pragma unroll
    for (int n = 0; n < 4; ++n)
      bvs[n] = *(const bf8_t*)&Ws[n * 16 + lr][lg * 8];
#pragma unroll
    for (int m = 0; m < 2; ++m) {
      bf8_t av = *(const bf8_t*)&As[w * 32 + m * 16 + lr][lg * 8];
#pragma unroll
      for (int n = 0; n < 4; ++n)
        acc[m][n] = MFMA16(av, bvs[n], acc[m][n]);
    }
  }

#pragma unroll
  for (int m = 0; m < 2; ++m)
#pragma unroll
    for (int n = 0; n < 4; ++n)
#pragma unroll
      for (int r = 0; r < 4; ++r) {
        const int row = n0 + w * 32 + m * 16 + lg * 4 + r;
        const int col = o0 + n * 16 + lr;
        float v = acc[m][n][r];
        if (g.bias) v += g.bias[col];
        v *= g.scale;
        if (g.mode == 0) {
          g.Cf[((size_t)row << 9) + col] = v;
        } else {
          const int bb = row & 1, rr = row >> 1;
          const int hh = col >> 6, dd = col & 63;
          size_t id;
          if (g.mode == 1) id = (((size_t)(bb * H_ + hh) * R_) + rr) * 64 + dd;
          else             id = (((size_t)(bb * H_ + hh) * 64) + dd) * R_ + kvperm(rr);
          const unsigned short hv = f2bf(v);
          g.hi[id] = hv;
          g.lo[id] = f2bf(v - bf2f(hv));
        }
      }
}

// ---------------------------------------------------------------------------
// Fused gate GEMMs + sigmoid + blend (unchanged structure).
// ---------------------------------------------------------------------------
__global__ __launch_bounds__(256, 4)
void gate_blend_gemm_kernel(const unsigned short* __restrict__ A1,
                            const unsigned short* __restrict__ A2,
                            const unsigned short* __restrict__ W1,
                            const unsigned short* __restrict__ W2,
                            const float* __restrict__ gb,
                            unsigned short* __restrict__ attnP)
{
  __shared__ unsigned short As[128][48];
  __shared__ unsigned short Ws[64][48];

  const int tid = threadIdx.x;
  const int w = tid >> 6;
  const int l = tid & 63;
  const int lr = l & 15;
  const int lg = l >> 4;
  const int n0 = blockIdx.x * 128;
  const int o0 = blockIdx.y * 64;

  f32x4 acc[2][4];
#pragma unroll
  for (int m = 0; m < 2; ++m)
#pragma unroll
    for (int n = 0; n < 4; ++n) acc[m][n] = (f32x4){0.f, 0.f, 0.f, 0.f};

  const int ar = tid >> 1;
  const int ac = (tid & 1) * 16;
  const int wr = tid >> 2;
  const int wc = (tid & 3) * 8;

  auto aP = [&](int kk) {
    const unsigned short* Ax = (kk < 48) ? A1 : A2;
    const int k0 = ((kk < 48) ? kk : kk - 48) * 32;
    return Ax + (size_t)(n0 + ar) * 1024 + (k0 & 1023) + ac;
  };
  auto wP = [&](int kk) {
    const unsigned short* Wx = (kk < 48) ? W1 : W2;
    const int k0 = ((kk < 48) ? kk : kk - 48) * 32;
    return Wx + (size_t)(o0 + wr) * 1536 + k0 + wc;
  };

  bf8_t ra0 = *(const bf8_t*)aP(0);
  bf8_t ra1 = *(const bf8_t*)(aP(0) + 8);
  bf8_t rw0 = *(const bf8_t*)wP(0);

  for (int kk = 0; kk < 96; ++kk) {
    __syncthreads();
    *(bf8_t*)&As[ar][ac] = ra0;
    *(bf8_t*)&As[ar][ac + 8] = ra1;
    *(bf8_t*)&Ws[wr][wc] = rw0;
    __syncthreads();
    if (kk + 1 < 96) {
      ra0 = *(const bf8_t*)aP(kk + 1);
      ra1 = *(const bf8_t*)(aP(kk + 1) + 8);
      rw0 = *(const bf8_t*)wP(kk + 1);
    }

    bf8_t bvs[4];
#pragma unroll
    for (int n = 0; n < 4; ++n)
      bvs[n] = *(const bf8_t*)&Ws[n * 16 + lr][lg * 8];
#pragma unroll
    for (int m = 0; m < 2; ++m) {
      bf8_t av = *(const bf8_t*)&As[w * 32 + m * 16 + lr][lg * 8];
#pragma unroll
      for (int n = 0; n < 4; ++n)
        acc[m][n] = MFMA16(av, bvs[n], acc[m][n]);
    }
  }

#pragma unroll
  for (int m = 0; m < 2; ++m)
#pragma unroll
    for (int n = 0; n < 4; ++n)
#pragma unroll
      for (int r = 0; r < 4; ++r) {
        const int row = n0 + w * 32 + m * 16 + lg * 4 + r;
        const int col = o0 + n * 16 + lr;
        const float t = acc[m][n][r] + gb[col];
        const float gt = 1.0f / (1.0f + __expf(-t));
        const size_t base = (size_t)row << 10;
        const float so = bf2f(A1[base + col]) + bf2f(A1[base + 512 + col]);
        const float ro = bf2f(A2[base + col]) + bf2f(A2[base + 512 + col]);
        const float a = gt * so + (1.0f - gt) * ro;
        const unsigned short hv = f2bf(a);
        attnP[base + col] = hv;
        attnP[base + 512 + col] = f2bf(a - bf2f(hv));
      }
}

// ---------------------------------------------------------------------------
// Split-precision 32x32x16 flash attention, KVBLK=64, exp2 domain, defer-max.
// Swapped QK^T (MFMA32(K,Q)) -> lane owns all scores of q=lane&31.
// V^T stored kv-PERMUTED (kvperm) so PV B-frags are contiguous b128 reads.
// out_mode 0: unnormalized fp32 partial [bh][q][64] + (m,l)
// out_mode 1: normalized bf16 hi/lo pair packed rows [q*B+b][1024]
// ---------------------------------------------------------------------------
__global__ __launch_bounds__(256, 2)
void flash_partial_kernel(const unsigned short* __restrict__ Qhi, const unsigned short* __restrict__ Qlo,
                          const unsigned short* __restrict__ Khi, const unsigned short* __restrict__ Klo,
                          const unsigned short* __restrict__ VtHi, const unsigned short* __restrict__ VtLo,
                          int q_len, int kv_len, int chunk, int zsplit, int out_mode,
                          float* __restrict__ accA, float* __restrict__ accB,
                          float* __restrict__ mlP, unsigned short* __restrict__ OutP)
{
  __shared__ unsigned short KsH[64][72];   // 144B rows: 16B-aligned, stride 36dw
  __shared__ unsigned short KsL[64][72];
  __shared__ unsigned short VsH[64][72];
  __shared__ unsigned short VsL[64][72];

  const int tid = threadIdx.x;
  const int w = tid >> 6;
  const int l = tid & 63;
  const int lq = l & 31;           // q col (QK B / scores) and d-row (PV A)
  const int hi = l >> 5;           // k-slot group
  const int bh = blockIdx.y;
  const int q0 = blockIdx.x * 128;
  const int c = blockIdx.z;
  const int kvbeg = c * chunk;
  const int kvend = kvbeg + chunk;
  const int qrow = q0 + w * 32 + lq;

  // Q B-fragments (col q = lq, k-slot hi*8+j -> d = kd*16 + hi*8 + j)
  bf8_t qh[4], ql[4];
  {
    const size_t qbase = ((size_t)bh * q_len + qrow) * 64;
#pragma unroll
    for (int kd = 0; kd < 4; ++kd) {
      qh[kd] = *(const bf8_t*)(Qhi + qbase + kd * 16 + hi * 8);
      ql[kd] = *(const bf8_t*)(Qlo + qbase + kd * 16 + hi * 8);
    }
  }

  f32x16 acc0 = {0,0,0,0,0,0,0,0,0,0,0,0,0,0,0,0};
  f32x16 acc1 = {0,0,0,0,0,0,0,0,0,0,0,0,0,0,0,0};
  float mrow = -INFINITY;
  float lrow = 0.0f;

  const int sr = tid >> 2;            // staging row 0..63
  const int sc = (tid & 3) * 16;      // staging col 0,16,32,48

  // prefetch first 64-kv tile into regs (T14)
  bf8_t rkh[2], rkl[2], rvh[2], rvl[2];
  {
    const size_t kb = ((size_t)bh * kv_len + kvbeg + sr) * 64 + sc;
    rkh[0] = *(const bf8_t*)(Khi + kb);  rkh[1] = *(const bf8_t*)(Khi + kb + 8);
    rkl[0] = *(const bf8_t*)(Klo + kb);  rkl[1] = *(const bf8_t*)(Klo + kb + 8);
    const size_t vb = ((size_t)bh * 64 + sr) * kv_len + kvbeg + sc;
    rvh[0] = *(const bf8_t*)(VtHi + vb); rvh[1] = *(const bf8_t*)(VtHi + vb + 8);
    rvl[0] = *(const bf8_t*)(VtLo + vb); rvl[1] = *(const bf8_t*)(VtLo + vb + 8);
  }

  for (int kv0 = kvbeg; kv0 < kvend; kv0 += 64) {
    __syncthreads();
    *(bf8_t*)&KsH[sr][sc] = rkh[0];  *(bf8_t*)&KsH[sr][sc + 8] = rkh[1];
    *(bf8_t*)&KsL[sr][sc] = rkl[0];  *(bf8_t*)&KsL[sr][sc + 8] = rkl[1];
    *(bf8_t*)&VsH[sr][sc] = rvh[0];  *(bf8_t*)&VsH[sr][sc + 8] = rvh[1];
    *(bf8_t*)&VsL[sr][sc] = rvl[0];  *(bf8_t*)&VsL[sr][sc + 8] = rvl[1];
    __syncthreads();
    if (kv0 + 64 < kvend) {
      const size_t kb = ((size_t)bh * kv_len + kv0 + 64 + sr) * 64 + sc;
      rkh[0] = *(const bf8_t*)(Khi + kb);  rkh[1] = *(const bf8_t*)(Khi + kb + 8);
      rkl[0] = *(const bf8_t*)(Klo + kb);  rkl[1] = *(const bf8_t*)(Klo + kb + 8);
      const size_t vb = ((size_t)bh * 64 + sr) * kv_len + kv0 + 64 + sc;
      rvh[0] = *(const bf8_t*)(VtHi + vb); rvh[1] = *(const bf8_t*)(VtHi + vb + 8);
      rvl[0] = *(const bf8_t*)(VtLo + vb); rvl[1] = *(const bf8_t*)(VtLo + vb + 8);
    }

    // ---- QK^T swapped (24 MFMA32): s0 = kv 0..31, s1 = kv 32..63 (x log2e)
    f32x16 s0 = {0,0,0,0,0,0,0,0,0,0,0,0,0,0,0,0};
    f32x16 s1 = {0,0,0,0,0,0,0,0,0,0,0,0,0,0,0,0};
    __builtin_amdgcn_s_setprio(1);
#pragma unroll
    for (int kd = 0; kd < 4; ++kd) {
      const bf8_t kfh0 = *(const bf8_t*)&KsH[lq][kd * 16 + hi * 8];
      const bf8_t kfl0 = *(const bf8_t*)&KsL[lq][kd * 16 + hi * 8];
      s0 = MFMA32(kfh0, qh[kd], s0);
      s0 = MFMA32(kfh0, ql[kd], s0);
      s0 = MFMA32(kfl0, qh[kd], s0);
      const bf8_t kfh1 = *(const bf8_t*)&KsH[32 + lq][kd * 16 + hi * 8];
      const bf8_t kfl1 = *(const bf8_t*)&KsL[32 + lq][kd * 16 + hi * 8];
      s1 = MFMA32(kfh1, qh[kd], s1);
      s1 = MFMA32(kfh1, ql[kd], s1);
      s1 = MFMA32(kfl1, qh[kd], s1);
    }
    __builtin_amdgcn_s_setprio(0);

    // ---- online softmax (exp2 domain), defer-max (THR = 8)
    float mx = fmaxf(s0[0], s1[0]);
#pragma unroll
    for (int r = 1; r < 16; ++r) mx = fmaxf(mx, fmaxf(s0[r], s1[r]));
    mx = fmaxf(mx, __shfl_xor(mx, 32));
    if (mx > mrow + 8.0f) {
      const float f = exp2f(mrow - mx);   // first tile: exp2(-inf)=0
      mrow = mx;
      lrow *= f;
#pragma unroll
      for (int r = 0; r < 16; ++r) { acc0[r] *= f; acc1[r] *= f; }
    }
    float ts = 0.f;
#pragma unroll
    for (int r = 0; r < 16; ++r) { s0[r] = exp2f(s0[r] - mrow); ts += s0[r]; }
#pragma unroll
    for (int r = 0; r < 16; ++r) { s1[r] = exp2f(s1[r] - mrow); ts += s1[r]; }
    ts += __shfl_xor(ts, 32);
    lrow += ts;

    // ---- P pack: trunc-hi + trunc-lo as packed u32 pairs (lane-local)
    bf8_t pah[4], pal[4];
#pragma unroll
    for (int n = 0; n < 2; ++n)
#pragma unroll
      for (int ks = 0; ks < 2; ++ks) {
        u32x4 hp, lp;
#pragma unroll
        for (int p2 = 0; p2 < 4; ++p2) {
          const float a = n ? s1[ks * 8 + p2 * 2]     : s0[ks * 8 + p2 * 2];
          const float b = n ? s1[ks * 8 + p2 * 2 + 1] : s0[ks * 8 + p2 * 2 + 1];
          const unsigned ua = __builtin_bit_cast(unsigned, a);
          const unsigned ub = __builtin_bit_cast(unsigned, b);
          hp[p2] = (ua >> 16) | (ub & 0xFFFF0000u);
          const float la = a - __builtin_bit_cast(float, ua & 0xFFFF0000u);
          const float lb = b - __builtin_bit_cast(float, ub & 0xFFFF0000u);
          lp[p2] = (__builtin_bit_cast(unsigned, la) >> 16) |
                   (__builtin_bit_cast(unsigned, lb) & 0xFFFF0000u);
        }
        pah[n * 2 + ks] = __builtin_bit_cast(bf8_t, hp);
        pal[n * 2 + ks] = __builtin_bit_cast(bf8_t, lp);
      }

    // ---- PV (24 MFMA32); V^T permuted-contiguous b128 reads
    __builtin_amdgcn_s_setprio(1);
#pragma unroll
    for (int n = 0; n < 2; ++n)
#pragma unroll
      for (int ks = 0; ks < 2; ++ks) {
        const int vcol = n * 32 + ks * 16 + hi * 8;
        const bf8_t ph = pah[n * 2 + ks];
        const bf8_t pl = pal[n * 2 + ks];
        {
          const bf8_t vfh = *(const bf8_t*)&VsH[lq][vcol];
          const bf8_t vfl = *(const bf8_t*)&VsL[lq][vcol];
          acc0 = MFMA32(vfh, ph, acc0);
          acc0 = MFMA32(vfh, pl, acc0);
          acc0 = MFMA32(vfl, ph, acc0);
        }
        {
          const bf8_t vfh = *(const bf8_t*)&VsH[32 + lq][vcol];
          const bf8_t vfl = *(const bf8_t*)&VsL[32 + lq][vcol];
          acc1 = MFMA32(vfh, ph, acc1);
          acc1 = MFMA32(vfh, pl, acc1);
          acc1 = MFMA32(vfl, ph, acc1);
        }
      }
    __builtin_amdgcn_s_setprio(0);
  }

  if (out_mode == 0) {
    // unnormalized partial [bh][q][64]; d = hd*32 + rg*8 + hi*4 + (0..3)
    const size_t cstride = (size_t)16 * q_len * 64;
    float* accbase = (c < zsplit) ? accA + (size_t)c * cstride
                                  : accB + (size_t)(c - zsplit) * cstride;
    float* rowp = accbase + ((size_t)bh * q_len + qrow) * 64;
#pragma unroll
    for (int rg = 0; rg < 4; ++rg) {
      *(float4*)(rowp + rg * 8 + hi * 4) =
          make_float4(acc0[rg * 4 + 0], acc0[rg * 4 + 1], acc0[rg * 4 + 2], acc0[rg * 4 + 3]);
      *(float4*)(rowp + 32 + rg * 8 + hi * 4) =
          make_float4(acc1[rg * 4 + 0], acc1[rg * 4 + 1], acc1[rg * 4 + 2], acc1[rg * 4 + 3]);
    }
    if (l < 32) {
      const int q = q0 + w * 32 + l;
      *(float2*)&mlP[((size_t)(c * 16 + bh) * q_len + q) * 2] = make_float2(mrow, lrow);
    }
  } else {
    // normalized bf16 pair, packed rows [q*B+b][1024] (hi | lo at +512)
    const float inv = 1.0f / lrow;
    const int b = bh >> 3, h = bh & 7;
    const size_t base = ((size_t)qrow * B_ + b) << 10;
#pragma unroll
    for (int hd = 0; hd < 2; ++hd)
#pragma unroll
      for (int rg = 0; rg < 4; ++rg) {
        const int col = h * 64 + hd * 32 + rg * 8 + hi * 4;
        ushort4 hv4, lv4;
#pragma unroll
        for (int i = 0; i < 4; ++i) {
          const float v = (hd ? acc1[rg * 4 + i] : acc0[rg * 4 + i]) * inv;
          const unsigned short hv = f2bf(v);
          ((unsigned short*)&hv4)[i] = hv;
          ((unsigned short*)&lv4)[i] = f2bf(v - bf2f(hv));
        }
        *(ushort4*)&OutP[base + col] = hv4;
        *(ushort4*)&OutP[base + 512 + col] = lv4;
      }
  }
}

// ---------------------------------------------------------------------------
// Merge stage-1 partials -> X2 (row-major pair) and X2^T (pair, kv-permuted)
// ---------------------------------------------------------------------------
__global__ __launch_bounds__(256)
void merge_x2_kernel(const float* __restrict__ acc, const float* __restrict__ ml,
                     unsigned short* __restrict__ X2hi, unsigned short* __restrict__ X2lo,
                     unsigned short* __restrict__ X2Thi, unsigned short* __restrict__ X2Tlo)
{
  const int idx = blockIdx.x * 256 + threadIdx.x;   // < 16*128*64
  const int d = idx & 63;
  const int q = (idx >> 6) & 127;
  const int bh = idx >> 13;
  float M = -INFINITY;
#pragma unroll
  for (int c = 0; c < 16; ++c)
    M = fmaxf(M, ml[((size_t)(c * 16 + bh) * 128 + q) * 2]);
  float ls = 0.f, o = 0.f;
#pragma unroll
  for (int c = 0; c < 16; ++c) {
    const size_t mi = ((size_t)(c * 16 + bh) * 128 + q) * 2;
    const float wgt = exp2f(ml[mi] - M);
    ls += wgt * ml[mi + 1];
    o += wgt * acc[(size_t)c * 131072 + ((size_t)bh * 128 + q) * 64 + d];
  }
  const float v = o / ls;
  const unsigned short hv = f2bf(v);
  const unsigned short lv = f2bf(v - bf2f(hv));
  X2hi[((size_t)bh * 128 + q) * 64 + d] = hv;
  X2lo[((size_t)bh * 128 + q) * 64 + d] = lv;
  const int qp = kvperm(q);
  X2Thi[((size_t)bh * 64 + d) * 128 + qp] = hv;
  X2Tlo[((size_t)bh * 64 + d) * 128 + qp] = lv;
}

// ---------------------------------------------------------------------------
// Merge stage-3 partials (2 chunks) -> packed pair rows [q*B+b][1024]
// ---------------------------------------------------------------------------
__global__ __launch_bounds__(256)
void merge_rows_kernel(const float* __restrict__ accA, const float* __restrict__ accB,
                       const float* __restrict__ ml, unsigned short* __restrict__ OutP)
{
  const int idx = blockIdx.x * 256 + threadIdx.x;   // < 16*2048*64
  const int d = idx & 63;
  const int q = (idx >> 6) & 2047;
  const int bh = idx >> 17;
  const size_t mi0 = ((size_t)bh * 2048 + q) * 2;
  const size_t mi1 = ((size_t)(16 + bh) * 2048 + q) * 2;
  const float m0 = ml[mi0], m1 = ml[mi1];
  const float M = fmaxf(m0, m1);
  const float w0 = exp2f(m0 - M), w1 = exp2f(m1 - M);
  const float ls = w0 * ml[mi0 + 1] + w1 * ml[mi1 + 1];
  const size_t aoff = ((size_t)bh * 2048 + q) * 64 + d;
  const float v = (w0 * accA[aoff] + w1 * accB[aoff]) / ls;
  const int b = bh >> 3, h = bh & 7;
  const size_t nrow = (size_t)q * B_ + b;
  const int col = h * 64 + d;
  const unsigned short hv = f2bf(v);
  OutP[nrow * 1024 + col] = hv;
  OutP[nrow * 1024 + 512 + col] = f2bf(v - bf2f(hv));
}

// ---------------------------------------------------------------------------
extern "C" void kernel_launch(void* const* d_in, const int* in_sizes, int n_in,
                              void* d_out, int out_size, void* d_ws, size_t ws_size,
                              hipStream_t stream)
{
  const float* reg_x = (const float*)d_in[0];
  const int*   ids   = (const int*)d_in[1];
  const float* table = (const float*)d_in[4];
  const float* wq1 = (const float*)d_in[5];  const float* bq1 = (const float*)d_in[6];
  const float* wq2 = (const float*)d_in[7];  const float* bq2 = (const float*)d_in[8];
  const float* wk  = (const float*)d_in[9];  const float* bk  = (const float*)d_in[10];
  const float* wv  = (const float*)d_in[11]; const float* bv  = (const float*)d_in[12];
  const float* wo  = (const float*)d_in[13]; const float* bo  = (const float*)d_in[14];
  const float* sgw = (const float*)d_in[15];
  const float* rgw = (const float*)d_in[16];
  const float* gb  = (const float*)d_in[17];
  float* out = (float*)d_out;
  char* W = (char*)d_ws;

  // ---- workspace layout (bytes), total 63,438,848 (< 66,060,288 proven-safe)
  const size_t WSLOT  = 1572864;                  // 512*1536*2
  const size_t oApair = 0;                        //  8 MB [reuse: stage-1 acc, stage-3 accA]
  const size_t oW     = 8388608;                  //  7 x 1.5 MB
  const size_t oKhi   = oW + 7 * WSLOT;           // [reuse: attn_p over Khi+Klo]
  const size_t oKlo   = oKhi + 4194304;
  const size_t oVtHi  = oKlo + 4194304;
  const size_t oVtLo  = oVtHi + 4194304;
  const size_t oQ1hi  = oVtLo + 4194304;          // [reuse: sout_p over Q1hi+Q1lo]
  const size_t oQ1lo  = oQ1hi + 4194304;
  const size_t oQ2hi  = oQ1lo + 4194304;          // [reuse: rout_p over Q2hi+Q2lo]
  const size_t oQ2lo  = oQ2hi + 4194304;
  const size_t oAcc1  = oQ2lo + 4194304;          // 8 MB, stage-3 accB
  const size_t oSQhi  = oAcc1 + 8388608;
  const size_t oSQlo  = oSQhi + 262144;
  const size_t oX2hi  = oSQlo + 262144;
  const size_t oX2lo  = oX2hi + 262144;
  const size_t oX2Thi = oX2lo + 262144;
  const size_t oX2Tlo = oX2Thi + 262144;
  const size_t oMl    = oX2Tlo + 262144;          // +524,288

  auto U16 = [&](size_t off) { return (unsigned short*)(W + off); };
  auto F32 = [&](size_t off) { return (float*)(W + off); };
  unsigned short* Apair  = U16(oApair);
  unsigned short* Wk3    = U16(oW + 0 * WSLOT);
  unsigned short* Wv3    = U16(oW + 1 * WSLOT);
  unsigned short* Wq13   = U16(oW + 2 * WSLOT);
  unsigned short* Wq23   = U16(oW + 3 * WSLOT);
  unsigned short* Wsg3   = U16(oW + 4 * WSLOT);
  unsigned short* Wrg3   = U16(oW + 5 * WSLOT);
  unsigned short* Wo3    = U16(oW + 6 * WSLOT);
  float*          accS   = F32(oApair);           // stage-1 partials; stage-3 chunk 0
  float*          accB3  = F32(oAcc1);            // stage-3 chunk 1
  float*          mlP    = F32(oMl);
  unsigned short* sout_p = U16(oQ1hi);            // Q1 dead after stage-2 flash
  unsigned short* rout_p = U16(oQ2hi);            // Q2 dead after stage-3 flash
  unsigned short* attn_p = U16(oKhi);             // K dead after stage-3 flash

  const dim3 blk(256);

  // ---- fused precision splits + gather (1 launch)
  WSplit7 ws7;
  ws7.j[0] = WSplitJob{wk,  Wk3};
  ws7.j[1] = WSplitJob{wv,  Wv3};
  ws7.j[2] = WSplitJob{wq1, Wq13};
  ws7.j[3] = WSplitJob{wq2, Wq23};
  ws7.j[4] = WSplitJob{sgw, Wsg3};
  ws7.j[5] = WSplitJob{rgw, Wrg3};
  ws7.j[6] = WSplitJob{wo,  Wo3};
  fused_split_kernel<<<15872, blk, 0, stream>>>(reg_x, Apair, ws7, table, ids,
                                                U16(oSQhi), U16(oSQlo));

  // ---- 4 projections in one launch (Q scales carry log2e for exp2 domain)
  GemmOuts4 proj;
  proj.o[0].W = Wk3;  proj.o[0].bias = bk;  proj.o[0].scale = 1.0f;    proj.o[0].Cf = nullptr;
  proj.o[0].hi = U16(oKhi);  proj.o[0].lo = U16(oKlo);  proj.o[0].mode = 1;
  proj.o[1].W = Wv3;  proj.o[1].bias = bv;  proj.o[1].scale = 1.0f;    proj.o[1].Cf = nullptr;
  proj.o[1].hi = U16(oVtHi); proj.o[1].lo = U16(oVtLo); proj.o[1].mode = 2;
  proj.o[2].W = Wq13; proj.o[2].bias = bq1; proj.o[2].scale = SLOG2E_; proj.o[2].Cf = nullptr;
  proj.o[2].hi = U16(oQ1hi); proj.o[2].lo = U16(oQ1lo); proj.o[2].mode = 1;
  proj.o[3].W = Wq23; proj.o[3].bias = bq2; proj.o[3].scale = SLOG2E_; proj.o[3].Cf = nullptr;
  proj.o[3].hi = U16(oQ2hi); proj.o[3].lo = U16(oQ2lo); proj.o[3].mode = 1;
  gemm_split_kernel<<<dim3(32, 8, 4), blk, 0, stream>>>(Apair, proj);

  // ---- stage 1: summary queries attend to reg tokens (16 KV chunks)
  flash_partial_kernel<<<dim3(1, 16, 16), blk, 0, stream>>>(
      U16(oSQhi), U16(oSQlo), U16(oKhi), U16(oKlo), U16(oVtHi), U16(oVtLo),
      S_, R_, 128, 16, 0, accS, accS, mlP, nullptr);
  merge_x2_kernel<<<512, blk, 0, stream>>>(accS, mlP,
      U16(oX2hi), U16(oX2lo), U16(oX2Thi), U16(oX2Tlo));

  // ---- stage 2: reg queries attend to summaries (1 chunk -> direct output)
  flash_partial_kernel<<<dim3(16, 16, 1), blk, 0, stream>>>(
      U16(oQ1hi), U16(oQ1lo), U16(oX2hi), U16(oX2lo), U16(oX2Thi), U16(oX2Tlo),
      R_, S_, 128, 1, 1, accS, accS, mlP, sout_p);

  // ---- stage 3: regular self-attention (2 KV chunks)
  flash_partial_kernel<<<dim3(16, 16, 2), blk, 0, stream>>>(
      U16(oQ2hi), U16(oQ2lo), U16(oKhi), U16(oKlo), U16(oVtHi), U16(oVtLo),
      R_, R_, 1024, 1, 0, accS, accB3, mlP, nullptr);
  merge_rows_kernel<<<8192, blk, 0, stream>>>(accS, accB3, mlP, rout_p);

  // ---- fused gate GEMMs + sigmoid + blend -> attn pair
  gate_blend_gemm_kernel<<<dim3(32, 8), blk, 0, stream>>>(
      sout_p, rout_p, Wsg3, Wrg3, gb, attn_p);

  // ---- output projection -> d_out
  GemmOuts4 gf;
  gf.o[0].W = Wo3; gf.o[0].bias = bo; gf.o[0].scale = 1.0f; gf.o[0].Cf = out;
  gf.o[0].hi = nullptr; gf.o[0].lo = nullptr; gf.o[0].mode = 0;
  gf.o[1] = gf.o[0]; gf.o[2] = gf.o[0]; gf.o[3] = gf.o[0];
  gemm_split_kernel<<<dim3(32, 8, 1), blk, 0, stream>>>(attn_p, gf);
}